// Round 1
// baseline (14525.775 us; speedup 1.0000x reference)
//
#include <hip/hip_runtime.h>
#include <cstdint>
#include <cmath>

// ---------------------------------------------------------------------------
// Informer forward, fp32, correctness-first round.
// B=16, LEN_SEQ=512, D_MODEL=512, N_HEAD=8 (D_HEAD=64), FACTOR=5, D_FF=2048.
// Key design point: exact reproduction of jax.random (threefry2x32) so the
// ProbSparse sampled indices and top-k row selection match the reference
// bit-for-bit in expectation. PRNG hypothesis H2: randint lower_bits[j] =
// threefry(rkey, (j, j+size)).second  (64-bit / (2,)+shape stream layout).
// ---------------------------------------------------------------------------

#define HD __host__ __device__

HD inline unsigned rotl32(unsigned x, int r) { return (x << r) | (x >> (32 - r)); }
HD inline void tfround(unsigned& x0, unsigned& x1, int r) {
    x0 += x1; x1 = rotl32(x1, r); x1 ^= x0;
}
HD inline void threefry2x32(unsigned k0, unsigned k1, unsigned c0, unsigned c1,
                            unsigned& o0, unsigned& o1) {
    unsigned ks2 = k0 ^ k1 ^ 0x1BD11BDAu;
    unsigned x0 = c0 + k0, x1 = c1 + k1;
    tfround(x0, x1, 13); tfround(x0, x1, 15); tfround(x0, x1, 26); tfround(x0, x1, 6);
    x0 += k1; x1 += ks2 + 1u;
    tfround(x0, x1, 17); tfround(x0, x1, 29); tfround(x0, x1, 16); tfround(x0, x1, 24);
    x0 += ks2; x1 += k0 + 2u;
    tfround(x0, x1, 13); tfround(x0, x1, 15); tfround(x0, x1, 26); tfround(x0, x1, 6);
    x0 += k0; x1 += k1 + 3u;
    tfround(x0, x1, 17); tfround(x0, x1, 29); tfround(x0, x1, 16); tfround(x0, x1, 24);
    x0 += k1; x1 += ks2 + 4u;
    tfround(x0, x1, 13); tfround(x0, x1, 15); tfround(x0, x1, 26); tfround(x0, x1, 6);
    x0 += ks2; x1 += k0 + 5u;
    o0 = x0; o1 = x1;
}

// ---------------------------------------------------------------------------
// Kernels
// ---------------------------------------------------------------------------

// out = in + positional encoding (depends only on (l,d))
__global__ void pe_add_k(const float* __restrict__ in, float* __restrict__ out, int total) {
    int t = blockIdx.x * 256 + threadIdx.x;
    if (t >= total) return;
    int d = t % 512;
    int l = (t / 512) % 512;
    float i2 = (float)(d & ~1);
    float div = expf(i2 * (-0.017988946039016f));  // -ln(10000)/512
    float ang = (float)l * div;
    float v = (d & 1) ? cosf(ang) : sinf(ang);
    out[t] = in[t] + v;
}

// rearrange dist_w (O,I,H) -> W2[(h*512+i)*512 + o]
__global__ void rearr_w2_k(const float* __restrict__ dw, float* __restrict__ w2, int total) {
    int t = blockIdx.x * 256 + threadIdx.x;
    if (t >= total) return;
    int o = t % 512;
    int rest = t / 512;
    int i = rest % 512;
    int h = rest / 512;
    w2[t] = dw[(size_t)o * 1536 + i * 3 + h];
}

// Generic fp32 GEMM: C[M,N] = A[M,K] @ B[K,N] (+bias) (+relu) (+res)
// Requires M%64==0, N%64==0, K%16==0 (all shapes here comply).
__global__ __launch_bounds__(256) void gemm_k(
    const float* __restrict__ A, const float* __restrict__ B,
    const float* __restrict__ bias, const float* __restrict__ res,
    float* __restrict__ C, int M, int N, int K, int relu) {
    __shared__ float As[16][65];
    __shared__ float Bs[16][65];
    int tx = threadIdx.x & 15;
    int ty = threadIdx.x >> 4;
    int bm = blockIdx.y * 64;
    int bn = blockIdx.x * 64;
    float acc[4][4] = {};
    for (int k0 = 0; k0 < K; k0 += 16) {
        #pragma unroll
        for (int i = 0; i < 4; i++) {
            int lin = threadIdx.x + 256 * i;
            int m = lin >> 4, kk = lin & 15;
            As[kk][m] = A[(size_t)(bm + m) * K + k0 + kk];
            int kk2 = lin >> 6, n = lin & 63;
            Bs[kk2][n] = B[(size_t)(k0 + kk2) * N + bn + n];
        }
        __syncthreads();
        #pragma unroll
        for (int kk = 0; kk < 16; kk++) {
            float a[4], b[4];
            #pragma unroll
            for (int i = 0; i < 4; i++) a[i] = As[kk][ty * 4 + i];
            #pragma unroll
            for (int j = 0; j < 4; j++) b[j] = Bs[kk][tx * 4 + j];
            #pragma unroll
            for (int i = 0; i < 4; i++)
                #pragma unroll
                for (int j = 0; j < 4; j++) acc[i][j] += a[i] * b[j];
        }
        __syncthreads();
    }
    #pragma unroll
    for (int i = 0; i < 4; i++) {
        int m = bm + ty * 4 + i;
        #pragma unroll
        for (int j = 0; j < 4; j++) {
            int n = bn + tx * 4 + j;
            float v = acc[i][j];
            if (bias) v += bias[n];
            if (relu) v = fmaxf(v, 0.f);
            if (res) v += res[(size_t)m * N + n];
            C[(size_t)m * N + n] = v;
        }
    }
}

// idx[j] = threefry(rkey, (j, j+size)).second & mask   (H2 hypothesis)
__global__ void ridx_k(unsigned k0, unsigned k1, int size, unsigned mask, int* __restrict__ idx) {
    int j = blockIdx.x * 256 + threadIdx.x;
    if (j >= size) return;
    unsigned o0, o1;
    threefry2x32(k0, k1, (unsigned)j, (unsigned)(j + size), o0, o1);
    idx[j] = (int)(o1 & mask);
}

// M[b,h,l] = max_s(Q.K_samp) - sum_s(Q.K_samp)/LK
__global__ void msamp_k(const float* __restrict__ Qp, const float* __restrict__ Kp,
                        const int* __restrict__ idx, float* __restrict__ Mout,
                        int LQ, int LK, int U) {
    int t = blockIdx.x * 256 + threadIdx.x;
    int total = 16 * 8 * LQ;
    if (t >= total) return;
    int l = t % LQ;
    int h = (t / LQ) & 7;
    int b = t / (LQ * 8);
    const float* q = Qp + ((size_t)(b * LQ + l) * 512 + h * 64);
    const float* kb = Kp + ((size_t)b * LK * 512 + h * 64);
    float qr[64];
    #pragma unroll
    for (int d = 0; d < 64; d++) qr[d] = q[d];
    float mx = -INFINITY, sm = 0.f;
    for (int s = 0; s < U; s++) {
        const float* kr = kb + (size_t)idx[l * U + s] * 512;
        float acc = 0.f;
        #pragma unroll
        for (int d = 0; d < 64; d++) acc += qr[d] * kr[d];
        mx = fmaxf(mx, acc);
        sm += acc;
    }
    Mout[(size_t)((b * 8) + h) * LQ + l] = mx - sm / (float)LK;
}

// top-u selection per (b,h), stable (ties -> lowest index), like lax.top_k
__global__ void topk_k(const float* __restrict__ M, int* __restrict__ top, int LQ, int u) {
    int t = blockIdx.x * 64 + threadIdx.x;
    if (t >= 128) return;
    const float* m = M + (size_t)t * LQ;
    unsigned long long chosen[8] = {0, 0, 0, 0, 0, 0, 0, 0};
    for (int j = 0; j < u; j++) {
        float best = -INFINITY;
        int bi = 0;
        for (int l = 0; l < LQ; l++) {
            if ((chosen[l >> 6] >> (l & 63)) & 1ull) continue;
            float v = m[l];
            if (v > best) { best = v; bi = l; }
        }
        chosen[bi >> 6] |= 1ull << (bi & 63);
        top[t * u + j] = bi;
    }
}

// vm[b, c] = mean over l of V[b,l,c]  (c = h*64+d)
__global__ void vmean_k(const float* __restrict__ Vp, float* __restrict__ vm, int LK) {
    int t = blockIdx.x * 256 + threadIdx.x;
    if (t >= 16 * 512) return;
    int c = t % 512;
    int b = t / 512;
    float s = 0.f;
    for (int l = 0; l < LK; l++) s += Vp[(size_t)(b * LK + l) * 512 + c];
    vm[t] = s / (float)LK;
}

// ctx[b,l,c] = vm[b,c]
__global__ void ctx_fill_k(const float* __restrict__ vm, float* __restrict__ ctx, int LQ, int total) {
    int t = blockIdx.x * 256 + threadIdx.x;
    if (t >= total) return;
    int c = t % 512;
    int b = t / (512 * LQ);
    ctx[t] = vm[b * 512 + c];
}

// full softmax-attention for one selected row l = top[b,h,uu]
__global__ __launch_bounds__(256) void attn_rows_k(
    const float* __restrict__ Qp, const float* __restrict__ Kp, const float* __restrict__ Vp,
    const int* __restrict__ top, float* __restrict__ ctx, int LQ, int LK, int u) {
    __shared__ float sc[512];
    __shared__ float red[256];
    __shared__ float qs[64];
    int bid = blockIdx.x;
    int uu = bid % u;
    int h = (bid / u) & 7;
    int b = bid / (u * 8);
    int l = top[((b * 8) + h) * u + uu];
    int tid = threadIdx.x;
    const float* q = Qp + ((size_t)(b * LQ + l) * 512 + h * 64);
    const float* kb = Kp + ((size_t)b * LK * 512 + h * 64);
    if (tid < 64) qs[tid] = q[tid];
    __syncthreads();
    for (int k = tid; k < LK; k += 256) {
        const float* kr = kb + (size_t)k * 512;
        float acc = 0.f;
        #pragma unroll
        for (int d = 0; d < 64; d++) acc += qs[d] * kr[d];
        sc[k] = acc * 0.125f;  // 1/sqrt(64)
    }
    __syncthreads();
    float lm = -INFINITY;
    for (int k = tid; k < LK; k += 256) lm = fmaxf(lm, sc[k]);
    red[tid] = lm;
    __syncthreads();
    for (int s = 128; s > 0; s >>= 1) {
        if (tid < s) red[tid] = fmaxf(red[tid], red[tid + s]);
        __syncthreads();
    }
    float mx = red[0];
    __syncthreads();
    float ls = 0.f;
    for (int k = tid; k < LK; k += 256) {
        float e = expf(sc[k] - mx);
        sc[k] = e;
        ls += e;
    }
    red[tid] = ls;
    __syncthreads();
    for (int s = 128; s > 0; s >>= 1) {
        if (tid < s) red[tid] += red[tid + s];
        __syncthreads();
    }
    float denom = red[0];
    __syncthreads();
    if (tid < 64) {
        int d = tid;
        const float* vb = Vp + ((size_t)b * LK * 512 + h * 64 + d);
        float acc = 0.f;
        for (int k = 0; k < LK; k++) acc += sc[k] * vb[(size_t)k * 512];
        ctx[(size_t)(b * LQ + l) * 512 + h * 64 + d] = acc / denom;
    }
}

// per-row layer norm, D=512
__global__ __launch_bounds__(256) void ln_k(const float* __restrict__ in, float* __restrict__ out) {
    __shared__ float red[256];
    int r = blockIdx.x;
    int tid = threadIdx.x;
    const float* x = in + (size_t)r * 512;
    float a = x[tid], b = x[tid + 256];
    red[tid] = a + b;
    __syncthreads();
    for (int s = 128; s > 0; s >>= 1) {
        if (tid < s) red[tid] += red[tid + s];
        __syncthreads();
    }
    float mu = red[0] / 512.f;
    __syncthreads();
    float d1 = a - mu, d2 = b - mu;
    red[tid] = d1 * d1 + d2 * d2;
    __syncthreads();
    for (int s = 128; s > 0; s >>= 1) {
        if (tid < s) red[tid] += red[tid + s];
        __syncthreads();
    }
    float inv = 1.0f / sqrtf(red[0] / 512.f + 1e-5f);
    out[(size_t)r * 512 + tid] = d1 * inv;
    out[(size_t)r * 512 + tid + 256] = d2 * inv;
}

// circular-pad im2col: xc[(b*L+t)*1536 + h*512 + i] = x[b, (t+h-1) mod L, i]
__global__ void xcat_k(const float* __restrict__ x, float* __restrict__ xc, int L, int total) {
    int t = blockIdx.x * 256 + threadIdx.x;
    if (t >= total) return;
    int i = t % 512;
    int h = (t / 512) % 3;
    int bt = t / 1536;
    int tt = bt % L;
    int b = bt / L;
    int src = (tt + h - 1 + L) % L;
    xc[t] = x[(size_t)(b * L + src) * 512 + i];
}

// per-channel mean/var over all rows (batch-style stats over (B, L))
__global__ __launch_bounds__(256) void bnstats_k(const float* __restrict__ y,
                                                 float* __restrict__ mu, float* __restrict__ var,
                                                 int rows) {
    __shared__ float red[256];
    int o = blockIdx.x;
    int tid = threadIdx.x;
    float s = 0.f;
    for (int r = tid; r < rows; r += 256) s += y[(size_t)r * 512 + o];
    red[tid] = s;
    __syncthreads();
    for (int st = 128; st > 0; st >>= 1) {
        if (tid < st) red[tid] += red[tid + st];
        __syncthreads();
    }
    float m = red[0] / (float)rows;
    __syncthreads();
    float s2 = 0.f;
    for (int r = tid; r < rows; r += 256) {
        float d = y[(size_t)r * 512 + o] - m;
        s2 += d * d;
    }
    red[tid] = s2;
    __syncthreads();
    for (int st = 128; st > 0; st >>= 1) {
        if (tid < st) red[tid] += red[tid + st];
        __syncthreads();
    }
    if (tid == 0) {
        mu[o] = m;
        var[o] = red[0] / (float)rows;
    }
}

// normalize -> (max-pool window 3 stride 2 pad 1) -> elu (elu monotone, so pool first)
__global__ void elu_pool_k(const float* __restrict__ y, const float* __restrict__ mu,
                           const float* __restrict__ var, float* __restrict__ out,
                           int L, int total) {
    int t = blockIdx.x * 256 + threadIdx.x;
    if (t >= total) return;
    int o = t % 512;
    int tp = (t / 512) % (L / 2);
    int b = t / (512 * (L / 2));
    float mm = mu[o];
    float inv = 1.0f / sqrtf(var[o] + 1e-5f);
    float m = -INFINITY;
    #pragma unroll
    for (int dt = 0; dt < 3; dt++) {
        int tt = 2 * tp - 1 + dt;
        if (tt < 0 || tt >= L) continue;
        float v = (y[(size_t)(b * L + tt) * 512 + o] - mm) * inv;
        m = fmaxf(m, v);
    }
    out[t] = m > 0.f ? m : expm1f(m);
}

// out[r] = dot(x[r,:512], w) + b   (one wave per row)
__global__ void final_k(const float* __restrict__ x, const float* __restrict__ w,
                        const float* __restrict__ bb, float* __restrict__ out, int rows) {
    int gid = blockIdx.x * 256 + threadIdx.x;
    int wid = gid >> 6;
    int lane = gid & 63;
    if (wid >= rows) return;
    const float* xr = x + (size_t)wid * 512;
    float acc = 0.f;
    for (int k = lane; k < 512; k += 64) acc += xr[k] * w[k];
    for (int off = 32; off > 0; off >>= 1) acc += __shfl_down(acc, off);
    if (lane == 0) out[wid] = acc + bb[0];
}

// ---------------------------------------------------------------------------
// Host driver
// ---------------------------------------------------------------------------

static inline int iceil_log(int L) { return (int)ceil(log((double)L)); }
static inline int imin(int a, int b) { return a < b ? a : b; }

extern "C" void kernel_launch(void* const* d_in, const int* in_sizes, int n_in,
                              void* d_out, int out_size, void* d_ws, size_t ws_size,
                              hipStream_t stream) {
    const float* IN  = (const float*)d_in[0];
    const float* Wq  = (const float*)d_in[1];
    const float* bq  = (const float*)d_in[2];
    const float* Wk  = (const float*)d_in[3];
    const float* bk  = (const float*)d_in[4];
    const float* Wv  = (const float*)d_in[5];
    const float* bv  = (const float*)d_in[6];
    const float* Wo  = (const float*)d_in[7];
    const float* bo  = (const float*)d_in[8];
    const float* ew1 = (const float*)d_in[9];
    const float* eb1 = (const float*)d_in[10];
    const float* ew2 = (const float*)d_in[11];
    const float* eb2 = (const float*)d_in[12];
    const float* dw1 = (const float*)d_in[13];
    const float* db1 = (const float*)d_in[14];
    const float* dw2 = (const float*)d_in[15];
    const float* db2 = (const float*)d_in[16];
    const float* DW  = (const float*)d_in[17];
    const float* db  = (const float*)d_in[18];
    const float* ow  = (const float*)d_in[19];
    const float* ob  = (const float*)d_in[20];
    float* OUT = (float*)d_out;

    float* ws = (float*)d_ws;
    size_t off = 0;
    auto alloc = [&](size_t n) { float* p = ws + off; off += n; return p; };
    float* PE   = alloc(4194304);
    float* Qb   = alloc(4194304);
    float* Kb   = alloc(4194304);
    float* Vb   = alloc(4194304);
    float* CTX  = alloc(4194304);   // also conv output buffer
    float* T1   = alloc(4194304);
    float* XLN  = alloc(4194304);
    float* T2   = alloc(4194304);
    float* T3   = alloc(4194304);
    float* HID  = alloc(16777216);  // FFN hidden; also im2col buffer
    float* D1   = alloc(2097152);
    float* D2   = alloc(1048576);
    float* Eb   = alloc(524288);
    float* W2   = alloc(786432);
    float* MB   = alloc(65536);
    float* VM   = alloc(8192);
    float* MU   = alloc(512);
    float* VARb = alloc(512);
    int* IDX  = (int*)alloc(17920);
    int* TOPB = (int*)alloc(4480);
    (void)ws_size; (void)n_in; (void)in_sizes; (void)out_size;

    auto gemm = [&](const float* A, const float* B, const float* bias, const float* res,
                    float* C, int M, int N, int K, int relu) {
        dim3 g(N / 64, M / 64);
        gemm_k<<<g, 256, 0, stream>>>(A, B, bias, res, C, M, N, K, relu);
    };

    // ProbSparse attention; writes outp = ctx @ Wo + bo + resp
    auto attn = [&](const float* qin, const float* kvin, const float* resp, float* outp,
                    int LQ, int LK, int ikey) {
        int Mq = 16 * LQ, Mk = 16 * LK;
        gemm(qin, Wq, bq, nullptr, Qb, Mq, 512, 512, 0);
        gemm(kvin, Wk, bk, nullptr, Kb, Mk, 512, 512, 0);
        gemm(kvin, Wv, bv, nullptr, Vb, Mk, 512, 512, 0);
        int U = imin(5 * iceil_log(LK), LK);
        int u = imin(5 * iceil_log(LQ), LQ);
        unsigned rk0, rk1;
        threefry2x32(0u, 42u, 0u, (unsigned)ikey, rk0, rk1);  // fold_in(key(42), ikey)
        int size = LQ * U;
        ridx_k<<<(size + 255) / 256, 256, 0, stream>>>(rk0, rk1, size, (unsigned)(LK - 1), IDX);
        int totM = 16 * 8 * LQ;
        msamp_k<<<(totM + 255) / 256, 256, 0, stream>>>(Qb, Kb, IDX, MB, LQ, LK, U);
        topk_k<<<2, 64, 0, stream>>>(MB, TOPB, LQ, u);
        vmean_k<<<(16 * 512 + 255) / 256, 256, 0, stream>>>(Vb, VM, LK);
        int totC = 16 * LQ * 512;
        ctx_fill_k<<<(totC + 255) / 256, 256, 0, stream>>>(VM, CTX, LQ, totC);
        attn_rows_k<<<16 * 8 * u, 256, 0, stream>>>(Qb, Kb, Vb, TOPB, CTX, LQ, LK, u);
        gemm(CTX, Wo, bo, resp, outp, Mq, 512, 512, 0);
    };

    auto encoder = [&](const float* X, int L, int ikey, float* OUTenc) {
        int M = 16 * L;
        attn(X, X, X, T1, L, L, ikey);          // T1 = X + attn(X)
        ln_k<<<M, 256, 0, stream>>>(T1, XLN);   // XLN = LN(T1)
        gemm(XLN, ew1, eb1, nullptr, HID, M, 2048, 512, 1);
        gemm(HID, ew2, eb2, XLN, T2, M, 512, 2048, 0);  // T2 = XLN + FFN
        ln_k<<<M, 256, 0, stream>>>(T2, OUTenc);
    };

    auto distill = [&](const float* X, int L, float* OUTd) {
        int M = 16 * L;
        int tot = M * 1536;
        xcat_k<<<(tot + 255) / 256, 256, 0, stream>>>(X, HID, L, tot);
        gemm(HID, W2, db, nullptr, CTX, M, 512, 1536, 0);
        bnstats_k<<<512, 256, 0, stream>>>(CTX, MU, VARb, M);
        int toto = 16 * (L / 2) * 512;
        elu_pool_k<<<(toto + 255) / 256, 256, 0, stream>>>(CTX, MU, VARb, OUTd, L, toto);
    };

    // --- forward ---
    int totPE = 16 * 512 * 512;
    pe_add_k<<<(totPE + 255) / 256, 256, 0, stream>>>(IN, PE, totPE);
    rearr_w2_k<<<(786432 + 255) / 256, 256, 0, stream>>>(DW, W2, 786432);

    encoder(PE, 512, 0, T3); distill(T3, 512, D1);
    encoder(D1, 256, 1, T3); distill(T3, 256, D2);
    encoder(D2, 128, 2, T3); distill(T3, 128, Eb);

    attn(PE, PE, PE, T1, 512, 512, 3);   // out1 = dec_inp + attn(dec_inp)
    attn(T1, Eb, T1, T2, 512, 64, 4);    // out2 = out1 + attn(out1, e, e)
    gemm(T2, dw1, db1, nullptr, HID, 8192, 2048, 512, 1);
    gemm(HID, dw2, db2, T2, T3, 8192, 512, 2048, 0);  // out3 = out2 + FFN(out2)
    final_k<<<(8192 * 64) / 256, 256, 0, stream>>>(T3, ow, ob, OUT, 8192);
}

// Round 2
// 5931.540 us; speedup vs baseline: 2.4489x; 2.4489x over previous
//
#include <hip/hip_runtime.h>
#include <cstdint>
#include <cmath>

// ---------------------------------------------------------------------------
// Informer forward, fp32. Round 2: parallel top-k (R1's 83%-of-runtime fix).
// B=16, LEN_SEQ=512, D_MODEL=512, N_HEAD=8 (D_HEAD=64), FACTOR=5, D_FF=2048.
// jax.random reproduced exactly via threefry2x32 (H2 stream layout, verified
// R1: absmax 9.8e-3 passed).
// ---------------------------------------------------------------------------

#define HD __host__ __device__

HD inline unsigned rotl32(unsigned x, int r) { return (x << r) | (x >> (32 - r)); }
HD inline void tfround(unsigned& x0, unsigned& x1, int r) {
    x0 += x1; x1 = rotl32(x1, r); x1 ^= x0;
}
HD inline void threefry2x32(unsigned k0, unsigned k1, unsigned c0, unsigned c1,
                            unsigned& o0, unsigned& o1) {
    unsigned ks2 = k0 ^ k1 ^ 0x1BD11BDAu;
    unsigned x0 = c0 + k0, x1 = c1 + k1;
    tfround(x0, x1, 13); tfround(x0, x1, 15); tfround(x0, x1, 26); tfround(x0, x1, 6);
    x0 += k1; x1 += ks2 + 1u;
    tfround(x0, x1, 17); tfround(x0, x1, 29); tfround(x0, x1, 16); tfround(x0, x1, 24);
    x0 += ks2; x1 += k0 + 2u;
    tfround(x0, x1, 13); tfround(x0, x1, 15); tfround(x0, x1, 26); tfround(x0, x1, 6);
    x0 += k0; x1 += k1 + 3u;
    tfround(x0, x1, 17); tfround(x0, x1, 29); tfround(x0, x1, 16); tfround(x0, x1, 24);
    x0 += k1; x1 += ks2 + 4u;
    tfround(x0, x1, 13); tfround(x0, x1, 15); tfround(x0, x1, 26); tfround(x0, x1, 6);
    x0 += ks2; x1 += k0 + 5u;
    o0 = x0; o1 = x1;
}

// ---------------------------------------------------------------------------
// Kernels
// ---------------------------------------------------------------------------

__global__ void pe_add_k(const float* __restrict__ in, float* __restrict__ out, int total) {
    int t = blockIdx.x * 256 + threadIdx.x;
    if (t >= total) return;
    int d = t % 512;
    int l = (t / 512) % 512;
    float i2 = (float)(d & ~1);
    float div = expf(i2 * (-0.017988946039016f));  // -ln(10000)/512
    float ang = (float)l * div;
    float v = (d & 1) ? cosf(ang) : sinf(ang);
    out[t] = in[t] + v;
}

// rearrange dist_w (O,I,H) -> W2[(h*512+i)*512 + o]
__global__ void rearr_w2_k(const float* __restrict__ dw, float* __restrict__ w2, int total) {
    int t = blockIdx.x * 256 + threadIdx.x;
    if (t >= total) return;
    int o = t % 512;
    int rest = t / 512;
    int i = rest % 512;
    int h = rest / 512;
    w2[t] = dw[(size_t)o * 1536 + i * 3 + h];
}

// Generic fp32 GEMM: C[M,N] = A[M,K] @ B[K,N] (+bias) (+relu) (+res)
__global__ __launch_bounds__(256) void gemm_k(
    const float* __restrict__ A, const float* __restrict__ B,
    const float* __restrict__ bias, const float* __restrict__ res,
    float* __restrict__ C, int M, int N, int K, int relu) {
    __shared__ float As[16][65];
    __shared__ float Bs[16][65];
    int tx = threadIdx.x & 15;
    int ty = threadIdx.x >> 4;
    int bm = blockIdx.y * 64;
    int bn = blockIdx.x * 64;
    float acc[4][4] = {};
    for (int k0 = 0; k0 < K; k0 += 16) {
        #pragma unroll
        for (int i = 0; i < 4; i++) {
            int lin = threadIdx.x + 256 * i;
            int m = lin >> 4, kk = lin & 15;
            As[kk][m] = A[(size_t)(bm + m) * K + k0 + kk];
            int kk2 = lin >> 6, n = lin & 63;
            Bs[kk2][n] = B[(size_t)(k0 + kk2) * N + bn + n];
        }
        __syncthreads();
        #pragma unroll
        for (int kk = 0; kk < 16; kk++) {
            float a[4], b[4];
            #pragma unroll
            for (int i = 0; i < 4; i++) a[i] = As[kk][ty * 4 + i];
            #pragma unroll
            for (int j = 0; j < 4; j++) b[j] = Bs[kk][tx * 4 + j];
            #pragma unroll
            for (int i = 0; i < 4; i++)
                #pragma unroll
                for (int j = 0; j < 4; j++) acc[i][j] += a[i] * b[j];
        }
        __syncthreads();
    }
    #pragma unroll
    for (int i = 0; i < 4; i++) {
        int m = bm + ty * 4 + i;
        #pragma unroll
        for (int j = 0; j < 4; j++) {
            int n = bn + tx * 4 + j;
            float v = acc[i][j];
            if (bias) v += bias[n];
            if (relu) v = fmaxf(v, 0.f);
            if (res) v += res[(size_t)m * N + n];
            C[(size_t)m * N + n] = v;
        }
    }
}

// idx[j] = threefry(rkey, (j, j+size)).second & mask   (H2, verified R1)
__global__ void ridx_k(unsigned k0, unsigned k1, int size, unsigned mask, int* __restrict__ idx) {
    int j = blockIdx.x * 256 + threadIdx.x;
    if (j >= size) return;
    unsigned o0, o1;
    threefry2x32(k0, k1, (unsigned)j, (unsigned)(j + size), o0, o1);
    idx[j] = (int)(o1 & mask);
}

// M[b,h,l] = max_s(Q.K_samp) - sum_s(Q.K_samp)/LK
__global__ void msamp_k(const float* __restrict__ Qp, const float* __restrict__ Kp,
                        const int* __restrict__ idx, float* __restrict__ Mout,
                        int LQ, int LK, int U) {
    int t = blockIdx.x * 256 + threadIdx.x;
    int total = 16 * 8 * LQ;
    if (t >= total) return;
    int l = t % LQ;
    int h = (t / LQ) & 7;
    int b = t / (LQ * 8);
    const float* q = Qp + ((size_t)(b * LQ + l) * 512 + h * 64);
    const float* kb = Kp + ((size_t)b * LK * 512 + h * 64);
    float qr[64];
    #pragma unroll
    for (int d = 0; d < 64; d++) qr[d] = q[d];
    float mx = -INFINITY, sm = 0.f;
    for (int s = 0; s < U; s++) {
        const float* kr = kb + (size_t)idx[l * U + s] * 512;
        float acc = 0.f;
        #pragma unroll
        for (int d = 0; d < 64; d++) acc += qr[d] * kr[d];
        mx = fmaxf(mx, acc);
        sm += acc;
    }
    Mout[(size_t)((b * 8) + h) * LQ + l] = mx - sm / (float)LK;
}

// Parallel top-u per (b,h): one 256-thread block per row. Stage M in LDS,
// u iterative argmax reductions with lowest-index tie-break (== serial scan
// and lax.top_k semantics).
__global__ __launch_bounds__(256) void topk_k(const float* __restrict__ M,
                                              int* __restrict__ top, int LQ, int u) {
    __shared__ float vals[512];
    __shared__ float rv[256];
    __shared__ int ri[256];
    int bh = blockIdx.x;
    int tid = threadIdx.x;
    const float* m = M + (size_t)bh * LQ;
    for (int l = tid; l < LQ; l += 256) vals[l] = m[l];
    __syncthreads();
    for (int j = 0; j < u; j++) {
        float best = -INFINITY;
        int bi = LQ;
        for (int l = tid; l < LQ; l += 256) {
            float v = vals[l];
            if (v > best) { best = v; bi = l; }  // ascending l per thread: keeps lowest idx on ties
        }
        rv[tid] = best; ri[tid] = bi;
        __syncthreads();
        for (int s = 128; s > 0; s >>= 1) {
            if (tid < s) {
                float v2 = rv[tid + s]; int i2 = ri[tid + s];
                if (v2 > rv[tid] || (v2 == rv[tid] && i2 < ri[tid])) { rv[tid] = v2; ri[tid] = i2; }
            }
            __syncthreads();
        }
        int sel = ri[0];
        if (tid == 0) {
            top[bh * u + j] = sel;
            vals[sel] = -INFINITY;
        }
        __syncthreads();
    }
}

// vm[b, c] = mean over l of V[b,l,c]
__global__ void vmean_k(const float* __restrict__ Vp, float* __restrict__ vm, int LK) {
    int t = blockIdx.x * 256 + threadIdx.x;
    if (t >= 16 * 512) return;
    int c = t % 512;
    int b = t / 512;
    float s = 0.f;
    for (int l = 0; l < LK; l++) s += Vp[(size_t)(b * LK + l) * 512 + c];
    vm[t] = s / (float)LK;
}

// ctx[b,l,c] = vm[b,c]
__global__ void ctx_fill_k(const float* __restrict__ vm, float* __restrict__ ctx, int LQ, int total) {
    int t = blockIdx.x * 256 + threadIdx.x;
    if (t >= total) return;
    int c = t % 512;
    int b = t / (512 * LQ);
    ctx[t] = vm[b * 512 + c];
}

// full softmax-attention for one selected row l = top[b,h,uu]
__global__ __launch_bounds__(256) void attn_rows_k(
    const float* __restrict__ Qp, const float* __restrict__ Kp, const float* __restrict__ Vp,
    const int* __restrict__ top, float* __restrict__ ctx, int LQ, int LK, int u) {
    __shared__ float sc[512];
    __shared__ float red[256];
    __shared__ float qs[64];
    int bid = blockIdx.x;
    int uu = bid % u;
    int h = (bid / u) & 7;
    int b = bid / (u * 8);
    int l = top[((b * 8) + h) * u + uu];
    int tid = threadIdx.x;
    const float* q = Qp + ((size_t)(b * LQ + l) * 512 + h * 64);
    const float* kb = Kp + ((size_t)b * LK * 512 + h * 64);
    if (tid < 64) qs[tid] = q[tid];
    __syncthreads();
    for (int k = tid; k < LK; k += 256) {
        const float* kr = kb + (size_t)k * 512;
        float acc = 0.f;
        #pragma unroll
        for (int d = 0; d < 64; d++) acc += qs[d] * kr[d];
        sc[k] = acc * 0.125f;  // 1/sqrt(64)
    }
    __syncthreads();
    float lm = -INFINITY;
    for (int k = tid; k < LK; k += 256) lm = fmaxf(lm, sc[k]);
    red[tid] = lm;
    __syncthreads();
    for (int s = 128; s > 0; s >>= 1) {
        if (tid < s) red[tid] = fmaxf(red[tid], red[tid + s]);
        __syncthreads();
    }
    float mx = red[0];
    __syncthreads();
    float ls = 0.f;
    for (int k = tid; k < LK; k += 256) {
        float e = expf(sc[k] - mx);
        sc[k] = e;
        ls += e;
    }
    red[tid] = ls;
    __syncthreads();
    for (int s = 128; s > 0; s >>= 1) {
        if (tid < s) red[tid] += red[tid + s];
        __syncthreads();
    }
    float denom = red[0];
    __syncthreads();
    if (tid < 64) {
        int d = tid;
        const float* vb = Vp + ((size_t)b * LK * 512 + h * 64 + d);
        float acc = 0.f;
        for (int k = 0; k < LK; k++) acc += sc[k] * vb[(size_t)k * 512];
        ctx[(size_t)(b * LQ + l) * 512 + h * 64 + d] = acc / denom;
    }
}

// per-row layer norm, D=512
__global__ __launch_bounds__(256) void ln_k(const float* __restrict__ in, float* __restrict__ out) {
    __shared__ float red[256];
    int r = blockIdx.x;
    int tid = threadIdx.x;
    const float* x = in + (size_t)r * 512;
    float a = x[tid], b = x[tid + 256];
    red[tid] = a + b;
    __syncthreads();
    for (int s = 128; s > 0; s >>= 1) {
        if (tid < s) red[tid] += red[tid + s];
        __syncthreads();
    }
    float mu = red[0] / 512.f;
    __syncthreads();
    float d1 = a - mu, d2 = b - mu;
    red[tid] = d1 * d1 + d2 * d2;
    __syncthreads();
    for (int s = 128; s > 0; s >>= 1) {
        if (tid < s) red[tid] += red[tid + s];
        __syncthreads();
    }
    float inv = 1.0f / sqrtf(red[0] / 512.f + 1e-5f);
    out[(size_t)r * 512 + tid] = d1 * inv;
    out[(size_t)r * 512 + tid + 256] = d2 * inv;
}

// circular-pad im2col: xc[(b*L+t)*1536 + h*512 + i] = x[b, (t+h-1) mod L, i]
__global__ void xcat_k(const float* __restrict__ x, float* __restrict__ xc, int L, int total) {
    int t = blockIdx.x * 256 + threadIdx.x;
    if (t >= total) return;
    int i = t % 512;
    int h = (t / 512) % 3;
    int bt = t / 1536;
    int tt = bt % L;
    int b = bt / L;
    int src = (tt + h - 1 + L) % L;
    xc[t] = x[(size_t)(b * L + src) * 512 + i];
}

// per-channel mean/var over all rows
__global__ __launch_bounds__(256) void bnstats_k(const float* __restrict__ y,
                                                 float* __restrict__ mu, float* __restrict__ var,
                                                 int rows) {
    __shared__ float red[256];
    int o = blockIdx.x;
    int tid = threadIdx.x;
    float s = 0.f;
    for (int r = tid; r < rows; r += 256) s += y[(size_t)r * 512 + o];
    red[tid] = s;
    __syncthreads();
    for (int st = 128; st > 0; st >>= 1) {
        if (tid < st) red[tid] += red[tid + st];
        __syncthreads();
    }
    float m = red[0] / (float)rows;
    __syncthreads();
    float s2 = 0.f;
    for (int r = tid; r < rows; r += 256) {
        float d = y[(size_t)r * 512 + o] - m;
        s2 += d * d;
    }
    red[tid] = s2;
    __syncthreads();
    for (int st = 128; st > 0; st >>= 1) {
        if (tid < st) red[tid] += red[tid + st];
        __syncthreads();
    }
    if (tid == 0) {
        mu[o] = m;
        var[o] = red[0] / (float)rows;
    }
}

// normalize -> max-pool(3,2,pad1) -> elu (monotone, pool first)
__global__ void elu_pool_k(const float* __restrict__ y, const float* __restrict__ mu,
                           const float* __restrict__ var, float* __restrict__ out,
                           int L, int total) {
    int t = blockIdx.x * 256 + threadIdx.x;
    if (t >= total) return;
    int o = t % 512;
    int tp = (t / 512) % (L / 2);
    int b = t / (512 * (L / 2));
    float mm = mu[o];
    float inv = 1.0f / sqrtf(var[o] + 1e-5f);
    float m = -INFINITY;
    #pragma unroll
    for (int dt = 0; dt < 3; dt++) {
        int tt = 2 * tp - 1 + dt;
        if (tt < 0 || tt >= L) continue;
        float v = (y[(size_t)(b * L + tt) * 512 + o] - mm) * inv;
        m = fmaxf(m, v);
    }
    out[t] = m > 0.f ? m : expm1f(m);
}

// out[r] = dot(x[r,:512], w) + b
__global__ void final_k(const float* __restrict__ x, const float* __restrict__ w,
                        const float* __restrict__ bb, float* __restrict__ out, int rows) {
    int gid = blockIdx.x * 256 + threadIdx.x;
    int wid = gid >> 6;
    int lane = gid & 63;
    if (wid >= rows) return;
    const float* xr = x + (size_t)wid * 512;
    float acc = 0.f;
    for (int k = lane; k < 512; k += 64) acc += xr[k] * w[k];
    for (int off = 32; off > 0; off >>= 1) acc += __shfl_down(acc, off);
    if (lane == 0) out[wid] = acc + bb[0];
}

// ---------------------------------------------------------------------------
// Host driver
// ---------------------------------------------------------------------------

static inline int iceil_log(int L) { return (int)ceil(log((double)L)); }
static inline int imin(int a, int b) { return a < b ? a : b; }

extern "C" void kernel_launch(void* const* d_in, const int* in_sizes, int n_in,
                              void* d_out, int out_size, void* d_ws, size_t ws_size,
                              hipStream_t stream) {
    const float* IN  = (const float*)d_in[0];
    const float* Wq  = (const float*)d_in[1];
    const float* bq  = (const float*)d_in[2];
    const float* Wk  = (const float*)d_in[3];
    const float* bk  = (const float*)d_in[4];
    const float* Wv  = (const float*)d_in[5];
    const float* bv  = (const float*)d_in[6];
    const float* Wo  = (const float*)d_in[7];
    const float* bo  = (const float*)d_in[8];
    const float* ew1 = (const float*)d_in[9];
    const float* eb1 = (const float*)d_in[10];
    const float* ew2 = (const float*)d_in[11];
    const float* eb2 = (const float*)d_in[12];
    const float* dw1 = (const float*)d_in[13];
    const float* db1 = (const float*)d_in[14];
    const float* dw2 = (const float*)d_in[15];
    const float* db2 = (const float*)d_in[16];
    const float* DW  = (const float*)d_in[17];
    const float* db  = (const float*)d_in[18];
    const float* ow  = (const float*)d_in[19];
    const float* ob  = (const float*)d_in[20];
    float* OUT = (float*)d_out;

    float* ws = (float*)d_ws;
    size_t off = 0;
    auto alloc = [&](size_t n) { float* p = ws + off; off += n; return p; };
    float* PE   = alloc(4194304);
    float* Qb   = alloc(4194304);
    float* Kb   = alloc(4194304);
    float* Vb   = alloc(4194304);
    float* CTX  = alloc(4194304);
    float* T1   = alloc(4194304);
    float* XLN  = alloc(4194304);
    float* T2   = alloc(4194304);
    float* T3   = alloc(4194304);
    float* HID  = alloc(16777216);
    float* D1   = alloc(2097152);
    float* D2   = alloc(1048576);
    float* Eb   = alloc(524288);
    float* W2   = alloc(786432);
    float* MB   = alloc(65536);
    float* VM   = alloc(8192);
    float* MU   = alloc(512);
    float* VARb = alloc(512);
    int* IDX  = (int*)alloc(17920);
    int* TOPB = (int*)alloc(4480);
    (void)ws_size; (void)n_in; (void)in_sizes; (void)out_size;

    auto gemm = [&](const float* A, const float* B, const float* bias, const float* res,
                    float* C, int M, int N, int K, int relu) {
        dim3 g(N / 64, M / 64);
        gemm_k<<<g, 256, 0, stream>>>(A, B, bias, res, C, M, N, K, relu);
    };

    auto attn = [&](const float* qin, const float* kvin, const float* resp, float* outp,
                    int LQ, int LK, int ikey) {
        int Mq = 16 * LQ, Mk = 16 * LK;
        gemm(qin, Wq, bq, nullptr, Qb, Mq, 512, 512, 0);
        gemm(kvin, Wk, bk, nullptr, Kb, Mk, 512, 512, 0);
        gemm(kvin, Wv, bv, nullptr, Vb, Mk, 512, 512, 0);
        int U = imin(5 * iceil_log(LK), LK);
        int u = imin(5 * iceil_log(LQ), LQ);
        unsigned rk0, rk1;
        threefry2x32(0u, 42u, 0u, (unsigned)ikey, rk0, rk1);
        int size = LQ * U;
        ridx_k<<<(size + 255) / 256, 256, 0, stream>>>(rk0, rk1, size, (unsigned)(LK - 1), IDX);
        int totM = 16 * 8 * LQ;
        msamp_k<<<(totM + 255) / 256, 256, 0, stream>>>(Qb, Kb, IDX, MB, LQ, LK, U);
        topk_k<<<128, 256, 0, stream>>>(MB, TOPB, LQ, u);
        vmean_k<<<(16 * 512 + 255) / 256, 256, 0, stream>>>(Vb, VM, LK);
        int totC = 16 * LQ * 512;
        ctx_fill_k<<<(totC + 255) / 256, 256, 0, stream>>>(VM, CTX, LQ, totC);
        attn_rows_k<<<16 * 8 * u, 256, 0, stream>>>(Qb, Kb, Vb, TOPB, CTX, LQ, LK, u);
        gemm(CTX, Wo, bo, resp, outp, Mq, 512, 512, 0);
    };

    auto encoder = [&](const float* X, int L, int ikey, float* OUTenc) {
        int M = 16 * L;
        attn(X, X, X, T1, L, L, ikey);
        ln_k<<<M, 256, 0, stream>>>(T1, XLN);
        gemm(XLN, ew1, eb1, nullptr, HID, M, 2048, 512, 1);
        gemm(HID, ew2, eb2, XLN, T2, M, 512, 2048, 0);
        ln_k<<<M, 256, 0, stream>>>(T2, OUTenc);
    };

    auto distill = [&](const float* X, int L, float* OUTd) {
        int M = 16 * L;
        int tot = M * 1536;
        xcat_k<<<(tot + 255) / 256, 256, 0, stream>>>(X, HID, L, tot);
        gemm(HID, W2, db, nullptr, CTX, M, 512, 1536, 0);
        bnstats_k<<<512, 256, 0, stream>>>(CTX, MU, VARb, M);
        int toto = 16 * (L / 2) * 512;
        elu_pool_k<<<(toto + 255) / 256, 256, 0, stream>>>(CTX, MU, VARb, OUTd, L, toto);
    };

    // --- forward ---
    int totPE = 16 * 512 * 512;
    pe_add_k<<<(totPE + 255) / 256, 256, 0, stream>>>(IN, PE, totPE);
    rearr_w2_k<<<(786432 + 255) / 256, 256, 0, stream>>>(DW, W2, 786432);

    encoder(PE, 512, 0, T3); distill(T3, 512, D1);
    encoder(D1, 256, 1, T3); distill(T3, 256, D2);
    encoder(D2, 128, 2, T3); distill(T3, 128, Eb);

    attn(PE, PE, PE, T1, 512, 512, 3);
    attn(T1, Eb, T1, T2, 512, 64, 4);
    gemm(T2, dw1, db1, nullptr, HID, 8192, 2048, 512, 1);
    gemm(HID, dw2, db2, T2, T3, 8192, 512, 2048, 0);
    final_k<<<(8192 * 64) / 256, 256, 0, stream>>>(T3, ow, ob, OUT, 8192);
}

// Round 3
// 3145.063 us; speedup vs baseline: 4.6186x; 1.8860x over previous
//
#include <hip/hip_runtime.h>
#include <cstdint>
#include <cmath>

// ---------------------------------------------------------------------------
// Informer forward. Round 3: all GEMMs -> bf16 MFMA (16x16x32, fp32 acc).
// Weights pre-converted to bf16 [N][K] once per launch; activations converted
// fp32->bf16 in-register during LDS staging. Epilogue keeps bias/relu/res.
// jax.random via threefry2x32 (H2 layout, verified R1). fp32 elsewhere.
// ---------------------------------------------------------------------------

#define HD __host__ __device__

typedef short short8 __attribute__((ext_vector_type(8)));
typedef short short4v __attribute__((ext_vector_type(4)));
typedef float float4v __attribute__((ext_vector_type(4)));

__device__ inline short f2bf(float f) {  // RNE
    unsigned u = __float_as_uint(f);
    unsigned r = u + 0x7FFFu + ((u >> 16) & 1u);
    return (short)(r >> 16);
}

HD inline unsigned rotl32(unsigned x, int r) { return (x << r) | (x >> (32 - r)); }
HD inline void tfround(unsigned& x0, unsigned& x1, int r) {
    x0 += x1; x1 = rotl32(x1, r); x1 ^= x0;
}
HD inline void threefry2x32(unsigned k0, unsigned k1, unsigned c0, unsigned c1,
                            unsigned& o0, unsigned& o1) {
    unsigned ks2 = k0 ^ k1 ^ 0x1BD11BDAu;
    unsigned x0 = c0 + k0, x1 = c1 + k1;
    tfround(x0, x1, 13); tfround(x0, x1, 15); tfround(x0, x1, 26); tfround(x0, x1, 6);
    x0 += k1; x1 += ks2 + 1u;
    tfround(x0, x1, 17); tfround(x0, x1, 29); tfround(x0, x1, 16); tfround(x0, x1, 24);
    x0 += ks2; x1 += k0 + 2u;
    tfround(x0, x1, 13); tfround(x0, x1, 15); tfround(x0, x1, 26); tfround(x0, x1, 6);
    x0 += k0; x1 += k1 + 3u;
    tfround(x0, x1, 17); tfround(x0, x1, 29); tfround(x0, x1, 16); tfround(x0, x1, 24);
    x0 += k1; x1 += ks2 + 4u;
    tfround(x0, x1, 13); tfround(x0, x1, 15); tfround(x0, x1, 26); tfround(x0, x1, 6);
    x0 += ks2; x1 += k0 + 5u;
    o0 = x0; o1 = x1;
}

// ---------------------------------------------------------------------------
// Kernels
// ---------------------------------------------------------------------------

__global__ void pe_add_k(const float* __restrict__ in, float* __restrict__ out, int total) {
    int t = blockIdx.x * 256 + threadIdx.x;
    if (t >= total) return;
    int d = t % 512;
    int l = (t / 512) % 512;
    float i2 = (float)(d & ~1);
    float div = expf(i2 * (-0.017988946039016f));  // -ln(10000)/512
    float ang = (float)l * div;
    float v = (d & 1) ? cosf(ang) : sinf(ang);
    out[t] = in[t] + v;
}

// fp32 [K][N] -> bf16 [N][K] via 32x32 LDS tile
__global__ __launch_bounds__(256) void transpose_bf16_k(const float* __restrict__ in,
                                                        short* __restrict__ out, int K, int N) {
    __shared__ float tile[32][33];
    int k0 = blockIdx.y * 32, n0 = blockIdx.x * 32;
    int c = threadIdx.x & 31, r0 = threadIdx.x >> 5;
    for (int rr = r0; rr < 32; rr += 8)
        tile[rr][c] = in[(size_t)(k0 + rr) * N + n0 + c];
    __syncthreads();
    for (int rr = r0; rr < 32; rr += 8)
        out[(size_t)(n0 + rr) * K + k0 + c] = f2bf(tile[c][rr]);
}

// dist_w (O,I,H) -> bf16 W2T[o][h*512+i]
__global__ void w2t_k(const float* __restrict__ dw, short* __restrict__ out, int total) {
    int t = blockIdx.x * 256 + threadIdx.x;
    if (t >= total) return;
    int kk = t % 1536;
    int o = t / 1536;
    int h = kk / 512, i = kk % 512;
    out[t] = f2bf(dw[(size_t)o * 1536 + i * 3 + h]);
}

// bf16 MFMA GEMM: C[M,N] = A[M,K](fp32, converted) @ Bt[N,K](bf16) (+bias)(+relu)(+res)
// Block 128x128, BK=32; 4 waves, each 64x64 via 4x4 tiles of 16x16x32.
__global__ __launch_bounds__(256) void gemm_bf_k(
    const float* __restrict__ A, const short* __restrict__ Bt,
    const float* __restrict__ bias, const float* __restrict__ res,
    float* __restrict__ C, int M, int N, int K, int relu) {
    __shared__ short As[128 * 32];
    __shared__ short Bs[128 * 32];
    int tid = threadIdx.x;
    int wave = tid >> 6, lane = tid & 63;
    int wy = wave >> 1, wx = wave & 1;
    int rl = lane & 15, quad = lane >> 4;
    int bm = blockIdx.y * 128, bn = blockIdx.x * 128;

    float4v acc[4][4];
    #pragma unroll
    for (int i = 0; i < 4; i++)
        #pragma unroll
        for (int j = 0; j < 4; j++) acc[i][j] = (float4v){0.f, 0.f, 0.f, 0.f};

    for (int k0 = 0; k0 < K; k0 += 32) {
        // stage A: 128x32 fp32 -> bf16. 1024 float4s / 256 threads = 4 iters
        #pragma unroll
        for (int it = 0; it < 4; it++) {
            int f = tid + it * 256;
            int row = f >> 3, c4 = f & 7;
            const float4* src = (const float4*)(A + (size_t)(bm + row) * K + k0 + c4 * 4);
            float4 v = *src;
            short4v s = {f2bf(v.x), f2bf(v.y), f2bf(v.z), f2bf(v.w)};
            *(short4v*)&As[row * 32 + c4 * 4] = s;
        }
        // stage B: 128 rows x 32 bf16 from Bt. 512 16B-chunks / 256 threads = 2 iters
        #pragma unroll
        for (int it = 0; it < 2; it++) {
            int c = tid + it * 256;
            int n = c >> 2, seg = c & 3;
            const float4* src = (const float4*)(Bt + (size_t)(bn + n) * K + k0 + seg * 8);
            *(float4*)&Bs[n * 32 + seg * 8] = *src;
        }
        __syncthreads();
        short8 a[4], b[4];
        #pragma unroll
        for (int i = 0; i < 4; i++)
            a[i] = *(const short8*)&As[(wy * 64 + i * 16 + rl) * 32 + quad * 8];
        #pragma unroll
        for (int j = 0; j < 4; j++)
            b[j] = *(const short8*)&Bs[(wx * 64 + j * 16 + rl) * 32 + quad * 8];
        #pragma unroll
        for (int i = 0; i < 4; i++)
            #pragma unroll
            for (int j = 0; j < 4; j++)
                acc[i][j] = __builtin_amdgcn_mfma_f32_16x16x32_bf16(a[i], b[j], acc[i][j], 0, 0, 0);
        __syncthreads();
    }
    // epilogue: C/D layout col=lane&15, row=quad*4+reg
    #pragma unroll
    for (int i = 0; i < 4; i++) {
        #pragma unroll
        for (int r = 0; r < 4; r++) {
            int gm = bm + wy * 64 + i * 16 + quad * 4 + r;
            #pragma unroll
            for (int j = 0; j < 4; j++) {
                int gn = bn + wx * 64 + j * 16 + rl;
                float v = acc[i][j][r];
                if (bias) v += bias[gn];
                if (relu) v = fmaxf(v, 0.f);
                if (res) v += res[(size_t)gm * N + gn];
                C[(size_t)gm * N + gn] = v;
            }
        }
    }
}

// idx[j] = threefry(rkey, (j, j+size)).second & mask   (H2, verified R1)
__global__ void ridx_k(unsigned k0, unsigned k1, int size, unsigned mask, int* __restrict__ idx) {
    int j = blockIdx.x * 256 + threadIdx.x;
    if (j >= size) return;
    unsigned o0, o1;
    threefry2x32(k0, k1, (unsigned)j, (unsigned)(j + size), o0, o1);
    idx[j] = (int)(o1 & mask);
}

// M[b,h,l] = max_s(Q.K_samp) - sum_s(Q.K_samp)/LK
__global__ void msamp_k(const float* __restrict__ Qp, const float* __restrict__ Kp,
                        const int* __restrict__ idx, float* __restrict__ Mout,
                        int LQ, int LK, int U) {
    int t = blockIdx.x * 256 + threadIdx.x;
    int total = 16 * 8 * LQ;
    if (t >= total) return;
    int l = t % LQ;
    int h = (t / LQ) & 7;
    int b = t / (LQ * 8);
    const float* q = Qp + ((size_t)(b * LQ + l) * 512 + h * 64);
    const float* kb = Kp + ((size_t)b * LK * 512 + h * 64);
    float qr[64];
    #pragma unroll
    for (int d = 0; d < 64; d++) qr[d] = q[d];
    float mx = -INFINITY, sm = 0.f;
    for (int s = 0; s < U; s++) {
        const float* kr = kb + (size_t)idx[l * U + s] * 512;
        float acc = 0.f;
        #pragma unroll
        for (int d = 0; d < 64; d++) acc += qr[d] * kr[d];
        mx = fmaxf(mx, acc);
        sm += acc;
    }
    Mout[(size_t)((b * 8) + h) * LQ + l] = mx - sm / (float)LK;
}

// Parallel top-u per (b,h): iterative argmax in LDS, lowest-index tie-break.
__global__ __launch_bounds__(256) void topk_k(const float* __restrict__ M,
                                              int* __restrict__ top, int LQ, int u) {
    __shared__ float vals[512];
    __shared__ float rv[256];
    __shared__ int ri[256];
    int bh = blockIdx.x;
    int tid = threadIdx.x;
    const float* m = M + (size_t)bh * LQ;
    for (int l = tid; l < LQ; l += 256) vals[l] = m[l];
    __syncthreads();
    for (int j = 0; j < u; j++) {
        float best = -INFINITY;
        int bi = LQ;
        for (int l = tid; l < LQ; l += 256) {
            float v = vals[l];
            if (v > best) { best = v; bi = l; }
        }
        rv[tid] = best; ri[tid] = bi;
        __syncthreads();
        for (int s = 128; s > 0; s >>= 1) {
            if (tid < s) {
                float v2 = rv[tid + s]; int i2 = ri[tid + s];
                if (v2 > rv[tid] || (v2 == rv[tid] && i2 < ri[tid])) { rv[tid] = v2; ri[tid] = i2; }
            }
            __syncthreads();
        }
        int sel = ri[0];
        if (tid == 0) {
            top[bh * u + j] = sel;
            vals[sel] = -INFINITY;
        }
        __syncthreads();
    }
}

// vm[b, c] = mean over l of V[b,l,c]
__global__ void vmean_k(const float* __restrict__ Vp, float* __restrict__ vm, int LK) {
    int t = blockIdx.x * 256 + threadIdx.x;
    if (t >= 16 * 512) return;
    int c = t % 512;
    int b = t / 512;
    float s = 0.f;
    for (int l = 0; l < LK; l++) s += Vp[(size_t)(b * LK + l) * 512 + c];
    vm[t] = s / (float)LK;
}

// ctx[b,l,c] = vm[b,c]
__global__ void ctx_fill_k(const float* __restrict__ vm, float* __restrict__ ctx, int LQ, int total) {
    int t = blockIdx.x * 256 + threadIdx.x;
    if (t >= total) return;
    int c = t % 512;
    int b = t / (512 * LQ);
    ctx[t] = vm[b * 512 + c];
}

// full softmax-attention for one selected row l = top[b,h,uu]
__global__ __launch_bounds__(256) void attn_rows_k(
    const float* __restrict__ Qp, const float* __restrict__ Kp, const float* __restrict__ Vp,
    const int* __restrict__ top, float* __restrict__ ctx, int LQ, int LK, int u) {
    __shared__ float sc[512];
    __shared__ float red[256];
    __shared__ float qs[64];
    int bid = blockIdx.x;
    int uu = bid % u;
    int h = (bid / u) & 7;
    int b = bid / (u * 8);
    int l = top[((b * 8) + h) * u + uu];
    int tid = threadIdx.x;
    const float* q = Qp + ((size_t)(b * LQ + l) * 512 + h * 64);
    const float* kb = Kp + ((size_t)b * LK * 512 + h * 64);
    if (tid < 64) qs[tid] = q[tid];
    __syncthreads();
    for (int k = tid; k < LK; k += 256) {
        const float* kr = kb + (size_t)k * 512;
        float acc = 0.f;
        #pragma unroll
        for (int d = 0; d < 64; d++) acc += qs[d] * kr[d];
        sc[k] = acc * 0.125f;
    }
    __syncthreads();
    float lm = -INFINITY;
    for (int k = tid; k < LK; k += 256) lm = fmaxf(lm, sc[k]);
    red[tid] = lm;
    __syncthreads();
    for (int s = 128; s > 0; s >>= 1) {
        if (tid < s) red[tid] = fmaxf(red[tid], red[tid + s]);
        __syncthreads();
    }
    float mx = red[0];
    __syncthreads();
    float ls = 0.f;
    for (int k = tid; k < LK; k += 256) {
        float e = expf(sc[k] - mx);
        sc[k] = e;
        ls += e;
    }
    red[tid] = ls;
    __syncthreads();
    for (int s = 128; s > 0; s >>= 1) {
        if (tid < s) red[tid] += red[tid + s];
        __syncthreads();
    }
    float denom = red[0];
    __syncthreads();
    if (tid < 64) {
        int d = tid;
        const float* vb = Vp + ((size_t)b * LK * 512 + h * 64 + d);
        float acc = 0.f;
        for (int k = 0; k < LK; k++) acc += sc[k] * vb[(size_t)k * 512];
        ctx[(size_t)(b * LQ + l) * 512 + h * 64 + d] = acc / denom;
    }
}

// per-row layer norm, D=512
__global__ __launch_bounds__(256) void ln_k(const float* __restrict__ in, float* __restrict__ out) {
    __shared__ float red[256];
    int r = blockIdx.x;
    int tid = threadIdx.x;
    const float* x = in + (size_t)r * 512;
    float a = x[tid], b = x[tid + 256];
    red[tid] = a + b;
    __syncthreads();
    for (int s = 128; s > 0; s >>= 1) {
        if (tid < s) red[tid] += red[tid + s];
        __syncthreads();
    }
    float mu = red[0] / 512.f;
    __syncthreads();
    float d1 = a - mu, d2 = b - mu;
    red[tid] = d1 * d1 + d2 * d2;
    __syncthreads();
    for (int s = 128; s > 0; s >>= 1) {
        if (tid < s) red[tid] += red[tid + s];
        __syncthreads();
    }
    float inv = 1.0f / sqrtf(red[0] / 512.f + 1e-5f);
    out[(size_t)r * 512 + tid] = d1 * inv;
    out[(size_t)r * 512 + tid + 256] = d2 * inv;
}

// circular-pad im2col: xc[(b*L+t)*1536 + h*512 + i] = x[b, (t+h-1) mod L, i]
__global__ void xcat_k(const float* __restrict__ x, float* __restrict__ xc, int L, int total) {
    int t = blockIdx.x * 256 + threadIdx.x;
    if (t >= total) return;
    int i = t % 512;
    int h = (t / 512) % 3;
    int bt = t / 1536;
    int tt = bt % L;
    int b = bt / L;
    int src = (tt + h - 1 + L) % L;
    xc[t] = x[(size_t)(b * L + src) * 512 + i];
}

// per-channel mean/var over all rows
__global__ __launch_bounds__(256) void bnstats_k(const float* __restrict__ y,
                                                 float* __restrict__ mu, float* __restrict__ var,
                                                 int rows) {
    __shared__ float red[256];
    int o = blockIdx.x;
    int tid = threadIdx.x;
    float s = 0.f;
    for (int r = tid; r < rows; r += 256) s += y[(size_t)r * 512 + o];
    red[tid] = s;
    __syncthreads();
    for (int st = 128; st > 0; st >>= 1) {
        if (tid < st) red[tid] += red[tid + st];
        __syncthreads();
    }
    float m = red[0] / (float)rows;
    __syncthreads();
    float s2 = 0.f;
    for (int r = tid; r < rows; r += 256) {
        float d = y[(size_t)r * 512 + o] - m;
        s2 += d * d;
    }
    red[tid] = s2;
    __syncthreads();
    for (int st = 128; st > 0; st >>= 1) {
        if (tid < st) red[tid] += red[tid + st];
        __syncthreads();
    }
    if (tid == 0) {
        mu[o] = m;
        var[o] = red[0] / (float)rows;
    }
}

// normalize -> max-pool(3,2,pad1) -> elu (monotone, pool first)
__global__ void elu_pool_k(const float* __restrict__ y, const float* __restrict__ mu,
                           const float* __restrict__ var, float* __restrict__ out,
                           int L, int total) {
    int t = blockIdx.x * 256 + threadIdx.x;
    if (t >= total) return;
    int o = t % 512;
    int tp = (t / 512) % (L / 2);
    int b = t / (512 * (L / 2));
    float mm = mu[o];
    float inv = 1.0f / sqrtf(var[o] + 1e-5f);
    float m = -INFINITY;
    #pragma unroll
    for (int dt = 0; dt < 3; dt++) {
        int tt = 2 * tp - 1 + dt;
        if (tt < 0 || tt >= L) continue;
        float v = (y[(size_t)(b * L + tt) * 512 + o] - mm) * inv;
        m = fmaxf(m, v);
    }
    out[t] = m > 0.f ? m : expm1f(m);
}

// out[r] = dot(x[r,:512], w) + b
__global__ void final_k(const float* __restrict__ x, const float* __restrict__ w,
                        const float* __restrict__ bb, float* __restrict__ out, int rows) {
    int gid = blockIdx.x * 256 + threadIdx.x;
    int wid = gid >> 6;
    int lane = gid & 63;
    if (wid >= rows) return;
    const float* xr = x + (size_t)wid * 512;
    float acc = 0.f;
    for (int k = lane; k < 512; k += 64) acc += xr[k] * w[k];
    for (int off = 32; off > 0; off >>= 1) acc += __shfl_down(acc, off);
    if (lane == 0) out[wid] = acc + bb[0];
}

// ---------------------------------------------------------------------------
// Host driver
// ---------------------------------------------------------------------------

static inline int iceil_log(int L) { return (int)ceil(log((double)L)); }
static inline int imin(int a, int b) { return a < b ? a : b; }

extern "C" void kernel_launch(void* const* d_in, const int* in_sizes, int n_in,
                              void* d_out, int out_size, void* d_ws, size_t ws_size,
                              hipStream_t stream) {
    const float* IN  = (const float*)d_in[0];
    const float* Wq  = (const float*)d_in[1];
    const float* bq  = (const float*)d_in[2];
    const float* Wk  = (const float*)d_in[3];
    const float* bk  = (const float*)d_in[4];
    const float* Wv  = (const float*)d_in[5];
    const float* bv  = (const float*)d_in[6];
    const float* Wo  = (const float*)d_in[7];
    const float* bo  = (const float*)d_in[8];
    const float* ew1 = (const float*)d_in[9];
    const float* eb1 = (const float*)d_in[10];
    const float* ew2 = (const float*)d_in[11];
    const float* eb2 = (const float*)d_in[12];
    const float* dw1 = (const float*)d_in[13];
    const float* db1 = (const float*)d_in[14];
    const float* dw2 = (const float*)d_in[15];
    const float* db2 = (const float*)d_in[16];
    const float* DW  = (const float*)d_in[17];
    const float* db  = (const float*)d_in[18];
    const float* ow  = (const float*)d_in[19];
    const float* ob  = (const float*)d_in[20];
    float* OUT = (float*)d_out;

    float* ws = (float*)d_ws;
    size_t off = 0;
    auto alloc = [&](size_t n) { float* p = ws + off; off += n; return p; };
    float* PE   = alloc(4194304);
    float* Qb   = alloc(4194304);
    float* Kb   = alloc(4194304);
    float* Vb   = alloc(4194304);
    float* CTX  = alloc(4194304);
    float* T1   = alloc(4194304);
    float* XLN  = alloc(4194304);
    float* T2   = alloc(4194304);
    float* T3   = alloc(4194304);
    float* HID  = alloc(16777216);
    float* D1   = alloc(2097152);
    float* D2   = alloc(1048576);
    float* Eb   = alloc(524288);
    float* MB   = alloc(65536);
    float* VM   = alloc(8192);
    float* MU   = alloc(512);
    float* VARb = alloc(512);
    int* IDX  = (int*)alloc(17920);
    int* TOPB = (int*)alloc(4480);
    // bf16 transposed weights [N][K] (alloc counts are in floats; 2 shorts/float)
    short* WqT  = (short*)alloc(131072);
    short* WkT  = (short*)alloc(131072);
    short* WvT  = (short*)alloc(131072);
    short* WoT  = (short*)alloc(131072);
    short* ew1T = (short*)alloc(524288);
    short* ew2T = (short*)alloc(524288);
    short* dw1T = (short*)alloc(524288);
    short* dw2T = (short*)alloc(524288);
    short* W2T  = (short*)alloc(393216);
    (void)ws_size; (void)n_in; (void)in_sizes; (void)out_size;

    auto gemm = [&](const float* A, const short* Bt, const float* bias, const float* res,
                    float* C, int M, int N, int K, int relu) {
        dim3 g(N / 128, M / 128);
        gemm_bf_k<<<g, 256, 0, stream>>>(A, Bt, bias, res, C, M, N, K, relu);
    };
    auto tr = [&](const float* W, short* Wt, int K, int N) {
        dim3 g(N / 32, K / 32);
        transpose_bf16_k<<<g, 256, 0, stream>>>(W, Wt, K, N);
    };

    auto attn = [&](const float* qin, const float* kvin, const float* resp, float* outp,
                    int LQ, int LK, int ikey) {
        int Mq = 16 * LQ, Mk = 16 * LK;
        gemm(qin, WqT, bq, nullptr, Qb, Mq, 512, 512, 0);
        gemm(kvin, WkT, bk, nullptr, Kb, Mk, 512, 512, 0);
        gemm(kvin, WvT, bv, nullptr, Vb, Mk, 512, 512, 0);
        int U = imin(5 * iceil_log(LK), LK);
        int u = imin(5 * iceil_log(LQ), LQ);
        unsigned rk0, rk1;
        threefry2x32(0u, 42u, 0u, (unsigned)ikey, rk0, rk1);
        int size = LQ * U;
        ridx_k<<<(size + 255) / 256, 256, 0, stream>>>(rk0, rk1, size, (unsigned)(LK - 1), IDX);
        int totM = 16 * 8 * LQ;
        msamp_k<<<(totM + 255) / 256, 256, 0, stream>>>(Qb, Kb, IDX, MB, LQ, LK, U);
        topk_k<<<128, 256, 0, stream>>>(MB, TOPB, LQ, u);
        vmean_k<<<(16 * 512 + 255) / 256, 256, 0, stream>>>(Vb, VM, LK);
        int totC = 16 * LQ * 512;
        ctx_fill_k<<<(totC + 255) / 256, 256, 0, stream>>>(VM, CTX, LQ, totC);
        attn_rows_k<<<16 * 8 * u, 256, 0, stream>>>(Qb, Kb, Vb, TOPB, CTX, LQ, LK, u);
        gemm(CTX, WoT, bo, resp, outp, Mq, 512, 512, 0);
    };

    auto encoder = [&](const float* X, int L, int ikey, float* OUTenc) {
        int M = 16 * L;
        attn(X, X, X, T1, L, L, ikey);
        ln_k<<<M, 256, 0, stream>>>(T1, XLN);
        gemm(XLN, ew1T, eb1, nullptr, HID, M, 2048, 512, 1);
        gemm(HID, ew2T, eb2, XLN, T2, M, 512, 2048, 0);
        ln_k<<<M, 256, 0, stream>>>(T2, OUTenc);
    };

    auto distill = [&](const float* X, int L, float* OUTd) {
        int M = 16 * L;
        int tot = M * 1536;
        xcat_k<<<(tot + 255) / 256, 256, 0, stream>>>(X, HID, L, tot);
        gemm(HID, W2T, db, nullptr, CTX, M, 512, 1536, 0);
        bnstats_k<<<512, 256, 0, stream>>>(CTX, MU, VARb, M);
        int toto = 16 * (L / 2) * 512;
        elu_pool_k<<<(toto + 255) / 256, 256, 0, stream>>>(CTX, MU, VARb, OUTd, L, toto);
    };

    // --- weight conversion (once per launch) ---
    tr(Wq, WqT, 512, 512);
    tr(Wk, WkT, 512, 512);
    tr(Wv, WvT, 512, 512);
    tr(Wo, WoT, 512, 512);
    tr(ew1, ew1T, 512, 2048);
    tr(ew2, ew2T, 2048, 512);
    tr(dw1, dw1T, 512, 2048);
    tr(dw2, dw2T, 2048, 512);
    w2t_k<<<(786432 + 255) / 256, 256, 0, stream>>>(DW, W2T, 786432);

    // --- forward ---
    int totPE = 16 * 512 * 512;
    pe_add_k<<<(totPE + 255) / 256, 256, 0, stream>>>(IN, PE, totPE);

    encoder(PE, 512, 0, T3); distill(T3, 512, D1);
    encoder(D1, 256, 1, T3); distill(T3, 256, D2);
    encoder(D2, 128, 2, T3); distill(T3, 128, Eb);

    attn(PE, PE, PE, T1, 512, 512, 3);
    attn(T1, Eb, T1, T2, 512, 64, 4);
    gemm(T2, dw1T, db1, nullptr, HID, 8192, 2048, 512, 1);
    gemm(HID, dw2T, db2, T2, T3, 8192, 512, 2048, 0);
    final_k<<<(8192 * 64) / 256, 256, 0, stream>>>(T3, ow, ob, OUT, 8192);
}

// Round 4
// 2515.125 us; speedup vs baseline: 5.7754x; 1.2505x over previous
//
#include <hip/hip_runtime.h>
#include <cstdint>
#include <cmath>

// ---------------------------------------------------------------------------
// Informer forward. Round 4: attn_rows rewrite (parallel PV + coalesced QK),
// fused QKV projection (N=1536), 64x64-tile GEMM for N<=1024 shapes,
// LDS pad 32->40 shorts (kills 8-way fragment-read bank conflict).
// jax.random via threefry2x32 (H2 layout, verified R1).
// ---------------------------------------------------------------------------

#define HD __host__ __device__

typedef short short8 __attribute__((ext_vector_type(8)));
typedef short short4v __attribute__((ext_vector_type(4)));
typedef float float4v __attribute__((ext_vector_type(4)));

__device__ inline short f2bf(float f) {  // RNE
    unsigned u = __float_as_uint(f);
    unsigned r = u + 0x7FFFu + ((u >> 16) & 1u);
    return (short)(r >> 16);
}

HD inline unsigned rotl32(unsigned x, int r) { return (x << r) | (x >> (32 - r)); }
HD inline void tfround(unsigned& x0, unsigned& x1, int r) {
    x0 += x1; x1 = rotl32(x1, r); x1 ^= x0;
}
HD inline void threefry2x32(unsigned k0, unsigned k1, unsigned c0, unsigned c1,
                            unsigned& o0, unsigned& o1) {
    unsigned ks2 = k0 ^ k1 ^ 0x1BD11BDAu;
    unsigned x0 = c0 + k0, x1 = c1 + k1;
    tfround(x0, x1, 13); tfround(x0, x1, 15); tfround(x0, x1, 26); tfround(x0, x1, 6);
    x0 += k1; x1 += ks2 + 1u;
    tfround(x0, x1, 17); tfround(x0, x1, 29); tfround(x0, x1, 16); tfround(x0, x1, 24);
    x0 += ks2; x1 += k0 + 2u;
    tfround(x0, x1, 13); tfround(x0, x1, 15); tfround(x0, x1, 26); tfround(x0, x1, 6);
    x0 += k0; x1 += k1 + 3u;
    tfround(x0, x1, 17); tfround(x0, x1, 29); tfround(x0, x1, 16); tfround(x0, x1, 24);
    x0 += k1; x1 += ks2 + 4u;
    tfround(x0, x1, 13); tfround(x0, x1, 15); tfround(x0, x1, 26); tfround(x0, x1, 6);
    x0 += ks2; x1 += k0 + 5u;
    o0 = x0; o1 = x1;
}

// ---------------------------------------------------------------------------
// Kernels
// ---------------------------------------------------------------------------

__global__ void pe_add_k(const float* __restrict__ in, float* __restrict__ out, int total) {
    int t = blockIdx.x * 256 + threadIdx.x;
    if (t >= total) return;
    int d = t % 512;
    int l = (t / 512) % 512;
    float i2 = (float)(d & ~1);
    float div = expf(i2 * (-0.017988946039016f));  // -ln(10000)/512
    float ang = (float)l * div;
    float v = (d & 1) ? cosf(ang) : sinf(ang);
    out[t] = in[t] + v;
}

// fp32 [K][N] -> bf16 [N][K] via 32x32 LDS tile
__global__ __launch_bounds__(256) void transpose_bf16_k(const float* __restrict__ in,
                                                        short* __restrict__ out, int K, int N) {
    __shared__ float tile[32][33];
    int k0 = blockIdx.y * 32, n0 = blockIdx.x * 32;
    int c = threadIdx.x & 31, r0 = threadIdx.x >> 5;
    for (int rr = r0; rr < 32; rr += 8)
        tile[rr][c] = in[(size_t)(k0 + rr) * N + n0 + c];
    __syncthreads();
    for (int rr = r0; rr < 32; rr += 8)
        out[(size_t)(n0 + rr) * K + k0 + c] = f2bf(tile[c][rr]);
}

// dist_w (O,I,H) -> bf16 W2T[o][h*512+i]
__global__ void w2t_k(const float* __restrict__ dw, short* __restrict__ out, int total) {
    int t = blockIdx.x * 256 + threadIdx.x;
    if (t >= total) return;
    int kk = t % 1536;
    int o = t / 1536;
    int h = kk / 512, i = kk % 512;
    out[t] = f2bf(dw[(size_t)o * 1536 + i * 3 + h]);
}

// concat biases bq|bk|bv -> bqkv[1536]
__global__ void bcat_k(const float* __restrict__ b0, const float* __restrict__ b1,
                       const float* __restrict__ b2, float* __restrict__ out) {
    int t = blockIdx.x * 256 + threadIdx.x;
    if (t >= 1536) return;
    out[t] = (t < 512) ? b0[t] : (t < 1024 ? b1[t - 512] : b2[t - 1024]);
}

// bf16 MFMA GEMM, 128x128 block, BK=32; 4 waves, each 64x64 (4x4 MFMA tiles).
// C[M,N] = A[M,K](fp32) @ Bt[N,K](bf16) (+bias)(+relu)(+res); C stride ldC.
__global__ __launch_bounds__(256) void gemm_bf_k(
    const float* __restrict__ A, const short* __restrict__ Bt,
    const float* __restrict__ bias, const float* __restrict__ res,
    float* __restrict__ C, int M, int N, int K, int relu, int ldC) {
    __shared__ short As[128 * 40];
    __shared__ short Bs[128 * 40];
    int tid = threadIdx.x;
    int wave = tid >> 6, lane = tid & 63;
    int wy = wave >> 1, wx = wave & 1;
    int rl = lane & 15, quad = lane >> 4;
    int bm = blockIdx.y * 128, bn = blockIdx.x * 128;

    float4v acc[4][4];
    #pragma unroll
    for (int i = 0; i < 4; i++)
        #pragma unroll
        for (int j = 0; j < 4; j++) acc[i][j] = (float4v){0.f, 0.f, 0.f, 0.f};

    for (int k0 = 0; k0 < K; k0 += 32) {
        #pragma unroll
        for (int it = 0; it < 4; it++) {
            int f = tid + it * 256;
            int row = f >> 3, c4 = f & 7;
            const float4* src = (const float4*)(A + (size_t)(bm + row) * K + k0 + c4 * 4);
            float4 v = *src;
            short4v s = {f2bf(v.x), f2bf(v.y), f2bf(v.z), f2bf(v.w)};
            *(short4v*)&As[row * 40 + c4 * 4] = s;
        }
        #pragma unroll
        for (int it = 0; it < 2; it++) {
            int c = tid + it * 256;
            int n = c >> 2, seg = c & 3;
            const float4* src = (const float4*)(Bt + (size_t)(bn + n) * K + k0 + seg * 8);
            *(float4*)&Bs[n * 40 + seg * 8] = *src;
        }
        __syncthreads();
        short8 a[4], b[4];
        #pragma unroll
        for (int i = 0; i < 4; i++)
            a[i] = *(const short8*)&As[(wy * 64 + i * 16 + rl) * 40 + quad * 8];
        #pragma unroll
        for (int j = 0; j < 4; j++)
            b[j] = *(const short8*)&Bs[(wx * 64 + j * 16 + rl) * 40 + quad * 8];
        #pragma unroll
        for (int i = 0; i < 4; i++)
            #pragma unroll
            for (int j = 0; j < 4; j++)
                acc[i][j] = __builtin_amdgcn_mfma_f32_16x16x32_bf16(a[i], b[j], acc[i][j], 0, 0, 0);
        __syncthreads();
    }
    #pragma unroll
    for (int i = 0; i < 4; i++) {
        #pragma unroll
        for (int r = 0; r < 4; r++) {
            int gm = bm + wy * 64 + i * 16 + quad * 4 + r;
            #pragma unroll
            for (int j = 0; j < 4; j++) {
                int gn = bn + wx * 64 + j * 16 + rl;
                float v = acc[i][j][r];
                if (bias) v += bias[gn];
                if (relu) v = fmaxf(v, 0.f);
                if (res) v += res[(size_t)gm * ldC + gn];
                C[(size_t)gm * ldC + gn] = v;
            }
        }
    }
}

// 64x64-tile variant for small-N GEMMs (better blocks/CU). 4 waves, each 16x64.
__global__ __launch_bounds__(256) void gemm64_k(
    const float* __restrict__ A, const short* __restrict__ Bt,
    const float* __restrict__ bias, const float* __restrict__ res,
    float* __restrict__ C, int M, int N, int K, int relu, int ldC) {
    __shared__ short As[64 * 40];
    __shared__ short Bs[64 * 40];
    int tid = threadIdx.x;
    int wave = tid >> 6, lane = tid & 63;
    int rl = lane & 15, quad = lane >> 4;
    int bm = blockIdx.y * 64, bn = blockIdx.x * 64;

    float4v acc[4];
    #pragma unroll
    for (int j = 0; j < 4; j++) acc[j] = (float4v){0.f, 0.f, 0.f, 0.f};

    for (int k0 = 0; k0 < K; k0 += 32) {
        #pragma unroll
        for (int it = 0; it < 2; it++) {
            int f = tid + it * 256;
            int row = f >> 3, c4 = f & 7;
            const float4* src = (const float4*)(A + (size_t)(bm + row) * K + k0 + c4 * 4);
            float4 v = *src;
            short4v s = {f2bf(v.x), f2bf(v.y), f2bf(v.z), f2bf(v.w)};
            *(short4v*)&As[row * 40 + c4 * 4] = s;
        }
        {
            int n = tid >> 2, seg = tid & 3;
            const float4* src = (const float4*)(Bt + (size_t)(bn + n) * K + k0 + seg * 8);
            *(float4*)&Bs[n * 40 + seg * 8] = *src;
        }
        __syncthreads();
        short8 a = *(const short8*)&As[(wave * 16 + rl) * 40 + quad * 8];
        short8 b[4];
        #pragma unroll
        for (int j = 0; j < 4; j++)
            b[j] = *(const short8*)&Bs[(j * 16 + rl) * 40 + quad * 8];
        #pragma unroll
        for (int j = 0; j < 4; j++)
            acc[j] = __builtin_amdgcn_mfma_f32_16x16x32_bf16(a, b[j], acc[j], 0, 0, 0);
        __syncthreads();
    }
    #pragma unroll
    for (int r = 0; r < 4; r++) {
        int gm = bm + wave * 16 + quad * 4 + r;
        #pragma unroll
        for (int j = 0; j < 4; j++) {
            int gn = bn + j * 16 + rl;
            float v = acc[j][r];
            if (bias) v += bias[gn];
            if (relu) v = fmaxf(v, 0.f);
            if (res) v += res[(size_t)gm * ldC + gn];
            C[(size_t)gm * ldC + gn] = v;
        }
    }
}

// idx[j] = threefry(rkey, (j, j+size)).second & mask   (H2, verified R1)
__global__ void ridx_k(unsigned k0, unsigned k1, int size, unsigned mask, int* __restrict__ idx) {
    int j = blockIdx.x * 256 + threadIdx.x;
    if (j >= size) return;
    unsigned o0, o1;
    threefry2x32(k0, k1, (unsigned)j, (unsigned)(j + size), o0, o1);
    idx[j] = (int)(o1 & mask);
}

// M[b,h,l] = max_s(Q.K_samp) - sum_s(Q.K_samp)/LK   (rows have stride ld)
__global__ void msamp_k(const float* __restrict__ Qp, const float* __restrict__ Kp,
                        const int* __restrict__ idx, float* __restrict__ Mout,
                        int LQ, int LK, int U, int ld) {
    int t = blockIdx.x * 256 + threadIdx.x;
    int total = 16 * 8 * LQ;
    if (t >= total) return;
    int l = t % LQ;
    int h = (t / LQ) & 7;
    int b = t / (LQ * 8);
    const float4* q = (const float4*)(Qp + ((size_t)(b * LQ + l) * ld + h * 64));
    const float* kb = Kp + ((size_t)b * LK * ld + h * 64);
    float4 qr[16];
    #pragma unroll
    for (int d = 0; d < 16; d++) qr[d] = q[d];
    float mx = -INFINITY, sm = 0.f;
    for (int s = 0; s < U; s++) {
        const float4* kr = (const float4*)(kb + (size_t)idx[l * U + s] * ld);
        float acc = 0.f;
        #pragma unroll
        for (int d = 0; d < 16; d++) {
            float4 kv = kr[d];
            acc += qr[d].x * kv.x + qr[d].y * kv.y + qr[d].z * kv.z + qr[d].w * kv.w;
        }
        mx = fmaxf(mx, acc);
        sm += acc;
    }
    Mout[(size_t)((b * 8) + h) * LQ + l] = mx - sm / (float)LK;
}

// Parallel top-u per (b,h): iterative argmax in LDS, lowest-index tie-break.
__global__ __launch_bounds__(256) void topk_k(const float* __restrict__ M,
                                              int* __restrict__ top, int LQ, int u) {
    __shared__ float vals[512];
    __shared__ float rv[256];
    __shared__ int ri[256];
    int bh = blockIdx.x;
    int tid = threadIdx.x;
    const float* m = M + (size_t)bh * LQ;
    for (int l = tid; l < LQ; l += 256) vals[l] = m[l];
    __syncthreads();
    for (int j = 0; j < u; j++) {
        float best = -INFINITY;
        int bi = LQ;
        for (int l = tid; l < LQ; l += 256) {
            float v = vals[l];
            if (v > best) { best = v; bi = l; }
        }
        rv[tid] = best; ri[tid] = bi;
        __syncthreads();
        for (int s = 128; s > 0; s >>= 1) {
            if (tid < s) {
                float v2 = rv[tid + s]; int i2 = ri[tid + s];
                if (v2 > rv[tid] || (v2 == rv[tid] && i2 < ri[tid])) { rv[tid] = v2; ri[tid] = i2; }
            }
            __syncthreads();
        }
        int sel = ri[0];
        if (tid == 0) {
            top[bh * u + j] = sel;
            vals[sel] = -INFINITY;
        }
        __syncthreads();
    }
}

// vm[b, c] = mean over l of V[b,l,c]  (V rows stride ld)
__global__ void vmean_k(const float* __restrict__ Vp, float* __restrict__ vm, int LK, int ld) {
    int t = blockIdx.x * 256 + threadIdx.x;
    if (t >= 16 * 512) return;
    int c = t % 512;
    int b = t / 512;
    float s = 0.f;
    for (int l = 0; l < LK; l++) s += Vp[(size_t)(b * LK + l) * ld + c];
    vm[t] = s / (float)LK;
}

// ctx[b,l,c] = vm[b,c]
__global__ void ctx_fill_k(const float* __restrict__ vm, float* __restrict__ ctx, int LQ, int total) {
    int t = blockIdx.x * 256 + threadIdx.x;
    if (t >= total) return;
    int c = t % 512;
    int b = t / (512 * LQ);
    ctx[t] = vm[b * 512 + c];
}

// full softmax-attention for one selected row l = top[b,h,uu]
// QK: 4 lanes per K-row (float4, coalesced 256B/row-group) + shfl combine.
// PV: 4 k-groups x 64 coalesced d-lanes + LDS reduce.
__global__ __launch_bounds__(256) void attn_rows_k(
    const float* __restrict__ Qp, const float* __restrict__ Kp, const float* __restrict__ Vp,
    const int* __restrict__ top, float* __restrict__ ctx, int LQ, int LK, int u, int ld) {
    __shared__ float sc[512];
    __shared__ float red[256];
    __shared__ float qs[64];
    int bid = blockIdx.x;
    int uu = bid % u;
    int h = (bid / u) & 7;
    int b = bid / (u * 8);
    int l = top[((b * 8) + h) * u + uu];
    int tid = threadIdx.x;
    const float* q = Qp + ((size_t)(b * LQ + l) * ld + h * 64);
    const float* kb = Kp + ((size_t)b * LK * ld + h * 64);
    if (tid < 64) qs[tid] = q[tid];
    __syncthreads();
    // QK^T
    int tq = tid & 3, tr = tid >> 2;
    float4 qv[4];
    #pragma unroll
    for (int i = 0; i < 4; i++) qv[i] = ((const float4*)qs)[tq * 4 + i];
    for (int k = tr; k < LK; k += 64) {
        const float4* kr = (const float4*)(kb + (size_t)k * ld + tq * 16);
        float acc = 0.f;
        #pragma unroll
        for (int i = 0; i < 4; i++) {
            float4 kv = kr[i];
            acc += qv[i].x * kv.x + qv[i].y * kv.y + qv[i].z * kv.z + qv[i].w * kv.w;
        }
        acc += __shfl_xor(acc, 1);
        acc += __shfl_xor(acc, 2);
        if (tq == 0) sc[k] = acc * 0.125f;  // 1/sqrt(64)
    }
    __syncthreads();
    // softmax
    float lm = -INFINITY;
    for (int k = tid; k < LK; k += 256) lm = fmaxf(lm, sc[k]);
    red[tid] = lm;
    __syncthreads();
    for (int s = 128; s > 0; s >>= 1) {
        if (tid < s) red[tid] = fmaxf(red[tid], red[tid + s]);
        __syncthreads();
    }
    float mx = red[0];
    __syncthreads();
    float ls = 0.f;
    for (int k = tid; k < LK; k += 256) {
        float e = expf(sc[k] - mx);
        sc[k] = e;
        ls += e;
    }
    red[tid] = ls;
    __syncthreads();
    for (int s = 128; s > 0; s >>= 1) {
        if (tid < s) red[tid] += red[tid + s];
        __syncthreads();
    }
    float denom = red[0];
    __syncthreads();
    // PV
    int grp = tid >> 6, d = tid & 63;
    const float* vb = Vp + ((size_t)b * LK * ld + h * 64 + d);
    float acc = 0.f;
    for (int k = grp; k < LK; k += 4) acc += sc[k] * vb[(size_t)k * ld];
    red[tid] = acc;
    __syncthreads();
    if (tid < 64) {
        float s = red[tid] + red[tid + 64] + red[tid + 128] + red[tid + 192];
        ctx[(size_t)(b * LQ + l) * 512 + h * 64 + tid] = s / denom;
    }
}

// per-row layer norm, D=512
__global__ __launch_bounds__(256) void ln_k(const float* __restrict__ in, float* __restrict__ out) {
    __shared__ float red[256];
    int r = blockIdx.x;
    int tid = threadIdx.x;
    const float* x = in + (size_t)r * 512;
    float a = x[tid], b = x[tid + 256];
    red[tid] = a + b;
    __syncthreads();
    for (int s = 128; s > 0; s >>= 1) {
        if (tid < s) red[tid] += red[tid + s];
        __syncthreads();
    }
    float mu = red[0] / 512.f;
    __syncthreads();
    float d1 = a - mu, d2 = b - mu;
    red[tid] = d1 * d1 + d2 * d2;
    __syncthreads();
    for (int s = 128; s > 0; s >>= 1) {
        if (tid < s) red[tid] += red[tid + s];
        __syncthreads();
    }
    float inv = 1.0f / sqrtf(red[0] / 512.f + 1e-5f);
    out[(size_t)r * 512 + tid] = d1 * inv;
    out[(size_t)r * 512 + tid + 256] = d2 * inv;
}

// circular-pad im2col: xc[(b*L+t)*1536 + h*512 + i] = x[b, (t+h-1) mod L, i]
__global__ void xcat_k(const float* __restrict__ x, float* __restrict__ xc, int L, int total) {
    int t = blockIdx.x * 256 + threadIdx.x;
    if (t >= total) return;
    int i = t % 512;
    int h = (t / 512) % 3;
    int bt = t / 1536;
    int tt = bt % L;
    int b = bt / L;
    int src = (tt + h - 1 + L) % L;
    xc[t] = x[(size_t)(b * L + src) * 512 + i];
}

// per-channel mean/var over all rows
__global__ __launch_bounds__(256) void bnstats_k(const float* __restrict__ y,
                                                 float* __restrict__ mu, float* __restrict__ var,
                                                 int rows) {
    __shared__ float red[256];
    int o = blockIdx.x;
    int tid = threadIdx.x;
    float s = 0.f;
    for (int r = tid; r < rows; r += 256) s += y[(size_t)r * 512 + o];
    red[tid] = s;
    __syncthreads();
    for (int st = 128; st > 0; st >>= 1) {
        if (tid < st) red[tid] += red[tid + st];
        __syncthreads();
    }
    float m = red[0] / (float)rows;
    __syncthreads();
    float s2 = 0.f;
    for (int r = tid; r < rows; r += 256) {
        float d = y[(size_t)r * 512 + o] - m;
        s2 += d * d;
    }
    red[tid] = s2;
    __syncthreads();
    for (int st = 128; st > 0; st >>= 1) {
        if (tid < st) red[tid] += red[tid + st];
        __syncthreads();
    }
    if (tid == 0) {
        mu[o] = m;
        var[o] = red[0] / (float)rows;
    }
}

// normalize -> max-pool(3,2,pad1) -> elu (monotone, pool first)
__global__ void elu_pool_k(const float* __restrict__ y, const float* __restrict__ mu,
                           const float* __restrict__ var, float* __restrict__ out,
                           int L, int total) {
    int t = blockIdx.x * 256 + threadIdx.x;
    if (t >= total) return;
    int o = t % 512;
    int tp = (t / 512) % (L / 2);
    int b = t / (512 * (L / 2));
    float mm = mu[o];
    float inv = 1.0f / sqrtf(var[o] + 1e-5f);
    float m = -INFINITY;
    #pragma unroll
    for (int dt = 0; dt < 3; dt++) {
        int tt = 2 * tp - 1 + dt;
        if (tt < 0 || tt >= L) continue;
        float v = (y[(size_t)(b * L + tt) * 512 + o] - mm) * inv;
        m = fmaxf(m, v);
    }
    out[t] = m > 0.f ? m : expm1f(m);
}

// out[r] = dot(x[r,:512], w) + b
__global__ void final_k(const float* __restrict__ x, const float* __restrict__ w,
                        const float* __restrict__ bb, float* __restrict__ out, int rows) {
    int gid = blockIdx.x * 256 + threadIdx.x;
    int wid = gid >> 6;
    int lane = gid & 63;
    if (wid >= rows) return;
    const float* xr = x + (size_t)wid * 512;
    float acc = 0.f;
    for (int k = lane; k < 512; k += 64) acc += xr[k] * w[k];
    for (int off = 32; off > 0; off >>= 1) acc += __shfl_down(acc, off);
    if (lane == 0) out[wid] = acc + bb[0];
}

// ---------------------------------------------------------------------------
// Host driver
// ---------------------------------------------------------------------------

static inline int iceil_log(int L) { return (int)ceil(log((double)L)); }
static inline int imin(int a, int b) { return a < b ? a : b; }

extern "C" void kernel_launch(void* const* d_in, const int* in_sizes, int n_in,
                              void* d_out, int out_size, void* d_ws, size_t ws_size,
                              hipStream_t stream) {
    const float* IN  = (const float*)d_in[0];
    const float* Wq  = (const float*)d_in[1];
    const float* bq  = (const float*)d_in[2];
    const float* Wk  = (const float*)d_in[3];
    const float* bk  = (const float*)d_in[4];
    const float* Wv  = (const float*)d_in[5];
    const float* bv  = (const float*)d_in[6];
    const float* Wo  = (const float*)d_in[7];
    const float* bo  = (const float*)d_in[8];
    const float* ew1 = (const float*)d_in[9];
    const float* eb1 = (const float*)d_in[10];
    const float* ew2 = (const float*)d_in[11];
    const float* eb2 = (const float*)d_in[12];
    const float* dw1 = (const float*)d_in[13];
    const float* db1 = (const float*)d_in[14];
    const float* dw2 = (const float*)d_in[15];
    const float* db2 = (const float*)d_in[16];
    const float* DW  = (const float*)d_in[17];
    const float* db  = (const float*)d_in[18];
    const float* ow  = (const float*)d_in[19];
    const float* ob  = (const float*)d_in[20];
    float* OUT = (float*)d_out;

    float* ws = (float*)d_ws;
    size_t off = 0;
    auto alloc = [&](size_t n) { float* p = ws + off; off += n; return p; };
    float* PE   = alloc(4194304);
    float* QKV  = alloc(12582912);  // [8192][1536]: Q|K|V columns
    float* CTX  = alloc(4194304);
    float* T1   = alloc(4194304);
    float* XLN  = alloc(4194304);
    float* T2   = alloc(4194304);
    float* T3   = alloc(4194304);
    float* HID  = alloc(16777216);
    float* D1   = alloc(2097152);
    float* D2   = alloc(1048576);
    float* Eb   = alloc(524288);
    float* MB   = alloc(65536);
    float* VM   = alloc(8192);
    float* MU   = alloc(512);
    float* VARb = alloc(512);
    float* BQKV = alloc(1536);
    int* IDX  = (int*)alloc(17920);
    int* TOPB = (int*)alloc(4480);
    short* WqkvT = (short*)alloc(393216);  // [1536][512] bf16: Wq|Wk|Wv rows
    short* WoT   = (short*)alloc(131072);
    short* ew1T  = (short*)alloc(524288);
    short* ew2T  = (short*)alloc(524288);
    short* dw1T  = (short*)alloc(524288);
    short* dw2T  = (short*)alloc(524288);
    short* W2T   = (short*)alloc(393216);
    (void)ws_size; (void)n_in; (void)in_sizes; (void)out_size;

    auto gemm128 = [&](const float* A, const short* Bt, const float* bias, const float* res,
                       float* C, int M, int N, int K, int relu, int ldC) {
        dim3 g(N / 128, M / 128);
        gemm_bf_k<<<g, 256, 0, stream>>>(A, Bt, bias, res, C, M, N, K, relu, ldC);
    };
    auto gemm64 = [&](const float* A, const short* Bt, const float* bias, const float* res,
                      float* C, int M, int N, int K, int relu, int ldC) {
        dim3 g(N / 64, M / 64);
        gemm64_k<<<g, 256, 0, stream>>>(A, Bt, bias, res, C, M, N, K, relu, ldC);
    };
    auto tr = [&](const float* W, short* Wt, int K, int N) {
        dim3 g(N / 32, K / 32);
        transpose_bf16_k<<<g, 256, 0, stream>>>(W, Wt, K, N);
    };

    auto attn = [&](const float* qin, const float* kvin, const float* resp, float* outp,
                    int LQ, int LK, int ikey) {
        int Mq = 16 * LQ, Mk = 16 * LK;
        const int ld = 1536;
        float* Qp = QKV;
        float* Kp = QKV + 512;
        float* Vp = QKV + 1024;
        if (qin == kvin) {
            gemm128(qin, WqkvT, BQKV, nullptr, QKV, Mq, 1536, 512, 0, ld);
        } else {
            gemm64(qin, WqkvT, BQKV, nullptr, QKV, Mq, 512, 512, 0, ld);
            gemm64(kvin, WqkvT + 512 * 512, BQKV + 512, nullptr, QKV + 512, Mk, 1024, 512, 0, ld);
        }
        int U = imin(5 * iceil_log(LK), LK);
        int u = imin(5 * iceil_log(LQ), LQ);
        unsigned rk0, rk1;
        threefry2x32(0u, 42u, 0u, (unsigned)ikey, rk0, rk1);
        int size = LQ * U;
        ridx_k<<<(size + 255) / 256, 256, 0, stream>>>(rk0, rk1, size, (unsigned)(LK - 1), IDX);
        int totM = 16 * 8 * LQ;
        msamp_k<<<(totM + 255) / 256, 256, 0, stream>>>(Qp, Kp, IDX, MB, LQ, LK, U, ld);
        topk_k<<<128, 256, 0, stream>>>(MB, TOPB, LQ, u);
        vmean_k<<<(16 * 512 + 255) / 256, 256, 0, stream>>>(Vp, VM, LK, ld);
        int totC = 16 * LQ * 512;
        ctx_fill_k<<<(totC + 255) / 256, 256, 0, stream>>>(VM, CTX, LQ, totC);
        attn_rows_k<<<16 * 8 * u, 256, 0, stream>>>(Qp, Kp, Vp, TOPB, CTX, LQ, LK, u, ld);
        gemm64(CTX, WoT, bo, resp, outp, Mq, 512, 512, 0, 512);
    };

    auto encoder = [&](const float* X, int L, int ikey, float* OUTenc) {
        int M = 16 * L;
        attn(X, X, X, T1, L, L, ikey);
        ln_k<<<M, 256, 0, stream>>>(T1, XLN);
        gemm128(XLN, ew1T, eb1, nullptr, HID, M, 2048, 512, 1, 2048);
        gemm64(HID, ew2T, eb2, XLN, T2, M, 512, 2048, 0, 512);
        ln_k<<<M, 256, 0, stream>>>(T2, OUTenc);
    };

    auto distill = [&](const float* X, int L, float* OUTd) {
        int M = 16 * L;
        int tot = M * 1536;
        xcat_k<<<(tot + 255) / 256, 256, 0, stream>>>(X, HID, L, tot);
        gemm64(HID, W2T, db, nullptr, CTX, M, 512, 1536, 0, 512);
        bnstats_k<<<512, 256, 0, stream>>>(CTX, MU, VARb, M);
        int toto = 16 * (L / 2) * 512;
        elu_pool_k<<<(toto + 255) / 256, 256, 0, stream>>>(CTX, MU, VARb, OUTd, L, toto);
    };

    // --- weight conversion (once per launch) ---
    tr(Wq, WqkvT, 512, 512);
    tr(Wk, WqkvT + 512 * 512, 512, 512);
    tr(Wv, WqkvT + 1024 * 512, 512, 512);
    tr(Wo, WoT, 512, 512);
    tr(ew1, ew1T, 512, 2048);
    tr(ew2, ew2T, 2048, 512);
    tr(dw1, dw1T, 512, 2048);
    tr(dw2, dw2T, 2048, 512);
    w2t_k<<<(786432 + 255) / 256, 256, 0, stream>>>(DW, W2T, 786432);
    bcat_k<<<6, 256, 0, stream>>>(bq, bk, bv, BQKV);

    // --- forward ---
    int totPE = 16 * 512 * 512;
    pe_add_k<<<(totPE + 255) / 256, 256, 0, stream>>>(IN, PE, totPE);

    encoder(PE, 512, 0, T3); distill(T3, 512, D1);
    encoder(D1, 256, 1, T3); distill(T3, 256, D2);
    encoder(D2, 128, 2, T3); distill(T3, 128, Eb);

    attn(PE, PE, PE, T1, 512, 512, 3);
    attn(T1, Eb, T1, T2, 512, 64, 4);
    gemm128(T2, dw1T, db1, nullptr, HID, 8192, 2048, 512, 1, 2048);
    gemm64(HID, dw2T, db2, T2, T3, 8192, 512, 2048, 0, 512);
    final_k<<<(8192 * 64) / 256, 256, 0, stream>>>(T3, ow, ob, OUT, 8192);
}

// Round 5
// 2365.258 us; speedup vs baseline: 6.1413x; 1.0634x over previous
//
#include <hip/hip_runtime.h>
#include <cstdint>
#include <cmath>

// ---------------------------------------------------------------------------
// Informer forward. Round 5: flash-style ProbSparse attention — one block per
// (b, h, u-half); K/V staged through LDS once per block instead of once per
// selected row (R4's attn_rows re-fetched K/V 35x -> 1.2 GB logical traffic).
// jax.random via threefry2x32 (H2 layout, verified R1).
// ---------------------------------------------------------------------------

#define HD __host__ __device__

typedef short short8 __attribute__((ext_vector_type(8)));
typedef short short4v __attribute__((ext_vector_type(4)));
typedef float float4v __attribute__((ext_vector_type(4)));

__device__ inline short f2bf(float f) {  // RNE
    unsigned u = __float_as_uint(f);
    unsigned r = u + 0x7FFFu + ((u >> 16) & 1u);
    return (short)(r >> 16);
}

HD inline unsigned rotl32(unsigned x, int r) { return (x << r) | (x >> (32 - r)); }
HD inline void tfround(unsigned& x0, unsigned& x1, int r) {
    x0 += x1; x1 = rotl32(x1, r); x1 ^= x0;
}
HD inline void threefry2x32(unsigned k0, unsigned k1, unsigned c0, unsigned c1,
                            unsigned& o0, unsigned& o1) {
    unsigned ks2 = k0 ^ k1 ^ 0x1BD11BDAu;
    unsigned x0 = c0 + k0, x1 = c1 + k1;
    tfround(x0, x1, 13); tfround(x0, x1, 15); tfround(x0, x1, 26); tfround(x0, x1, 6);
    x0 += k1; x1 += ks2 + 1u;
    tfround(x0, x1, 17); tfround(x0, x1, 29); tfround(x0, x1, 16); tfround(x0, x1, 24);
    x0 += ks2; x1 += k0 + 2u;
    tfround(x0, x1, 13); tfround(x0, x1, 15); tfround(x0, x1, 26); tfround(x0, x1, 6);
    x0 += k0; x1 += k1 + 3u;
    tfround(x0, x1, 17); tfround(x0, x1, 29); tfround(x0, x1, 16); tfround(x0, x1, 24);
    x0 += k1; x1 += ks2 + 4u;
    tfround(x0, x1, 13); tfround(x0, x1, 15); tfround(x0, x1, 26); tfround(x0, x1, 6);
    x0 += ks2; x1 += k0 + 5u;
    o0 = x0; o1 = x1;
}

// ---------------------------------------------------------------------------
// Kernels
// ---------------------------------------------------------------------------

__global__ void pe_add_k(const float* __restrict__ in, float* __restrict__ out, int total) {
    int t = blockIdx.x * 256 + threadIdx.x;
    if (t >= total) return;
    int d = t % 512;
    int l = (t / 512) % 512;
    float i2 = (float)(d & ~1);
    float div = expf(i2 * (-0.017988946039016f));  // -ln(10000)/512
    float ang = (float)l * div;
    float v = (d & 1) ? cosf(ang) : sinf(ang);
    out[t] = in[t] + v;
}

// fp32 [K][N] -> bf16 [N][K] via 32x32 LDS tile
__global__ __launch_bounds__(256) void transpose_bf16_k(const float* __restrict__ in,
                                                        short* __restrict__ out, int K, int N) {
    __shared__ float tile[32][33];
    int k0 = blockIdx.y * 32, n0 = blockIdx.x * 32;
    int c = threadIdx.x & 31, r0 = threadIdx.x >> 5;
    for (int rr = r0; rr < 32; rr += 8)
        tile[rr][c] = in[(size_t)(k0 + rr) * N + n0 + c];
    __syncthreads();
    for (int rr = r0; rr < 32; rr += 8)
        out[(size_t)(n0 + rr) * K + k0 + c] = f2bf(tile[c][rr]);
}

// dist_w (O,I,H) -> bf16 W2T[o][h*512+i]
__global__ void w2t_k(const float* __restrict__ dw, short* __restrict__ out, int total) {
    int t = blockIdx.x * 256 + threadIdx.x;
    if (t >= total) return;
    int kk = t % 1536;
    int o = t / 1536;
    int h = kk / 512, i = kk % 512;
    out[t] = f2bf(dw[(size_t)o * 1536 + i * 3 + h]);
}

// concat biases bq|bk|bv -> bqkv[1536]
__global__ void bcat_k(const float* __restrict__ b0, const float* __restrict__ b1,
                       const float* __restrict__ b2, float* __restrict__ out) {
    int t = blockIdx.x * 256 + threadIdx.x;
    if (t >= 1536) return;
    out[t] = (t < 512) ? b0[t] : (t < 1024 ? b1[t - 512] : b2[t - 1024]);
}

// bf16 MFMA GEMM, 128x128 block, BK=32; 4 waves, each 64x64 (4x4 MFMA tiles).
__global__ __launch_bounds__(256) void gemm_bf_k(
    const float* __restrict__ A, const short* __restrict__ Bt,
    const float* __restrict__ bias, const float* __restrict__ res,
    float* __restrict__ C, int M, int N, int K, int relu, int ldC) {
    __shared__ short As[128 * 40];
    __shared__ short Bs[128 * 40];
    int tid = threadIdx.x;
    int wave = tid >> 6, lane = tid & 63;
    int wy = wave >> 1, wx = wave & 1;
    int rl = lane & 15, quad = lane >> 4;
    int bm = blockIdx.y * 128, bn = blockIdx.x * 128;

    float4v acc[4][4];
    #pragma unroll
    for (int i = 0; i < 4; i++)
        #pragma unroll
        for (int j = 0; j < 4; j++) acc[i][j] = (float4v){0.f, 0.f, 0.f, 0.f};

    for (int k0 = 0; k0 < K; k0 += 32) {
        #pragma unroll
        for (int it = 0; it < 4; it++) {
            int f = tid + it * 256;
            int row = f >> 3, c4 = f & 7;
            const float4* src = (const float4*)(A + (size_t)(bm + row) * K + k0 + c4 * 4);
            float4 v = *src;
            short4v s = {f2bf(v.x), f2bf(v.y), f2bf(v.z), f2bf(v.w)};
            *(short4v*)&As[row * 40 + c4 * 4] = s;
        }
        #pragma unroll
        for (int it = 0; it < 2; it++) {
            int c = tid + it * 256;
            int n = c >> 2, seg = c & 3;
            const float4* src = (const float4*)(Bt + (size_t)(bn + n) * K + k0 + seg * 8);
            *(float4*)&Bs[n * 40 + seg * 8] = *src;
        }
        __syncthreads();
        short8 a[4], b[4];
        #pragma unroll
        for (int i = 0; i < 4; i++)
            a[i] = *(const short8*)&As[(wy * 64 + i * 16 + rl) * 40 + quad * 8];
        #pragma unroll
        for (int j = 0; j < 4; j++)
            b[j] = *(const short8*)&Bs[(wx * 64 + j * 16 + rl) * 40 + quad * 8];
        #pragma unroll
        for (int i = 0; i < 4; i++)
            #pragma unroll
            for (int j = 0; j < 4; j++)
                acc[i][j] = __builtin_amdgcn_mfma_f32_16x16x32_bf16(a[i], b[j], acc[i][j], 0, 0, 0);
        __syncthreads();
    }
    #pragma unroll
    for (int i = 0; i < 4; i++) {
        #pragma unroll
        for (int r = 0; r < 4; r++) {
            int gm = bm + wy * 64 + i * 16 + quad * 4 + r;
            #pragma unroll
            for (int j = 0; j < 4; j++) {
                int gn = bn + wx * 64 + j * 16 + rl;
                float v = acc[i][j][r];
                if (bias) v += bias[gn];
                if (relu) v = fmaxf(v, 0.f);
                if (res) v += res[(size_t)gm * ldC + gn];
                C[(size_t)gm * ldC + gn] = v;
            }
        }
    }
}

// 64x64-tile variant for small-N GEMMs. 4 waves, each 16x64.
__global__ __launch_bounds__(256) void gemm64_k(
    const float* __restrict__ A, const short* __restrict__ Bt,
    const float* __restrict__ bias, const float* __restrict__ res,
    float* __restrict__ C, int M, int N, int K, int relu, int ldC) {
    __shared__ short As[64 * 40];
    __shared__ short Bs[64 * 40];
    int tid = threadIdx.x;
    int wave = tid >> 6, lane = tid & 63;
    int rl = lane & 15, quad = lane >> 4;
    int bm = blockIdx.y * 64, bn = blockIdx.x * 64;

    float4v acc[4];
    #pragma unroll
    for (int j = 0; j < 4; j++) acc[j] = (float4v){0.f, 0.f, 0.f, 0.f};

    for (int k0 = 0; k0 < K; k0 += 32) {
        #pragma unroll
        for (int it = 0; it < 2; it++) {
            int f = tid + it * 256;
            int row = f >> 3, c4 = f & 7;
            const float4* src = (const float4*)(A + (size_t)(bm + row) * K + k0 + c4 * 4);
            float4 v = *src;
            short4v s = {f2bf(v.x), f2bf(v.y), f2bf(v.z), f2bf(v.w)};
            *(short4v*)&As[row * 40 + c4 * 4] = s;
        }
        {
            int n = tid >> 2, seg = tid & 3;
            const float4* src = (const float4*)(Bt + (size_t)(bn + n) * K + k0 + seg * 8);
            *(float4*)&Bs[n * 40 + seg * 8] = *src;
        }
        __syncthreads();
        short8 a = *(const short8*)&As[(wave * 16 + rl) * 40 + quad * 8];
        short8 b[4];
        #pragma unroll
        for (int j = 0; j < 4; j++)
            b[j] = *(const short8*)&Bs[(j * 16 + rl) * 40 + quad * 8];
        #pragma unroll
        for (int j = 0; j < 4; j++)
            acc[j] = __builtin_amdgcn_mfma_f32_16x16x32_bf16(a, b[j], acc[j], 0, 0, 0);
        __syncthreads();
    }
    #pragma unroll
    for (int r = 0; r < 4; r++) {
        int gm = bm + wave * 16 + quad * 4 + r;
        #pragma unroll
        for (int j = 0; j < 4; j++) {
            int gn = bn + j * 16 + rl;
            float v = acc[j][r];
            if (bias) v += bias[gn];
            if (relu) v = fmaxf(v, 0.f);
            if (res) v += res[(size_t)gm * ldC + gn];
            C[(size_t)gm * ldC + gn] = v;
        }
    }
}

// idx[j] = threefry(rkey, (j, j+size)).second & mask   (H2, verified R1)
__global__ void ridx_k(unsigned k0, unsigned k1, int size, unsigned mask, int* __restrict__ idx) {
    int j = blockIdx.x * 256 + threadIdx.x;
    if (j >= size) return;
    unsigned o0, o1;
    threefry2x32(k0, k1, (unsigned)j, (unsigned)(j + size), o0, o1);
    idx[j] = (int)(o1 & mask);
}

// M[b,h,l] = max_s(Q.K_samp) - sum_s(Q.K_samp)/LK   (rows have stride ld)
__global__ void msamp_k(const float* __restrict__ Qp, const float* __restrict__ Kp,
                        const int* __restrict__ idx, float* __restrict__ Mout,
                        int LQ, int LK, int U, int ld) {
    int t = blockIdx.x * 256 + threadIdx.x;
    int total = 16 * 8 * LQ;
    if (t >= total) return;
    int l = t % LQ;
    int h = (t / LQ) & 7;
    int b = t / (LQ * 8);
    const float4* q = (const float4*)(Qp + ((size_t)(b * LQ + l) * ld + h * 64));
    const float* kb = Kp + ((size_t)b * LK * ld + h * 64);
    float4 qr[16];
    #pragma unroll
    for (int d = 0; d < 16; d++) qr[d] = q[d];
    float mx = -INFINITY, sm = 0.f;
    for (int s = 0; s < U; s++) {
        const float4* kr = (const float4*)(kb + (size_t)idx[l * U + s] * ld);
        float acc = 0.f;
        #pragma unroll
        for (int d = 0; d < 16; d++) {
            float4 kv = kr[d];
            acc += qr[d].x * kv.x + qr[d].y * kv.y + qr[d].z * kv.z + qr[d].w * kv.w;
        }
        mx = fmaxf(mx, acc);
        sm += acc;
    }
    Mout[(size_t)((b * 8) + h) * LQ + l] = mx - sm / (float)LK;
}

// Parallel top-u per (b,h): iterative argmax in LDS, lowest-index tie-break.
__global__ __launch_bounds__(256) void topk_k(const float* __restrict__ M,
                                              int* __restrict__ top, int LQ, int u) {
    __shared__ float vals[512];
    __shared__ float rv[256];
    __shared__ int ri[256];
    int bh = blockIdx.x;
    int tid = threadIdx.x;
    const float* m = M + (size_t)bh * LQ;
    for (int l = tid; l < LQ; l += 256) vals[l] = m[l];
    __syncthreads();
    for (int j = 0; j < u; j++) {
        float best = -INFINITY;
        int bi = LQ;
        for (int l = tid; l < LQ; l += 256) {
            float v = vals[l];
            if (v > best) { best = v; bi = l; }
        }
        rv[tid] = best; ri[tid] = bi;
        __syncthreads();
        for (int s = 128; s > 0; s >>= 1) {
            if (tid < s) {
                float v2 = rv[tid + s]; int i2 = ri[tid + s];
                if (v2 > rv[tid] || (v2 == rv[tid] && i2 < ri[tid])) { rv[tid] = v2; ri[tid] = i2; }
            }
            __syncthreads();
        }
        int sel = ri[0];
        if (tid == 0) {
            top[bh * u + j] = sel;
            vals[sel] = -INFINITY;
        }
        __syncthreads();
    }
}

// vm[b, c] = mean over l of V[b,l,c]  (V rows stride ld)
__global__ void vmean_k(const float* __restrict__ Vp, float* __restrict__ vm, int LK, int ld) {
    int t = blockIdx.x * 256 + threadIdx.x;
    if (t >= 16 * 512) return;
    int c = t % 512;
    int b = t / 512;
    float s = 0.f;
    for (int l = 0; l < LK; l++) s += Vp[(size_t)(b * LK + l) * ld + c];
    vm[t] = s / (float)LK;
}

// ctx[b,l,c] = vm[b,c]
__global__ void ctx_fill_k(const float* __restrict__ vm, float* __restrict__ ctx, int LQ, int total) {
    int t = blockIdx.x * 256 + threadIdx.x;
    if (t >= total) return;
    int c = t % 512;
    int b = t / (512 * LQ);
    ctx[t] = vm[b * 512 + c];
}

// Flash-style ProbSparse attention: one block per (b, h, u-half).
// K/V staged in LDS tiles once per block; scores (fp32) in LDS; wave-per-row
// softmax; PV accumulated in registers. Row r of sc is written/softmaxed/read
// exclusively by wave r%4 (no cross-wave hazard on sc).
__global__ __launch_bounds__(256) void attn_flash_k(
    const float* __restrict__ Qp, const float* __restrict__ Kp, const float* __restrict__ Vp,
    const int* __restrict__ top, float* __restrict__ ctx, int LQ, int LK, int u, int ld) {
    __shared__ float qs[18][64];
    __shared__ int ls[18];
    __shared__ float kv[64][65];
    __shared__ float sc[18][512];
    int bid = blockIdx.x;
    int chunk = bid & 1;  // 2 chunks per (b,h)
    int h = (bid >> 1) & 7;
    int b = bid >> 4;
    int CH = (u + 1) >> 1;
    int r0 = chunk * CH;
    int nr = min(CH, u - r0);
    int tid = threadIdx.x;
    int wave = tid >> 6, lane = tid & 63;

    if (tid < nr) ls[tid] = top[((b * 8) + h) * u + r0 + tid];
    __syncthreads();
    for (int t = tid; t < nr * 64; t += 256) {
        int r = t >> 6, d = t & 63;
        qs[r][d] = Qp[((size_t)(b * LQ + ls[r])) * ld + h * 64 + d];
    }

    int ntile = LK >> 6;
    const float* kbase = Kp + ((size_t)b * LK) * ld + h * 64;
    for (int T = 0; T < ntile; T++) {
        __syncthreads();
        for (int t = tid; t < 4096; t += 256) {
            int kk = t >> 6, d = t & 63;
            kv[kk][d] = kbase[(size_t)(T * 64 + kk) * ld + d];
        }
        __syncthreads();
        for (int p = tid; p < nr * 64; p += 256) {
            int r = p >> 6, kk = p & 63;
            float acc = 0.f;
            #pragma unroll
            for (int d = 0; d < 64; d++) acc += qs[r][d] * kv[kk][d];
            sc[r][T * 64 + kk] = acc * 0.125f;  // 1/sqrt(64)
        }
    }
    // softmax per row (wave r%4 owns row r)
    for (int r = wave; r < nr; r += 4) {
        float mx = -INFINITY;
        for (int k = lane; k < LK; k += 64) mx = fmaxf(mx, sc[r][k]);
        #pragma unroll
        for (int o = 32; o > 0; o >>= 1) mx = fmaxf(mx, __shfl_xor(mx, o));
        float s = 0.f;
        for (int k = lane; k < LK; k += 64) {
            float e = expf(sc[r][k] - mx);
            sc[r][k] = e;
            s += e;
        }
        #pragma unroll
        for (int o = 32; o > 0; o >>= 1) s += __shfl_xor(s, o);
        float inv = 1.0f / s;
        for (int k = lane; k < LK; k += 64) sc[r][k] *= inv;
    }
    // PV
    float acc[5];
    #pragma unroll
    for (int i = 0; i < 5; i++) acc[i] = 0.f;
    const float* vbase = Vp + ((size_t)b * LK) * ld + h * 64;
    for (int T = 0; T < ntile; T++) {
        __syncthreads();
        for (int t = tid; t < 4096; t += 256) {
            int kk = t >> 6, d = t & 63;
            kv[kk][d] = vbase[(size_t)(T * 64 + kk) * ld + d];
        }
        __syncthreads();
        int ri = 0;
        for (int r = wave; r < nr; r += 4, ri++) {
            float a = 0.f;
            #pragma unroll
            for (int kk = 0; kk < 64; kk++) a += sc[r][T * 64 + kk] * kv[kk][lane];
            acc[ri] += a;
        }
    }
    int ri = 0;
    for (int r = wave; r < nr; r += 4, ri++)
        ctx[((size_t)(b * LQ + ls[r])) * 512 + h * 64 + lane] = acc[ri];
}

// per-row layer norm, D=512
__global__ __launch_bounds__(256) void ln_k(const float* __restrict__ in, float* __restrict__ out) {
    __shared__ float red[256];
    int r = blockIdx.x;
    int tid = threadIdx.x;
    const float* x = in + (size_t)r * 512;
    float a = x[tid], b = x[tid + 256];
    red[tid] = a + b;
    __syncthreads();
    for (int s = 128; s > 0; s >>= 1) {
        if (tid < s) red[tid] += red[tid + s];
        __syncthreads();
    }
    float mu = red[0] / 512.f;
    __syncthreads();
    float d1 = a - mu, d2 = b - mu;
    red[tid] = d1 * d1 + d2 * d2;
    __syncthreads();
    for (int s = 128; s > 0; s >>= 1) {
        if (tid < s) red[tid] += red[tid + s];
        __syncthreads();
    }
    float inv = 1.0f / sqrtf(red[0] / 512.f + 1e-5f);
    out[(size_t)r * 512 + tid] = d1 * inv;
    out[(size_t)r * 512 + tid + 256] = d2 * inv;
}

// circular-pad im2col: xc[(b*L+t)*1536 + h*512 + i] = x[b, (t+h-1) mod L, i]
__global__ void xcat_k(const float* __restrict__ x, float* __restrict__ xc, int L, int total) {
    int t = blockIdx.x * 256 + threadIdx.x;
    if (t >= total) return;
    int i = t % 512;
    int h = (t / 512) % 3;
    int bt = t / 1536;
    int tt = bt % L;
    int b = bt / L;
    int src = (tt + h - 1 + L) % L;
    xc[t] = x[(size_t)(b * L + src) * 512 + i];
}

// per-channel mean/var over all rows
__global__ __launch_bounds__(256) void bnstats_k(const float* __restrict__ y,
                                                 float* __restrict__ mu, float* __restrict__ var,
                                                 int rows) {
    __shared__ float red[256];
    int o = blockIdx.x;
    int tid = threadIdx.x;
    float s = 0.f;
    for (int r = tid; r < rows; r += 256) s += y[(size_t)r * 512 + o];
    red[tid] = s;
    __syncthreads();
    for (int st = 128; st > 0; st >>= 1) {
        if (tid < st) red[tid] += red[tid + st];
        __syncthreads();
    }
    float m = red[0] / (float)rows;
    __syncthreads();
    float s2 = 0.f;
    for (int r = tid; r < rows; r += 256) {
        float d = y[(size_t)r * 512 + o] - m;
        s2 += d * d;
    }
    red[tid] = s2;
    __syncthreads();
    for (int st = 128; st > 0; st >>= 1) {
        if (tid < st) red[tid] += red[tid + st];
        __syncthreads();
    }
    if (tid == 0) {
        mu[o] = m;
        var[o] = red[0] / (float)rows;
    }
}

// normalize -> max-pool(3,2,pad1) -> elu (monotone, pool first)
__global__ void elu_pool_k(const float* __restrict__ y, const float* __restrict__ mu,
                           const float* __restrict__ var, float* __restrict__ out,
                           int L, int total) {
    int t = blockIdx.x * 256 + threadIdx.x;
    if (t >= total) return;
    int o = t % 512;
    int tp = (t / 512) % (L / 2);
    int b = t / (512 * (L / 2));
    float mm = mu[o];
    float inv = 1.0f / sqrtf(var[o] + 1e-5f);
    float m = -INFINITY;
    #pragma unroll
    for (int dt = 0; dt < 3; dt++) {
        int tt = 2 * tp - 1 + dt;
        if (tt < 0 || tt >= L) continue;
        float v = (y[(size_t)(b * L + tt) * 512 + o] - mm) * inv;
        m = fmaxf(m, v);
    }
    out[t] = m > 0.f ? m : expm1f(m);
}

// out[r] = dot(x[r,:512], w) + b
__global__ void final_k(const float* __restrict__ x, const float* __restrict__ w,
                        const float* __restrict__ bb, float* __restrict__ out, int rows) {
    int gid = blockIdx.x * 256 + threadIdx.x;
    int wid = gid >> 6;
    int lane = gid & 63;
    if (wid >= rows) return;
    const float* xr = x + (size_t)wid * 512;
    float acc = 0.f;
    for (int k = lane; k < 512; k += 64) acc += xr[k] * w[k];
    for (int off = 32; off > 0; off >>= 1) acc += __shfl_down(acc, off);
    if (lane == 0) out[wid] = acc + bb[0];
}

// ---------------------------------------------------------------------------
// Host driver
// ---------------------------------------------------------------------------

static inline int iceil_log(int L) { return (int)ceil(log((double)L)); }
static inline int imin(int a, int b) { return a < b ? a : b; }

extern "C" void kernel_launch(void* const* d_in, const int* in_sizes, int n_in,
                              void* d_out, int out_size, void* d_ws, size_t ws_size,
                              hipStream_t stream) {
    const float* IN  = (const float*)d_in[0];
    const float* Wq  = (const float*)d_in[1];
    const float* bq  = (const float*)d_in[2];
    const float* Wk  = (const float*)d_in[3];
    const float* bk  = (const float*)d_in[4];
    const float* Wv  = (const float*)d_in[5];
    const float* bv  = (const float*)d_in[6];
    const float* Wo  = (const float*)d_in[7];
    const float* bo  = (const float*)d_in[8];
    const float* ew1 = (const float*)d_in[9];
    const float* eb1 = (const float*)d_in[10];
    const float* ew2 = (const float*)d_in[11];
    const float* eb2 = (const float*)d_in[12];
    const float* dw1 = (const float*)d_in[13];
    const float* db1 = (const float*)d_in[14];
    const float* dw2 = (const float*)d_in[15];
    const float* db2 = (const float*)d_in[16];
    const float* DW  = (const float*)d_in[17];
    const float* db  = (const float*)d_in[18];
    const float* ow  = (const float*)d_in[19];
    const float* ob  = (const float*)d_in[20];
    float* OUT = (float*)d_out;

    float* ws = (float*)d_ws;
    size_t off = 0;
    auto alloc = [&](size_t n) { float* p = ws + off; off += n; return p; };
    float* PE   = alloc(4194304);
    float* QKV  = alloc(12582912);  // [8192][1536]: Q|K|V columns
    float* CTX  = alloc(4194304);
    float* T1   = alloc(4194304);
    float* XLN  = alloc(4194304);
    float* T2   = alloc(4194304);
    float* T3   = alloc(4194304);
    float* HID  = alloc(16777216);
    float* D1   = alloc(2097152);
    float* D2   = alloc(1048576);
    float* Eb   = alloc(524288);
    float* MB   = alloc(65536);
    float* VM   = alloc(8192);
    float* MU   = alloc(512);
    float* VARb = alloc(512);
    float* BQKV = alloc(1536);
    int* IDX  = (int*)alloc(17920);
    int* TOPB = (int*)alloc(4480);
    short* WqkvT = (short*)alloc(393216);  // [1536][512] bf16: Wq|Wk|Wv rows
    short* WoT   = (short*)alloc(131072);
    short* ew1T  = (short*)alloc(524288);
    short* ew2T  = (short*)alloc(524288);
    short* dw1T  = (short*)alloc(524288);
    short* dw2T  = (short*)alloc(524288);
    short* W2T   = (short*)alloc(393216);
    (void)ws_size; (void)n_in; (void)in_sizes; (void)out_size;

    auto gemm128 = [&](const float* A, const short* Bt, const float* bias, const float* res,
                       float* C, int M, int N, int K, int relu, int ldC) {
        dim3 g(N / 128, M / 128);
        gemm_bf_k<<<g, 256, 0, stream>>>(A, Bt, bias, res, C, M, N, K, relu, ldC);
    };
    auto gemm64 = [&](const float* A, const short* Bt, const float* bias, const float* res,
                      float* C, int M, int N, int K, int relu, int ldC) {
        dim3 g(N / 64, M / 64);
        gemm64_k<<<g, 256, 0, stream>>>(A, Bt, bias, res, C, M, N, K, relu, ldC);
    };
    auto tr = [&](const float* W, short* Wt, int K, int N) {
        dim3 g(N / 32, K / 32);
        transpose_bf16_k<<<g, 256, 0, stream>>>(W, Wt, K, N);
    };

    auto attn = [&](const float* qin, const float* kvin, const float* resp, float* outp,
                    int LQ, int LK, int ikey) {
        int Mq = 16 * LQ, Mk = 16 * LK;
        const int ld = 1536;
        float* Qp = QKV;
        float* Kp = QKV + 512;
        float* Vp = QKV + 1024;
        if (qin == kvin) {
            gemm128(qin, WqkvT, BQKV, nullptr, QKV, Mq, 1536, 512, 0, ld);
        } else {
            gemm64(qin, WqkvT, BQKV, nullptr, QKV, Mq, 512, 512, 0, ld);
            gemm64(kvin, WqkvT + 512 * 512, BQKV + 512, nullptr, QKV + 512, Mk, 1024, 512, 0, ld);
        }
        int U = imin(5 * iceil_log(LK), LK);
        int u = imin(5 * iceil_log(LQ), LQ);
        unsigned rk0, rk1;
        threefry2x32(0u, 42u, 0u, (unsigned)ikey, rk0, rk1);
        int size = LQ * U;
        ridx_k<<<(size + 255) / 256, 256, 0, stream>>>(rk0, rk1, size, (unsigned)(LK - 1), IDX);
        int totM = 16 * 8 * LQ;
        msamp_k<<<(totM + 255) / 256, 256, 0, stream>>>(Qp, Kp, IDX, MB, LQ, LK, U, ld);
        topk_k<<<128, 256, 0, stream>>>(MB, TOPB, LQ, u);
        vmean_k<<<(16 * 512 + 255) / 256, 256, 0, stream>>>(Vp, VM, LK, ld);
        int totC = 16 * LQ * 512;
        ctx_fill_k<<<(totC + 255) / 256, 256, 0, stream>>>(VM, CTX, LQ, totC);
        attn_flash_k<<<16 * 8 * 2, 256, 0, stream>>>(Qp, Kp, Vp, TOPB, CTX, LQ, LK, u, ld);
        gemm64(CTX, WoT, bo, resp, outp, Mq, 512, 512, 0, 512);
    };

    auto encoder = [&](const float* X, int L, int ikey, float* OUTenc) {
        int M = 16 * L;
        attn(X, X, X, T1, L, L, ikey);
        ln_k<<<M, 256, 0, stream>>>(T1, XLN);
        gemm128(XLN, ew1T, eb1, nullptr, HID, M, 2048, 512, 1, 2048);
        gemm64(HID, ew2T, eb2, XLN, T2, M, 512, 2048, 0, 512);
        ln_k<<<M, 256, 0, stream>>>(T2, OUTenc);
    };

    auto distill = [&](const float* X, int L, float* OUTd) {
        int M = 16 * L;
        int tot = M * 1536;
        xcat_k<<<(tot + 255) / 256, 256, 0, stream>>>(X, HID, L, tot);
        gemm64(HID, W2T, db, nullptr, CTX, M, 512, 1536, 0, 512);
        bnstats_k<<<512, 256, 0, stream>>>(CTX, MU, VARb, M);
        int toto = 16 * (L / 2) * 512;
        elu_pool_k<<<(toto + 255) / 256, 256, 0, stream>>>(CTX, MU, VARb, OUTd, L, toto);
    };

    // --- weight conversion (once per launch) ---
    tr(Wq, WqkvT, 512, 512);
    tr(Wk, WqkvT + 512 * 512, 512, 512);
    tr(Wv, WqkvT + 1024 * 512, 512, 512);
    tr(Wo, WoT, 512, 512);
    tr(ew1, ew1T, 512, 2048);
    tr(ew2, ew2T, 2048, 512);
    tr(dw1, dw1T, 512, 2048);
    tr(dw2, dw2T, 2048, 512);
    w2t_k<<<(786432 + 255) / 256, 256, 0, stream>>>(DW, W2T, 786432);
    bcat_k<<<6, 256, 0, stream>>>(bq, bk, bv, BQKV);

    // --- forward ---
    int totPE = 16 * 512 * 512;
    pe_add_k<<<(totPE + 255) / 256, 256, 0, stream>>>(IN, PE, totPE);

    encoder(PE, 512, 0, T3); distill(T3, 512, D1);
    encoder(D1, 256, 1, T3); distill(T3, 256, D2);
    encoder(D2, 128, 2, T3); distill(T3, 128, Eb);

    attn(PE, PE, PE, T1, 512, 512, 3);
    attn(T1, Eb, T1, T2, 512, 64, 4);
    gemm128(T2, dw1T, db1, nullptr, HID, 8192, 2048, 512, 1, 2048);
    gemm64(HID, dw2T, db2, T2, T3, 8192, 512, 2048, 0, 512);
    final_k<<<(8192 * 64) / 256, 256, 0, stream>>>(T3, ow, ob, OUT, 8192);
}

// Round 6
// 2076.708 us; speedup vs baseline: 6.9946x; 1.1389x over previous
//
#include <hip/hip_runtime.h>
#include <cstdint>
#include <cmath>

// ---------------------------------------------------------------------------
// Informer forward. Round 6: parallel vmean (R5 showed 5x121us = 25% of
// runtime at 1.4% occupancy — serial 512-row walk per thread).
// jax.random via threefry2x32 (H2 layout, verified R1).
// ---------------------------------------------------------------------------

#define HD __host__ __device__

typedef short short8 __attribute__((ext_vector_type(8)));
typedef short short4v __attribute__((ext_vector_type(4)));
typedef float float4v __attribute__((ext_vector_type(4)));

__device__ inline short f2bf(float f) {  // RNE
    unsigned u = __float_as_uint(f);
    unsigned r = u + 0x7FFFu + ((u >> 16) & 1u);
    return (short)(r >> 16);
}

HD inline unsigned rotl32(unsigned x, int r) { return (x << r) | (x >> (32 - r)); }
HD inline void tfround(unsigned& x0, unsigned& x1, int r) {
    x0 += x1; x1 = rotl32(x1, r); x1 ^= x0;
}
HD inline void threefry2x32(unsigned k0, unsigned k1, unsigned c0, unsigned c1,
                            unsigned& o0, unsigned& o1) {
    unsigned ks2 = k0 ^ k1 ^ 0x1BD11BDAu;
    unsigned x0 = c0 + k0, x1 = c1 + k1;
    tfround(x0, x1, 13); tfround(x0, x1, 15); tfround(x0, x1, 26); tfround(x0, x1, 6);
    x0 += k1; x1 += ks2 + 1u;
    tfround(x0, x1, 17); tfround(x0, x1, 29); tfround(x0, x1, 16); tfround(x0, x1, 24);
    x0 += ks2; x1 += k0 + 2u;
    tfround(x0, x1, 13); tfround(x0, x1, 15); tfround(x0, x1, 26); tfround(x0, x1, 6);
    x0 += k0; x1 += k1 + 3u;
    tfround(x0, x1, 17); tfround(x0, x1, 29); tfround(x0, x1, 16); tfround(x0, x1, 24);
    x0 += k1; x1 += ks2 + 4u;
    tfround(x0, x1, 13); tfround(x0, x1, 15); tfround(x0, x1, 26); tfround(x0, x1, 6);
    x0 += ks2; x1 += k0 + 5u;
    o0 = x0; o1 = x1;
}

// ---------------------------------------------------------------------------
// Kernels
// ---------------------------------------------------------------------------

__global__ void pe_add_k(const float* __restrict__ in, float* __restrict__ out, int total) {
    int t = blockIdx.x * 256 + threadIdx.x;
    if (t >= total) return;
    int d = t % 512;
    int l = (t / 512) % 512;
    float i2 = (float)(d & ~1);
    float div = expf(i2 * (-0.017988946039016f));  // -ln(10000)/512
    float ang = (float)l * div;
    float v = (d & 1) ? cosf(ang) : sinf(ang);
    out[t] = in[t] + v;
}

// fp32 [K][N] -> bf16 [N][K] via 32x32 LDS tile
__global__ __launch_bounds__(256) void transpose_bf16_k(const float* __restrict__ in,
                                                        short* __restrict__ out, int K, int N) {
    __shared__ float tile[32][33];
    int k0 = blockIdx.y * 32, n0 = blockIdx.x * 32;
    int c = threadIdx.x & 31, r0 = threadIdx.x >> 5;
    for (int rr = r0; rr < 32; rr += 8)
        tile[rr][c] = in[(size_t)(k0 + rr) * N + n0 + c];
    __syncthreads();
    for (int rr = r0; rr < 32; rr += 8)
        out[(size_t)(n0 + rr) * K + k0 + c] = f2bf(tile[c][rr]);
}

// dist_w (O,I,H) -> bf16 W2T[o][h*512+i]
__global__ void w2t_k(const float* __restrict__ dw, short* __restrict__ out, int total) {
    int t = blockIdx.x * 256 + threadIdx.x;
    if (t >= total) return;
    int kk = t % 1536;
    int o = t / 1536;
    int h = kk / 512, i = kk % 512;
    out[t] = f2bf(dw[(size_t)o * 1536 + i * 3 + h]);
}

// concat biases bq|bk|bv -> bqkv[1536]
__global__ void bcat_k(const float* __restrict__ b0, const float* __restrict__ b1,
                       const float* __restrict__ b2, float* __restrict__ out) {
    int t = blockIdx.x * 256 + threadIdx.x;
    if (t >= 1536) return;
    out[t] = (t < 512) ? b0[t] : (t < 1024 ? b1[t - 512] : b2[t - 1024]);
}

// bf16 MFMA GEMM, 128x128 block, BK=32; 4 waves, each 64x64 (4x4 MFMA tiles).
__global__ __launch_bounds__(256) void gemm_bf_k(
    const float* __restrict__ A, const short* __restrict__ Bt,
    const float* __restrict__ bias, const float* __restrict__ res,
    float* __restrict__ C, int M, int N, int K, int relu, int ldC) {
    __shared__ short As[128 * 40];
    __shared__ short Bs[128 * 40];
    int tid = threadIdx.x;
    int wave = tid >> 6, lane = tid & 63;
    int wy = wave >> 1, wx = wave & 1;
    int rl = lane & 15, quad = lane >> 4;
    int bm = blockIdx.y * 128, bn = blockIdx.x * 128;

    float4v acc[4][4];
    #pragma unroll
    for (int i = 0; i < 4; i++)
        #pragma unroll
        for (int j = 0; j < 4; j++) acc[i][j] = (float4v){0.f, 0.f, 0.f, 0.f};

    for (int k0 = 0; k0 < K; k0 += 32) {
        #pragma unroll
        for (int it = 0; it < 4; it++) {
            int f = tid + it * 256;
            int row = f >> 3, c4 = f & 7;
            const float4* src = (const float4*)(A + (size_t)(bm + row) * K + k0 + c4 * 4);
            float4 v = *src;
            short4v s = {f2bf(v.x), f2bf(v.y), f2bf(v.z), f2bf(v.w)};
            *(short4v*)&As[row * 40 + c4 * 4] = s;
        }
        #pragma unroll
        for (int it = 0; it < 2; it++) {
            int c = tid + it * 256;
            int n = c >> 2, seg = c & 3;
            const float4* src = (const float4*)(Bt + (size_t)(bn + n) * K + k0 + seg * 8);
            *(float4*)&Bs[n * 40 + seg * 8] = *src;
        }
        __syncthreads();
        short8 a[4], b[4];
        #pragma unroll
        for (int i = 0; i < 4; i++)
            a[i] = *(const short8*)&As[(wy * 64 + i * 16 + rl) * 40 + quad * 8];
        #pragma unroll
        for (int j = 0; j < 4; j++)
            b[j] = *(const short8*)&Bs[(wx * 64 + j * 16 + rl) * 40 + quad * 8];
        #pragma unroll
        for (int i = 0; i < 4; i++)
            #pragma unroll
            for (int j = 0; j < 4; j++)
                acc[i][j] = __builtin_amdgcn_mfma_f32_16x16x32_bf16(a[i], b[j], acc[i][j], 0, 0, 0);
        __syncthreads();
    }
    #pragma unroll
    for (int i = 0; i < 4; i++) {
        #pragma unroll
        for (int r = 0; r < 4; r++) {
            int gm = bm + wy * 64 + i * 16 + quad * 4 + r;
            #pragma unroll
            for (int j = 0; j < 4; j++) {
                int gn = bn + wx * 64 + j * 16 + rl;
                float v = acc[i][j][r];
                if (bias) v += bias[gn];
                if (relu) v = fmaxf(v, 0.f);
                if (res) v += res[(size_t)gm * ldC + gn];
                C[(size_t)gm * ldC + gn] = v;
            }
        }
    }
}

// 64x64-tile variant for small-N GEMMs. 4 waves, each 16x64.
__global__ __launch_bounds__(256) void gemm64_k(
    const float* __restrict__ A, const short* __restrict__ Bt,
    const float* __restrict__ bias, const float* __restrict__ res,
    float* __restrict__ C, int M, int N, int K, int relu, int ldC) {
    __shared__ short As[64 * 40];
    __shared__ short Bs[64 * 40];
    int tid = threadIdx.x;
    int wave = tid >> 6, lane = tid & 63;
    int rl = lane & 15, quad = lane >> 4;
    int bm = blockIdx.y * 64, bn = blockIdx.x * 64;

    float4v acc[4];
    #pragma unroll
    for (int j = 0; j < 4; j++) acc[j] = (float4v){0.f, 0.f, 0.f, 0.f};

    for (int k0 = 0; k0 < K; k0 += 32) {
        #pragma unroll
        for (int it = 0; it < 2; it++) {
            int f = tid + it * 256;
            int row = f >> 3, c4 = f & 7;
            const float4* src = (const float4*)(A + (size_t)(bm + row) * K + k0 + c4 * 4);
            float4 v = *src;
            short4v s = {f2bf(v.x), f2bf(v.y), f2bf(v.z), f2bf(v.w)};
            *(short4v*)&As[row * 40 + c4 * 4] = s;
        }
        {
            int n = tid >> 2, seg = tid & 3;
            const float4* src = (const float4*)(Bt + (size_t)(bn + n) * K + k0 + seg * 8);
            *(float4*)&Bs[n * 40 + seg * 8] = *src;
        }
        __syncthreads();
        short8 a = *(const short8*)&As[(wave * 16 + rl) * 40 + quad * 8];
        short8 b[4];
        #pragma unroll
        for (int j = 0; j < 4; j++)
            b[j] = *(const short8*)&Bs[(j * 16 + rl) * 40 + quad * 8];
        #pragma unroll
        for (int j = 0; j < 4; j++)
            acc[j] = __builtin_amdgcn_mfma_f32_16x16x32_bf16(a, b[j], acc[j], 0, 0, 0);
        __syncthreads();
    }
    #pragma unroll
    for (int r = 0; r < 4; r++) {
        int gm = bm + wave * 16 + quad * 4 + r;
        #pragma unroll
        for (int j = 0; j < 4; j++) {
            int gn = bn + j * 16 + rl;
            float v = acc[j][r];
            if (bias) v += bias[gn];
            if (relu) v = fmaxf(v, 0.f);
            if (res) v += res[(size_t)gm * ldC + gn];
            C[(size_t)gm * ldC + gn] = v;
        }
    }
}

// idx[j] = threefry(rkey, (j, j+size)).second & mask   (H2, verified R1)
__global__ void ridx_k(unsigned k0, unsigned k1, int size, unsigned mask, int* __restrict__ idx) {
    int j = blockIdx.x * 256 + threadIdx.x;
    if (j >= size) return;
    unsigned o0, o1;
    threefry2x32(k0, k1, (unsigned)j, (unsigned)(j + size), o0, o1);
    idx[j] = (int)(o1 & mask);
}

// M[b,h,l] = max_s(Q.K_samp) - sum_s(Q.K_samp)/LK   (rows have stride ld)
__global__ void msamp_k(const float* __restrict__ Qp, const float* __restrict__ Kp,
                        const int* __restrict__ idx, float* __restrict__ Mout,
                        int LQ, int LK, int U, int ld) {
    int t = blockIdx.x * 256 + threadIdx.x;
    int total = 16 * 8 * LQ;
    if (t >= total) return;
    int l = t % LQ;
    int h = (t / LQ) & 7;
    int b = t / (LQ * 8);
    const float4* q = (const float4*)(Qp + ((size_t)(b * LQ + l) * ld + h * 64));
    const float* kb = Kp + ((size_t)b * LK * ld + h * 64);
    float4 qr[16];
    #pragma unroll
    for (int d = 0; d < 16; d++) qr[d] = q[d];
    float mx = -INFINITY, sm = 0.f;
    for (int s = 0; s < U; s++) {
        const float4* kr = (const float4*)(kb + (size_t)idx[l * U + s] * ld);
        float acc = 0.f;
        #pragma unroll
        for (int d = 0; d < 16; d++) {
            float4 kv = kr[d];
            acc += qr[d].x * kv.x + qr[d].y * kv.y + qr[d].z * kv.z + qr[d].w * kv.w;
        }
        mx = fmaxf(mx, acc);
        sm += acc;
    }
    Mout[(size_t)((b * 8) + h) * LQ + l] = mx - sm / (float)LK;
}

// Parallel top-u per (b,h): iterative argmax in LDS, lowest-index tie-break.
__global__ __launch_bounds__(256) void topk_k(const float* __restrict__ M,
                                              int* __restrict__ top, int LQ, int u) {
    __shared__ float vals[512];
    __shared__ float rv[256];
    __shared__ int ri[256];
    int bh = blockIdx.x;
    int tid = threadIdx.x;
    const float* m = M + (size_t)bh * LQ;
    for (int l = tid; l < LQ; l += 256) vals[l] = m[l];
    __syncthreads();
    for (int j = 0; j < u; j++) {
        float best = -INFINITY;
        int bi = LQ;
        for (int l = tid; l < LQ; l += 256) {
            float v = vals[l];
            if (v > best) { best = v; bi = l; }
        }
        rv[tid] = best; ri[tid] = bi;
        __syncthreads();
        for (int s = 128; s > 0; s >>= 1) {
            if (tid < s) {
                float v2 = rv[tid + s]; int i2 = ri[tid + s];
                if (v2 > rv[tid] || (v2 == rv[tid] && i2 < ri[tid])) { rv[tid] = v2; ri[tid] = i2; }
            }
            __syncthreads();
        }
        int sel = ri[0];
        if (tid == 0) {
            top[bh * u + j] = sel;
            vals[sel] = -INFINITY;
        }
        __syncthreads();
    }
}

// vm[b,c] = mean over l of V[b,l,c]; parallel over l (R6 fix: was 1.4%-occ
// serial walk, 121us/dispatch). 256 threads = 32 c x 8 l-groups.
// grid: (512/32 = 16 c-chunks, 16 b).
__global__ __launch_bounds__(256) void vmean_k(const float* __restrict__ Vp,
                                               float* __restrict__ vm, int LK, int ld) {
    __shared__ float red[8][33];
    int b = blockIdx.y;
    int c0 = blockIdx.x * 32;
    int ci = threadIdx.x & 31, g = threadIdx.x >> 5;
    const float* base = Vp + (size_t)b * LK * ld + c0 + ci;
    float s = 0.f;
    for (int l = g; l < LK; l += 8) s += base[(size_t)l * ld];
    red[g][ci] = s;
    __syncthreads();
    if (threadIdx.x < 32) {
        float t = 0.f;
        #pragma unroll
        for (int g2 = 0; g2 < 8; g2++) t += red[g2][threadIdx.x];
        vm[b * 512 + c0 + threadIdx.x] = t / (float)LK;
    }
}

// ctx[b,l,c] = vm[b,c]
__global__ void ctx_fill_k(const float* __restrict__ vm, float* __restrict__ ctx, int LQ, int total) {
    int t = blockIdx.x * 256 + threadIdx.x;
    if (t >= total) return;
    int c = t % 512;
    int b = t / (512 * LQ);
    ctx[t] = vm[b * 512 + c];
}

// Flash-style ProbSparse attention: one block per (b, h, u-half).
__global__ __launch_bounds__(256) void attn_flash_k(
    const float* __restrict__ Qp, const float* __restrict__ Kp, const float* __restrict__ Vp,
    const int* __restrict__ top, float* __restrict__ ctx, int LQ, int LK, int u, int ld) {
    __shared__ float qs[18][64];
    __shared__ int ls[18];
    __shared__ float kv[64][65];
    __shared__ float sc[18][512];
    int bid = blockIdx.x;
    int chunk = bid & 1;  // 2 chunks per (b,h)
    int h = (bid >> 1) & 7;
    int b = bid >> 4;
    int CH = (u + 1) >> 1;
    int r0 = chunk * CH;
    int nr = min(CH, u - r0);
    int tid = threadIdx.x;
    int wave = tid >> 6, lane = tid & 63;

    if (tid < nr) ls[tid] = top[((b * 8) + h) * u + r0 + tid];
    __syncthreads();
    for (int t = tid; t < nr * 64; t += 256) {
        int r = t >> 6, d = t & 63;
        qs[r][d] = Qp[((size_t)(b * LQ + ls[r])) * ld + h * 64 + d];
    }

    int ntile = LK >> 6;
    const float* kbase = Kp + ((size_t)b * LK) * ld + h * 64;
    for (int T = 0; T < ntile; T++) {
        __syncthreads();
        for (int t = tid; t < 4096; t += 256) {
            int kk = t >> 6, d = t & 63;
            kv[kk][d] = kbase[(size_t)(T * 64 + kk) * ld + d];
        }
        __syncthreads();
        for (int p = tid; p < nr * 64; p += 256) {
            int r = p >> 6, kk = p & 63;
            float acc = 0.f;
            #pragma unroll
            for (int d = 0; d < 64; d++) acc += qs[r][d] * kv[kk][d];
            sc[r][T * 64 + kk] = acc * 0.125f;  // 1/sqrt(64)
        }
    }
    // softmax per row (wave r%4 owns row r)
    for (int r = wave; r < nr; r += 4) {
        float mx = -INFINITY;
        for (int k = lane; k < LK; k += 64) mx = fmaxf(mx, sc[r][k]);
        #pragma unroll
        for (int o = 32; o > 0; o >>= 1) mx = fmaxf(mx, __shfl_xor(mx, o));
        float s = 0.f;
        for (int k = lane; k < LK; k += 64) {
            float e = expf(sc[r][k] - mx);
            sc[r][k] = e;
            s += e;
        }
        #pragma unroll
        for (int o = 32; o > 0; o >>= 1) s += __shfl_xor(s, o);
        float inv = 1.0f / s;
        for (int k = lane; k < LK; k += 64) sc[r][k] *= inv;
    }
    // PV
    float acc[5];
    #pragma unroll
    for (int i = 0; i < 5; i++) acc[i] = 0.f;
    const float* vbase = Vp + ((size_t)b * LK) * ld + h * 64;
    for (int T = 0; T < ntile; T++) {
        __syncthreads();
        for (int t = tid; t < 4096; t += 256) {
            int kk = t >> 6, d = t & 63;
            kv[kk][d] = vbase[(size_t)(T * 64 + kk) * ld + d];
        }
        __syncthreads();
        int ri = 0;
        for (int r = wave; r < nr; r += 4, ri++) {
            float a = 0.f;
            #pragma unroll
            for (int kk = 0; kk < 64; kk++) a += sc[r][T * 64 + kk] * kv[kk][lane];
            acc[ri] += a;
        }
    }
    int ri = 0;
    for (int r = wave; r < nr; r += 4, ri++)
        ctx[((size_t)(b * LQ + ls[r])) * 512 + h * 64 + lane] = acc[ri];
}

// per-row layer norm, D=512
__global__ __launch_bounds__(256) void ln_k(const float* __restrict__ in, float* __restrict__ out) {
    __shared__ float red[256];
    int r = blockIdx.x;
    int tid = threadIdx.x;
    const float* x = in + (size_t)r * 512;
    float a = x[tid], b = x[tid + 256];
    red[tid] = a + b;
    __syncthreads();
    for (int s = 128; s > 0; s >>= 1) {
        if (tid < s) red[tid] += red[tid + s];
        __syncthreads();
    }
    float mu = red[0] / 512.f;
    __syncthreads();
    float d1 = a - mu, d2 = b - mu;
    red[tid] = d1 * d1 + d2 * d2;
    __syncthreads();
    for (int s = 128; s > 0; s >>= 1) {
        if (tid < s) red[tid] += red[tid + s];
        __syncthreads();
    }
    float inv = 1.0f / sqrtf(red[0] / 512.f + 1e-5f);
    out[(size_t)r * 512 + tid] = d1 * inv;
    out[(size_t)r * 512 + tid + 256] = d2 * inv;
}

// circular-pad im2col: xc[(b*L+t)*1536 + h*512 + i] = x[b, (t+h-1) mod L, i]
__global__ void xcat_k(const float* __restrict__ x, float* __restrict__ xc, int L, int total) {
    int t = blockIdx.x * 256 + threadIdx.x;
    if (t >= total) return;
    int i = t % 512;
    int h = (t / 512) % 3;
    int bt = t / 1536;
    int tt = bt % L;
    int b = bt / L;
    int src = (tt + h - 1 + L) % L;
    xc[t] = x[(size_t)(b * L + src) * 512 + i];
}

// per-channel mean/var over all rows
__global__ __launch_bounds__(256) void bnstats_k(const float* __restrict__ y,
                                                 float* __restrict__ mu, float* __restrict__ var,
                                                 int rows) {
    __shared__ float red[256];
    int o = blockIdx.x;
    int tid = threadIdx.x;
    float s = 0.f;
    for (int r = tid; r < rows; r += 256) s += y[(size_t)r * 512 + o];
    red[tid] = s;
    __syncthreads();
    for (int st = 128; st > 0; st >>= 1) {
        if (tid < st) red[tid] += red[tid + st];
        __syncthreads();
    }
    float m = red[0] / (float)rows;
    __syncthreads();
    float s2 = 0.f;
    for (int r = tid; r < rows; r += 256) {
        float d = y[(size_t)r * 512 + o] - m;
        s2 += d * d;
    }
    red[tid] = s2;
    __syncthreads();
    for (int st = 128; st > 0; st >>= 1) {
        if (tid < st) red[tid] += red[tid + st];
        __syncthreads();
    }
    if (tid == 0) {
        mu[o] = m;
        var[o] = red[0] / (float)rows;
    }
}

// normalize -> max-pool(3,2,pad1) -> elu (monotone, pool first)
__global__ void elu_pool_k(const float* __restrict__ y, const float* __restrict__ mu,
                           const float* __restrict__ var, float* __restrict__ out,
                           int L, int total) {
    int t = blockIdx.x * 256 + threadIdx.x;
    if (t >= total) return;
    int o = t % 512;
    int tp = (t / 512) % (L / 2);
    int b = t / (512 * (L / 2));
    float mm = mu[o];
    float inv = 1.0f / sqrtf(var[o] + 1e-5f);
    float m = -INFINITY;
    #pragma unroll
    for (int dt = 0; dt < 3; dt++) {
        int tt = 2 * tp - 1 + dt;
        if (tt < 0 || tt >= L) continue;
        float v = (y[(size_t)(b * L + tt) * 512 + o] - mm) * inv;
        m = fmaxf(m, v);
    }
    out[t] = m > 0.f ? m : expm1f(m);
}

// out[r] = dot(x[r,:512], w) + b
__global__ void final_k(const float* __restrict__ x, const float* __restrict__ w,
                        const float* __restrict__ bb, float* __restrict__ out, int rows) {
    int gid = blockIdx.x * 256 + threadIdx.x;
    int wid = gid >> 6;
    int lane = gid & 63;
    if (wid >= rows) return;
    const float* xr = x + (size_t)wid * 512;
    float acc = 0.f;
    for (int k = lane; k < 512; k += 64) acc += xr[k] * w[k];
    for (int off = 32; off > 0; off >>= 1) acc += __shfl_down(acc, off);
    if (lane == 0) out[wid] = acc + bb[0];
}

// ---------------------------------------------------------------------------
// Host driver
// ---------------------------------------------------------------------------

static inline int iceil_log(int L) { return (int)ceil(log((double)L)); }
static inline int imin(int a, int b) { return a < b ? a : b; }

extern "C" void kernel_launch(void* const* d_in, const int* in_sizes, int n_in,
                              void* d_out, int out_size, void* d_ws, size_t ws_size,
                              hipStream_t stream) {
    const float* IN  = (const float*)d_in[0];
    const float* Wq  = (const float*)d_in[1];
    const float* bq  = (const float*)d_in[2];
    const float* Wk  = (const float*)d_in[3];
    const float* bk  = (const float*)d_in[4];
    const float* Wv  = (const float*)d_in[5];
    const float* bv  = (const float*)d_in[6];
    const float* Wo  = (const float*)d_in[7];
    const float* bo  = (const float*)d_in[8];
    const float* ew1 = (const float*)d_in[9];
    const float* eb1 = (const float*)d_in[10];
    const float* ew2 = (const float*)d_in[11];
    const float* eb2 = (const float*)d_in[12];
    const float* dw1 = (const float*)d_in[13];
    const float* db1 = (const float*)d_in[14];
    const float* dw2 = (const float*)d_in[15];
    const float* db2 = (const float*)d_in[16];
    const float* DW  = (const float*)d_in[17];
    const float* db  = (const float*)d_in[18];
    const float* ow  = (const float*)d_in[19];
    const float* ob  = (const float*)d_in[20];
    float* OUT = (float*)d_out;

    float* ws = (float*)d_ws;
    size_t off = 0;
    auto alloc = [&](size_t n) { float* p = ws + off; off += n; return p; };
    float* PE   = alloc(4194304);
    float* QKV  = alloc(12582912);  // [8192][1536]: Q|K|V columns
    float* CTX  = alloc(4194304);
    float* T1   = alloc(4194304);
    float* XLN  = alloc(4194304);
    float* T2   = alloc(4194304);
    float* T3   = alloc(4194304);
    float* HID  = alloc(16777216);
    float* D1   = alloc(2097152);
    float* D2   = alloc(1048576);
    float* Eb   = alloc(524288);
    float* MB   = alloc(65536);
    float* VM   = alloc(8192);
    float* MU   = alloc(512);
    float* VARb = alloc(512);
    float* BQKV = alloc(1536);
    int* IDX  = (int*)alloc(17920);
    int* TOPB = (int*)alloc(4480);
    short* WqkvT = (short*)alloc(393216);  // [1536][512] bf16: Wq|Wk|Wv rows
    short* WoT   = (short*)alloc(131072);
    short* ew1T  = (short*)alloc(524288);
    short* ew2T  = (short*)alloc(524288);
    short* dw1T  = (short*)alloc(524288);
    short* dw2T  = (short*)alloc(524288);
    short* W2T   = (short*)alloc(393216);
    (void)ws_size; (void)n_in; (void)in_sizes; (void)out_size;

    auto gemm128 = [&](const float* A, const short* Bt, const float* bias, const float* res,
                       float* C, int M, int N, int K, int relu, int ldC) {
        dim3 g(N / 128, M / 128);
        gemm_bf_k<<<g, 256, 0, stream>>>(A, Bt, bias, res, C, M, N, K, relu, ldC);
    };
    auto gemm64 = [&](const float* A, const short* Bt, const float* bias, const float* res,
                      float* C, int M, int N, int K, int relu, int ldC) {
        dim3 g(N / 64, M / 64);
        gemm64_k<<<g, 256, 0, stream>>>(A, Bt, bias, res, C, M, N, K, relu, ldC);
    };
    auto tr = [&](const float* W, short* Wt, int K, int N) {
        dim3 g(N / 32, K / 32);
        transpose_bf16_k<<<g, 256, 0, stream>>>(W, Wt, K, N);
    };

    auto attn = [&](const float* qin, const float* kvin, const float* resp, float* outp,
                    int LQ, int LK, int ikey) {
        int Mq = 16 * LQ, Mk = 16 * LK;
        const int ld = 1536;
        float* Qp = QKV;
        float* Kp = QKV + 512;
        float* Vp = QKV + 1024;
        if (qin == kvin) {
            gemm128(qin, WqkvT, BQKV, nullptr, QKV, Mq, 1536, 512, 0, ld);
        } else {
            gemm64(qin, WqkvT, BQKV, nullptr, QKV, Mq, 512, 512, 0, ld);
            gemm64(kvin, WqkvT + 512 * 512, BQKV + 512, nullptr, QKV + 512, Mk, 1024, 512, 0, ld);
        }
        int U = imin(5 * iceil_log(LK), LK);
        int u = imin(5 * iceil_log(LQ), LQ);
        unsigned rk0, rk1;
        threefry2x32(0u, 42u, 0u, (unsigned)ikey, rk0, rk1);
        int size = LQ * U;
        ridx_k<<<(size + 255) / 256, 256, 0, stream>>>(rk0, rk1, size, (unsigned)(LK - 1), IDX);
        int totM = 16 * 8 * LQ;
        msamp_k<<<(totM + 255) / 256, 256, 0, stream>>>(Qp, Kp, IDX, MB, LQ, LK, U, ld);
        topk_k<<<128, 256, 0, stream>>>(MB, TOPB, LQ, u);
        vmean_k<<<dim3(16, 16), 256, 0, stream>>>(Vp, VM, LK, ld);
        int totC = 16 * LQ * 512;
        ctx_fill_k<<<(totC + 255) / 256, 256, 0, stream>>>(VM, CTX, LQ, totC);
        attn_flash_k<<<16 * 8 * 2, 256, 0, stream>>>(Qp, Kp, Vp, TOPB, CTX, LQ, LK, u, ld);
        gemm64(CTX, WoT, bo, resp, outp, Mq, 512, 512, 0, 512);
    };

    auto encoder = [&](const float* X, int L, int ikey, float* OUTenc) {
        int M = 16 * L;
        attn(X, X, X, T1, L, L, ikey);
        ln_k<<<M, 256, 0, stream>>>(T1, XLN);
        gemm128(XLN, ew1T, eb1, nullptr, HID, M, 2048, 512, 1, 2048);
        gemm64(HID, ew2T, eb2, XLN, T2, M, 512, 2048, 0, 512);
        ln_k<<<M, 256, 0, stream>>>(T2, OUTenc);
    };

    auto distill = [&](const float* X, int L, float* OUTd) {
        int M = 16 * L;
        int tot = M * 1536;
        xcat_k<<<(tot + 255) / 256, 256, 0, stream>>>(X, HID, L, tot);
        gemm64(HID, W2T, db, nullptr, CTX, M, 512, 1536, 0, 512);
        bnstats_k<<<512, 256, 0, stream>>>(CTX, MU, VARb, M);
        int toto = 16 * (L / 2) * 512;
        elu_pool_k<<<(toto + 255) / 256, 256, 0, stream>>>(CTX, MU, VARb, OUTd, L, toto);
    };

    // --- weight conversion (once per launch) ---
    tr(Wq, WqkvT, 512, 512);
    tr(Wk, WqkvT + 512 * 512, 512, 512);
    tr(Wv, WqkvT + 1024 * 512, 512, 512);
    tr(Wo, WoT, 512, 512);
    tr(ew1, ew1T, 512, 2048);
    tr(ew2, ew2T, 2048, 512);
    tr(dw1, dw1T, 512, 2048);
    tr(dw2, dw2T, 2048, 512);
    w2t_k<<<(786432 + 255) / 256, 256, 0, stream>>>(DW, W2T, 786432);
    bcat_k<<<6, 256, 0, stream>>>(bq, bk, bv, BQKV);

    // --- forward ---
    int totPE = 16 * 512 * 512;
    pe_add_k<<<(totPE + 255) / 256, 256, 0, stream>>>(IN, PE, totPE);

    encoder(PE, 512, 0, T3); distill(T3, 512, D1);
    encoder(D1, 256, 1, T3); distill(T3, 256, D2);
    encoder(D2, 128, 2, T3); distill(T3, 128, Eb);

    attn(PE, PE, PE, T1, 512, 512, 3);
    attn(T1, Eb, T1, T2, 512, 64, 4);
    gemm128(T2, dw1T, db1, nullptr, HID, 8192, 2048, 512, 1, 2048);
    gemm64(HID, dw2T, db2, T2, T3, 8192, 512, 2048, 0, 512);
    final_k<<<(8192 * 64) / 256, 256, 0, stream>>>(T3, ow, ob, OUT, 8192);
}

// Round 7
// 2017.564 us; speedup vs baseline: 7.1997x; 1.0293x over previous
//
#include <hip/hip_runtime.h>
#include <cstdint>
#include <cmath>

// ---------------------------------------------------------------------------
// Informer forward. Round 7: msamp 4-way sample-split (R6 profile: 5x93us at
// 10% occupancy — grid capped at 1 block/CU with 35-deep serial gather chain).
// jax.random via threefry2x32 (H2 layout, verified R1).
// ---------------------------------------------------------------------------

#define HD __host__ __device__

typedef short short8 __attribute__((ext_vector_type(8)));
typedef short short4v __attribute__((ext_vector_type(4)));
typedef float float4v __attribute__((ext_vector_type(4)));

__device__ inline short f2bf(float f) {  // RNE
    unsigned u = __float_as_uint(f);
    unsigned r = u + 0x7FFFu + ((u >> 16) & 1u);
    return (short)(r >> 16);
}

HD inline unsigned rotl32(unsigned x, int r) { return (x << r) | (x >> (32 - r)); }
HD inline void tfround(unsigned& x0, unsigned& x1, int r) {
    x0 += x1; x1 = rotl32(x1, r); x1 ^= x0;
}
HD inline void threefry2x32(unsigned k0, unsigned k1, unsigned c0, unsigned c1,
                            unsigned& o0, unsigned& o1) {
    unsigned ks2 = k0 ^ k1 ^ 0x1BD11BDAu;
    unsigned x0 = c0 + k0, x1 = c1 + k1;
    tfround(x0, x1, 13); tfround(x0, x1, 15); tfround(x0, x1, 26); tfround(x0, x1, 6);
    x0 += k1; x1 += ks2 + 1u;
    tfround(x0, x1, 17); tfround(x0, x1, 29); tfround(x0, x1, 16); tfround(x0, x1, 24);
    x0 += ks2; x1 += k0 + 2u;
    tfround(x0, x1, 13); tfround(x0, x1, 15); tfround(x0, x1, 26); tfround(x0, x1, 6);
    x0 += k0; x1 += k1 + 3u;
    tfround(x0, x1, 17); tfround(x0, x1, 29); tfround(x0, x1, 16); tfround(x0, x1, 24);
    x0 += k1; x1 += ks2 + 4u;
    tfround(x0, x1, 13); tfround(x0, x1, 15); tfround(x0, x1, 26); tfround(x0, x1, 6);
    x0 += ks2; x1 += k0 + 5u;
    o0 = x0; o1 = x1;
}

// ---------------------------------------------------------------------------
// Kernels
// ---------------------------------------------------------------------------

__global__ void pe_add_k(const float* __restrict__ in, float* __restrict__ out, int total) {
    int t = blockIdx.x * 256 + threadIdx.x;
    if (t >= total) return;
    int d = t % 512;
    int l = (t / 512) % 512;
    float i2 = (float)(d & ~1);
    float div = expf(i2 * (-0.017988946039016f));  // -ln(10000)/512
    float ang = (float)l * div;
    float v = (d & 1) ? cosf(ang) : sinf(ang);
    out[t] = in[t] + v;
}

// fp32 [K][N] -> bf16 [N][K] via 32x32 LDS tile
__global__ __launch_bounds__(256) void transpose_bf16_k(const float* __restrict__ in,
                                                        short* __restrict__ out, int K, int N) {
    __shared__ float tile[32][33];
    int k0 = blockIdx.y * 32, n0 = blockIdx.x * 32;
    int c = threadIdx.x & 31, r0 = threadIdx.x >> 5;
    for (int rr = r0; rr < 32; rr += 8)
        tile[rr][c] = in[(size_t)(k0 + rr) * N + n0 + c];
    __syncthreads();
    for (int rr = r0; rr < 32; rr += 8)
        out[(size_t)(n0 + rr) * K + k0 + c] = f2bf(tile[c][rr]);
}

// dist_w (O,I,H) -> bf16 W2T[o][h*512+i]
__global__ void w2t_k(const float* __restrict__ dw, short* __restrict__ out, int total) {
    int t = blockIdx.x * 256 + threadIdx.x;
    if (t >= total) return;
    int kk = t % 1536;
    int o = t / 1536;
    int h = kk / 512, i = kk % 512;
    out[t] = f2bf(dw[(size_t)o * 1536 + i * 3 + h]);
}

// concat biases bq|bk|bv -> bqkv[1536]
__global__ void bcat_k(const float* __restrict__ b0, const float* __restrict__ b1,
                       const float* __restrict__ b2, float* __restrict__ out) {
    int t = blockIdx.x * 256 + threadIdx.x;
    if (t >= 1536) return;
    out[t] = (t < 512) ? b0[t] : (t < 1024 ? b1[t - 512] : b2[t - 1024]);
}

// bf16 MFMA GEMM, 128x128 block, BK=32; 4 waves, each 64x64 (4x4 MFMA tiles).
__global__ __launch_bounds__(256) void gemm_bf_k(
    const float* __restrict__ A, const short* __restrict__ Bt,
    const float* __restrict__ bias, const float* __restrict__ res,
    float* __restrict__ C, int M, int N, int K, int relu, int ldC) {
    __shared__ short As[128 * 40];
    __shared__ short Bs[128 * 40];
    int tid = threadIdx.x;
    int wave = tid >> 6, lane = tid & 63;
    int wy = wave >> 1, wx = wave & 1;
    int rl = lane & 15, quad = lane >> 4;
    int bm = blockIdx.y * 128, bn = blockIdx.x * 128;

    float4v acc[4][4];
    #pragma unroll
    for (int i = 0; i < 4; i++)
        #pragma unroll
        for (int j = 0; j < 4; j++) acc[i][j] = (float4v){0.f, 0.f, 0.f, 0.f};

    for (int k0 = 0; k0 < K; k0 += 32) {
        #pragma unroll
        for (int it = 0; it < 4; it++) {
            int f = tid + it * 256;
            int row = f >> 3, c4 = f & 7;
            const float4* src = (const float4*)(A + (size_t)(bm + row) * K + k0 + c4 * 4);
            float4 v = *src;
            short4v s = {f2bf(v.x), f2bf(v.y), f2bf(v.z), f2bf(v.w)};
            *(short4v*)&As[row * 40 + c4 * 4] = s;
        }
        #pragma unroll
        for (int it = 0; it < 2; it++) {
            int c = tid + it * 256;
            int n = c >> 2, seg = c & 3;
            const float4* src = (const float4*)(Bt + (size_t)(bn + n) * K + k0 + seg * 8);
            *(float4*)&Bs[n * 40 + seg * 8] = *src;
        }
        __syncthreads();
        short8 a[4], b[4];
        #pragma unroll
        for (int i = 0; i < 4; i++)
            a[i] = *(const short8*)&As[(wy * 64 + i * 16 + rl) * 40 + quad * 8];
        #pragma unroll
        for (int j = 0; j < 4; j++)
            b[j] = *(const short8*)&Bs[(wx * 64 + j * 16 + rl) * 40 + quad * 8];
        #pragma unroll
        for (int i = 0; i < 4; i++)
            #pragma unroll
            for (int j = 0; j < 4; j++)
                acc[i][j] = __builtin_amdgcn_mfma_f32_16x16x32_bf16(a[i], b[j], acc[i][j], 0, 0, 0);
        __syncthreads();
    }
    #pragma unroll
    for (int i = 0; i < 4; i++) {
        #pragma unroll
        for (int r = 0; r < 4; r++) {
            int gm = bm + wy * 64 + i * 16 + quad * 4 + r;
            #pragma unroll
            for (int j = 0; j < 4; j++) {
                int gn = bn + wx * 64 + j * 16 + rl;
                float v = acc[i][j][r];
                if (bias) v += bias[gn];
                if (relu) v = fmaxf(v, 0.f);
                if (res) v += res[(size_t)gm * ldC + gn];
                C[(size_t)gm * ldC + gn] = v;
            }
        }
    }
}

// 64x64-tile variant for small-N GEMMs. 4 waves, each 16x64.
__global__ __launch_bounds__(256) void gemm64_k(
    const float* __restrict__ A, const short* __restrict__ Bt,
    const float* __restrict__ bias, const float* __restrict__ res,
    float* __restrict__ C, int M, int N, int K, int relu, int ldC) {
    __shared__ short As[64 * 40];
    __shared__ short Bs[64 * 40];
    int tid = threadIdx.x;
    int wave = tid >> 6, lane = tid & 63;
    int rl = lane & 15, quad = lane >> 4;
    int bm = blockIdx.y * 64, bn = blockIdx.x * 64;

    float4v acc[4];
    #pragma unroll
    for (int j = 0; j < 4; j++) acc[j] = (float4v){0.f, 0.f, 0.f, 0.f};

    for (int k0 = 0; k0 < K; k0 += 32) {
        #pragma unroll
        for (int it = 0; it < 2; it++) {
            int f = tid + it * 256;
            int row = f >> 3, c4 = f & 7;
            const float4* src = (const float4*)(A + (size_t)(bm + row) * K + k0 + c4 * 4);
            float4 v = *src;
            short4v s = {f2bf(v.x), f2bf(v.y), f2bf(v.z), f2bf(v.w)};
            *(short4v*)&As[row * 40 + c4 * 4] = s;
        }
        {
            int n = tid >> 2, seg = tid & 3;
            const float4* src = (const float4*)(Bt + (size_t)(bn + n) * K + k0 + seg * 8);
            *(float4*)&Bs[n * 40 + seg * 8] = *src;
        }
        __syncthreads();
        short8 a = *(const short8*)&As[(wave * 16 + rl) * 40 + quad * 8];
        short8 b[4];
        #pragma unroll
        for (int j = 0; j < 4; j++)
            b[j] = *(const short8*)&Bs[(j * 16 + rl) * 40 + quad * 8];
        #pragma unroll
        for (int j = 0; j < 4; j++)
            acc[j] = __builtin_amdgcn_mfma_f32_16x16x32_bf16(a, b[j], acc[j], 0, 0, 0);
        __syncthreads();
    }
    #pragma unroll
    for (int r = 0; r < 4; r++) {
        int gm = bm + wave * 16 + quad * 4 + r;
        #pragma unroll
        for (int j = 0; j < 4; j++) {
            int gn = bn + j * 16 + rl;
            float v = acc[j][r];
            if (bias) v += bias[gn];
            if (relu) v = fmaxf(v, 0.f);
            if (res) v += res[(size_t)gm * ldC + gn];
            C[(size_t)gm * ldC + gn] = v;
        }
    }
}

// idx[j] = threefry(rkey, (j, j+size)).second & mask   (H2, verified R1)
__global__ void ridx_k(unsigned k0, unsigned k1, int size, unsigned mask, int* __restrict__ idx) {
    int j = blockIdx.x * 256 + threadIdx.x;
    if (j >= size) return;
    unsigned o0, o1;
    threefry2x32(k0, k1, (unsigned)j, (unsigned)(j + size), o0, o1);
    idx[j] = (int)(o1 & mask);
}

// M[b,h,l] = max_s(Q.K_samp) - sum_s(Q.K_samp)/LK   (rows have stride ld)
// R7: 4 lanes per (b,h,l), each phase p handles samples s=p,p+4,...; quad
// shfl_xor combines max/sum. 4x occupancy, 4x shorter latency chain.
__global__ void msamp_k(const float* __restrict__ Qp, const float* __restrict__ Kp,
                        const int* __restrict__ idx, float* __restrict__ Mout,
                        int LQ, int LK, int U, int ld) {
    int t = blockIdx.x * 256 + threadIdx.x;
    int total = 16 * 8 * LQ * 4;
    if (t >= total) return;
    int p = t & 3;
    int rest = t >> 2;
    int l = rest % LQ;
    int h = (rest / LQ) & 7;
    int b = rest / (LQ * 8);
    const float4* q = (const float4*)(Qp + ((size_t)(b * LQ + l) * ld + h * 64));
    const float* kb = Kp + ((size_t)b * LK * ld + h * 64);
    float4 qr[16];
    #pragma unroll
    for (int d = 0; d < 16; d++) qr[d] = q[d];
    float mx = -INFINITY, sm = 0.f;
    for (int s = p; s < U; s += 4) {
        const float4* kr = (const float4*)(kb + (size_t)idx[l * U + s] * ld);
        float acc = 0.f;
        #pragma unroll
        for (int d = 0; d < 16; d++) {
            float4 kv = kr[d];
            acc += qr[d].x * kv.x + qr[d].y * kv.y + qr[d].z * kv.z + qr[d].w * kv.w;
        }
        mx = fmaxf(mx, acc);
        sm += acc;
    }
    mx = fmaxf(mx, __shfl_xor(mx, 1));
    mx = fmaxf(mx, __shfl_xor(mx, 2));
    sm += __shfl_xor(sm, 1);
    sm += __shfl_xor(sm, 2);
    if (p == 0)
        Mout[(size_t)((b * 8) + h) * LQ + l] = mx - sm / (float)LK;
}

// Parallel top-u per (b,h): iterative argmax in LDS, lowest-index tie-break.
__global__ __launch_bounds__(256) void topk_k(const float* __restrict__ M,
                                              int* __restrict__ top, int LQ, int u) {
    __shared__ float vals[512];
    __shared__ float rv[256];
    __shared__ int ri[256];
    int bh = blockIdx.x;
    int tid = threadIdx.x;
    const float* m = M + (size_t)bh * LQ;
    for (int l = tid; l < LQ; l += 256) vals[l] = m[l];
    __syncthreads();
    for (int j = 0; j < u; j++) {
        float best = -INFINITY;
        int bi = LQ;
        for (int l = tid; l < LQ; l += 256) {
            float v = vals[l];
            if (v > best) { best = v; bi = l; }
        }
        rv[tid] = best; ri[tid] = bi;
        __syncthreads();
        for (int s = 128; s > 0; s >>= 1) {
            if (tid < s) {
                float v2 = rv[tid + s]; int i2 = ri[tid + s];
                if (v2 > rv[tid] || (v2 == rv[tid] && i2 < ri[tid])) { rv[tid] = v2; ri[tid] = i2; }
            }
            __syncthreads();
        }
        int sel = ri[0];
        if (tid == 0) {
            top[bh * u + j] = sel;
            vals[sel] = -INFINITY;
        }
        __syncthreads();
    }
}

// vm[b,c] = mean over l of V[b,l,c]; parallel over l. grid (16 c-chunks, 16 b).
__global__ __launch_bounds__(256) void vmean_k(const float* __restrict__ Vp,
                                               float* __restrict__ vm, int LK, int ld) {
    __shared__ float red[8][33];
    int b = blockIdx.y;
    int c0 = blockIdx.x * 32;
    int ci = threadIdx.x & 31, g = threadIdx.x >> 5;
    const float* base = Vp + (size_t)b * LK * ld + c0 + ci;
    float s = 0.f;
    for (int l = g; l < LK; l += 8) s += base[(size_t)l * ld];
    red[g][ci] = s;
    __syncthreads();
    if (threadIdx.x < 32) {
        float t = 0.f;
        #pragma unroll
        for (int g2 = 0; g2 < 8; g2++) t += red[g2][threadIdx.x];
        vm[b * 512 + c0 + threadIdx.x] = t / (float)LK;
    }
}

// ctx[b,l,c] = vm[b,c]
__global__ void ctx_fill_k(const float* __restrict__ vm, float* __restrict__ ctx, int LQ, int total) {
    int t = blockIdx.x * 256 + threadIdx.x;
    if (t >= total) return;
    int c = t % 512;
    int b = t / (512 * LQ);
    ctx[t] = vm[b * 512 + c];
}

// Flash-style ProbSparse attention: one block per (b, h, u-half).
__global__ __launch_bounds__(256) void attn_flash_k(
    const float* __restrict__ Qp, const float* __restrict__ Kp, const float* __restrict__ Vp,
    const int* __restrict__ top, float* __restrict__ ctx, int LQ, int LK, int u, int ld) {
    __shared__ float qs[18][64];
    __shared__ int ls[18];
    __shared__ float kv[64][65];
    __shared__ float sc[18][512];
    int bid = blockIdx.x;
    int chunk = bid & 1;  // 2 chunks per (b,h)
    int h = (bid >> 1) & 7;
    int b = bid >> 4;
    int CH = (u + 1) >> 1;
    int r0 = chunk * CH;
    int nr = min(CH, u - r0);
    int tid = threadIdx.x;
    int wave = tid >> 6, lane = tid & 63;

    if (tid < nr) ls[tid] = top[((b * 8) + h) * u + r0 + tid];
    __syncthreads();
    for (int t = tid; t < nr * 64; t += 256) {
        int r = t >> 6, d = t & 63;
        qs[r][d] = Qp[((size_t)(b * LQ + ls[r])) * ld + h * 64 + d];
    }

    int ntile = LK >> 6;
    const float* kbase = Kp + ((size_t)b * LK) * ld + h * 64;
    for (int T = 0; T < ntile; T++) {
        __syncthreads();
        for (int t = tid; t < 4096; t += 256) {
            int kk = t >> 6, d = t & 63;
            kv[kk][d] = kbase[(size_t)(T * 64 + kk) * ld + d];
        }
        __syncthreads();
        for (int p = tid; p < nr * 64; p += 256) {
            int r = p >> 6, kk = p & 63;
            float acc = 0.f;
            #pragma unroll
            for (int d = 0; d < 64; d++) acc += qs[r][d] * kv[kk][d];
            sc[r][T * 64 + kk] = acc * 0.125f;  // 1/sqrt(64)
        }
    }
    // softmax per row (wave r%4 owns row r)
    for (int r = wave; r < nr; r += 4) {
        float mx = -INFINITY;
        for (int k = lane; k < LK; k += 64) mx = fmaxf(mx, sc[r][k]);
        #pragma unroll
        for (int o = 32; o > 0; o >>= 1) mx = fmaxf(mx, __shfl_xor(mx, o));
        float s = 0.f;
        for (int k = lane; k < LK; k += 64) {
            float e = expf(sc[r][k] - mx);
            sc[r][k] = e;
            s += e;
        }
        #pragma unroll
        for (int o = 32; o > 0; o >>= 1) s += __shfl_xor(s, o);
        float inv = 1.0f / s;
        for (int k = lane; k < LK; k += 64) sc[r][k] *= inv;
    }
    // PV
    float acc[5];
    #pragma unroll
    for (int i = 0; i < 5; i++) acc[i] = 0.f;
    const float* vbase = Vp + ((size_t)b * LK) * ld + h * 64;
    for (int T = 0; T < ntile; T++) {
        __syncthreads();
        for (int t = tid; t < 4096; t += 256) {
            int kk = t >> 6, d = t & 63;
            kv[kk][d] = vbase[(size_t)(T * 64 + kk) * ld + d];
        }
        __syncthreads();
        int ri = 0;
        for (int r = wave; r < nr; r += 4, ri++) {
            float a = 0.f;
            #pragma unroll
            for (int kk = 0; kk < 64; kk++) a += sc[r][T * 64 + kk] * kv[kk][lane];
            acc[ri] += a;
        }
    }
    int ri = 0;
    for (int r = wave; r < nr; r += 4, ri++)
        ctx[((size_t)(b * LQ + ls[r])) * 512 + h * 64 + lane] = acc[ri];
}

// per-row layer norm, D=512
__global__ __launch_bounds__(256) void ln_k(const float* __restrict__ in, float* __restrict__ out) {
    __shared__ float red[256];
    int r = blockIdx.x;
    int tid = threadIdx.x;
    const float* x = in + (size_t)r * 512;
    float a = x[tid], b = x[tid + 256];
    red[tid] = a + b;
    __syncthreads();
    for (int s = 128; s > 0; s >>= 1) {
        if (tid < s) red[tid] += red[tid + s];
        __syncthreads();
    }
    float mu = red[0] / 512.f;
    __syncthreads();
    float d1 = a - mu, d2 = b - mu;
    red[tid] = d1 * d1 + d2 * d2;
    __syncthreads();
    for (int s = 128; s > 0; s >>= 1) {
        if (tid < s) red[tid] += red[tid + s];
        __syncthreads();
    }
    float inv = 1.0f / sqrtf(red[0] / 512.f + 1e-5f);
    out[(size_t)r * 512 + tid] = d1 * inv;
    out[(size_t)r * 512 + tid + 256] = d2 * inv;
}

// circular-pad im2col: xc[(b*L+t)*1536 + h*512 + i] = x[b, (t+h-1) mod L, i]
__global__ void xcat_k(const float* __restrict__ x, float* __restrict__ xc, int L, int total) {
    int t = blockIdx.x * 256 + threadIdx.x;
    if (t >= total) return;
    int i = t % 512;
    int h = (t / 512) % 3;
    int bt = t / 1536;
    int tt = bt % L;
    int b = bt / L;
    int src = (tt + h - 1 + L) % L;
    xc[t] = x[(size_t)(b * L + src) * 512 + i];
}

// per-channel mean/var over all rows
__global__ __launch_bounds__(256) void bnstats_k(const float* __restrict__ y,
                                                 float* __restrict__ mu, float* __restrict__ var,
                                                 int rows) {
    __shared__ float red[256];
    int o = blockIdx.x;
    int tid = threadIdx.x;
    float s = 0.f;
    for (int r = tid; r < rows; r += 256) s += y[(size_t)r * 512 + o];
    red[tid] = s;
    __syncthreads();
    for (int st = 128; st > 0; st >>= 1) {
        if (tid < st) red[tid] += red[tid + st];
        __syncthreads();
    }
    float m = red[0] / (float)rows;
    __syncthreads();
    float s2 = 0.f;
    for (int r = tid; r < rows; r += 256) {
        float d = y[(size_t)r * 512 + o] - m;
        s2 += d * d;
    }
    red[tid] = s2;
    __syncthreads();
    for (int st = 128; st > 0; st >>= 1) {
        if (tid < st) red[tid] += red[tid + st];
        __syncthreads();
    }
    if (tid == 0) {
        mu[o] = m;
        var[o] = red[0] / (float)rows;
    }
}

// normalize -> max-pool(3,2,pad1) -> elu (monotone, pool first)
__global__ void elu_pool_k(const float* __restrict__ y, const float* __restrict__ mu,
                           const float* __restrict__ var, float* __restrict__ out,
                           int L, int total) {
    int t = blockIdx.x * 256 + threadIdx.x;
    if (t >= total) return;
    int o = t % 512;
    int tp = (t / 512) % (L / 2);
    int b = t / (512 * (L / 2));
    float mm = mu[o];
    float inv = 1.0f / sqrtf(var[o] + 1e-5f);
    float m = -INFINITY;
    #pragma unroll
    for (int dt = 0; dt < 3; dt++) {
        int tt = 2 * tp - 1 + dt;
        if (tt < 0 || tt >= L) continue;
        float v = (y[(size_t)(b * L + tt) * 512 + o] - mm) * inv;
        m = fmaxf(m, v);
    }
    out[t] = m > 0.f ? m : expm1f(m);
}

// out[r] = dot(x[r,:512], w) + b
__global__ void final_k(const float* __restrict__ x, const float* __restrict__ w,
                        const float* __restrict__ bb, float* __restrict__ out, int rows) {
    int gid = blockIdx.x * 256 + threadIdx.x;
    int wid = gid >> 6;
    int lane = gid & 63;
    if (wid >= rows) return;
    const float* xr = x + (size_t)wid * 512;
    float acc = 0.f;
    for (int k = lane; k < 512; k += 64) acc += xr[k] * w[k];
    for (int off = 32; off > 0; off >>= 1) acc += __shfl_down(acc, off);
    if (lane == 0) out[wid] = acc + bb[0];
}

// ---------------------------------------------------------------------------
// Host driver
// ---------------------------------------------------------------------------

static inline int iceil_log(int L) { return (int)ceil(log((double)L)); }
static inline int imin(int a, int b) { return a < b ? a : b; }

extern "C" void kernel_launch(void* const* d_in, const int* in_sizes, int n_in,
                              void* d_out, int out_size, void* d_ws, size_t ws_size,
                              hipStream_t stream) {
    const float* IN  = (const float*)d_in[0];
    const float* Wq  = (const float*)d_in[1];
    const float* bq  = (const float*)d_in[2];
    const float* Wk  = (const float*)d_in[3];
    const float* bk  = (const float*)d_in[4];
    const float* Wv  = (const float*)d_in[5];
    const float* bv  = (const float*)d_in[6];
    const float* Wo  = (const float*)d_in[7];
    const float* bo  = (const float*)d_in[8];
    const float* ew1 = (const float*)d_in[9];
    const float* eb1 = (const float*)d_in[10];
    const float* ew2 = (const float*)d_in[11];
    const float* eb2 = (const float*)d_in[12];
    const float* dw1 = (const float*)d_in[13];
    const float* db1 = (const float*)d_in[14];
    const float* dw2 = (const float*)d_in[15];
    const float* db2 = (const float*)d_in[16];
    const float* DW  = (const float*)d_in[17];
    const float* db  = (const float*)d_in[18];
    const float* ow  = (const float*)d_in[19];
    const float* ob  = (const float*)d_in[20];
    float* OUT = (float*)d_out;

    float* ws = (float*)d_ws;
    size_t off = 0;
    auto alloc = [&](size_t n) { float* p = ws + off; off += n; return p; };
    float* PE   = alloc(4194304);
    float* QKV  = alloc(12582912);  // [8192][1536]: Q|K|V columns
    float* CTX  = alloc(4194304);
    float* T1   = alloc(4194304);
    float* XLN  = alloc(4194304);
    float* T2   = alloc(4194304);
    float* T3   = alloc(4194304);
    float* HID  = alloc(16777216);
    float* D1   = alloc(2097152);
    float* D2   = alloc(1048576);
    float* Eb   = alloc(524288);
    float* MB   = alloc(65536);
    float* VM   = alloc(8192);
    float* MU   = alloc(512);
    float* VARb = alloc(512);
    float* BQKV = alloc(1536);
    int* IDX  = (int*)alloc(17920);
    int* TOPB = (int*)alloc(4480);
    short* WqkvT = (short*)alloc(393216);  // [1536][512] bf16: Wq|Wk|Wv rows
    short* WoT   = (short*)alloc(131072);
    short* ew1T  = (short*)alloc(524288);
    short* ew2T  = (short*)alloc(524288);
    short* dw1T  = (short*)alloc(524288);
    short* dw2T  = (short*)alloc(524288);
    short* W2T   = (short*)alloc(393216);
    (void)ws_size; (void)n_in; (void)in_sizes; (void)out_size;

    auto gemm128 = [&](const float* A, const short* Bt, const float* bias, const float* res,
                       float* C, int M, int N, int K, int relu, int ldC) {
        dim3 g(N / 128, M / 128);
        gemm_bf_k<<<g, 256, 0, stream>>>(A, Bt, bias, res, C, M, N, K, relu, ldC);
    };
    auto gemm64 = [&](const float* A, const short* Bt, const float* bias, const float* res,
                      float* C, int M, int N, int K, int relu, int ldC) {
        dim3 g(N / 64, M / 64);
        gemm64_k<<<g, 256, 0, stream>>>(A, Bt, bias, res, C, M, N, K, relu, ldC);
    };
    auto tr = [&](const float* W, short* Wt, int K, int N) {
        dim3 g(N / 32, K / 32);
        transpose_bf16_k<<<g, 256, 0, stream>>>(W, Wt, K, N);
    };

    auto attn = [&](const float* qin, const float* kvin, const float* resp, float* outp,
                    int LQ, int LK, int ikey) {
        int Mq = 16 * LQ, Mk = 16 * LK;
        const int ld = 1536;
        float* Qp = QKV;
        float* Kp = QKV + 512;
        float* Vp = QKV + 1024;
        if (qin == kvin) {
            gemm128(qin, WqkvT, BQKV, nullptr, QKV, Mq, 1536, 512, 0, ld);
        } else {
            gemm64(qin, WqkvT, BQKV, nullptr, QKV, Mq, 512, 512, 0, ld);
            gemm64(kvin, WqkvT + 512 * 512, BQKV + 512, nullptr, QKV + 512, Mk, 1024, 512, 0, ld);
        }
        int U = imin(5 * iceil_log(LK), LK);
        int u = imin(5 * iceil_log(LQ), LQ);
        unsigned rk0, rk1;
        threefry2x32(0u, 42u, 0u, (unsigned)ikey, rk0, rk1);
        int size = LQ * U;
        ridx_k<<<(size + 255) / 256, 256, 0, stream>>>(rk0, rk1, size, (unsigned)(LK - 1), IDX);
        int totM = 16 * 8 * LQ * 4;
        msamp_k<<<(totM + 255) / 256, 256, 0, stream>>>(Qp, Kp, IDX, MB, LQ, LK, U, ld);
        topk_k<<<128, 256, 0, stream>>>(MB, TOPB, LQ, u);
        vmean_k<<<dim3(16, 16), 256, 0, stream>>>(Vp, VM, LK, ld);
        int totC = 16 * LQ * 512;
        ctx_fill_k<<<(totC + 255) / 256, 256, 0, stream>>>(VM, CTX, LQ, totC);
        attn_flash_k<<<16 * 8 * 2, 256, 0, stream>>>(Qp, Kp, Vp, TOPB, CTX, LQ, LK, u, ld);
        gemm64(CTX, WoT, bo, resp, outp, Mq, 512, 512, 0, 512);
    };

    auto encoder = [&](const float* X, int L, int ikey, float* OUTenc) {
        int M = 16 * L;
        attn(X, X, X, T1, L, L, ikey);
        ln_k<<<M, 256, 0, stream>>>(T1, XLN);
        gemm128(XLN, ew1T, eb1, nullptr, HID, M, 2048, 512, 1, 2048);
        gemm64(HID, ew2T, eb2, XLN, T2, M, 512, 2048, 0, 512);
        ln_k<<<M, 256, 0, stream>>>(T2, OUTenc);
    };

    auto distill = [&](const float* X, int L, float* OUTd) {
        int M = 16 * L;
        int tot = M * 1536;
        xcat_k<<<(tot + 255) / 256, 256, 0, stream>>>(X, HID, L, tot);
        gemm64(HID, W2T, db, nullptr, CTX, M, 512, 1536, 0, 512);
        bnstats_k<<<512, 256, 0, stream>>>(CTX, MU, VARb, M);
        int toto = 16 * (L / 2) * 512;
        elu_pool_k<<<(toto + 255) / 256, 256, 0, stream>>>(CTX, MU, VARb, OUTd, L, toto);
    };

    // --- weight conversion (once per launch) ---
    tr(Wq, WqkvT, 512, 512);
    tr(Wk, WqkvT + 512 * 512, 512, 512);
    tr(Wv, WqkvT + 1024 * 512, 512, 512);
    tr(Wo, WoT, 512, 512);
    tr(ew1, ew1T, 512, 2048);
    tr(ew2, ew2T, 2048, 512);
    tr(dw1, dw1T, 512, 2048);
    tr(dw2, dw2T, 2048, 512);
    w2t_k<<<(786432 + 255) / 256, 256, 0, stream>>>(DW, W2T, 786432);
    bcat_k<<<6, 256, 0, stream>>>(bq, bk, bv, BQKV);

    // --- forward ---
    int totPE = 16 * 512 * 512;
    pe_add_k<<<(totPE + 255) / 256, 256, 0, stream>>>(IN, PE, totPE);

    encoder(PE, 512, 0, T3); distill(T3, 512, D1);
    encoder(D1, 256, 1, T3); distill(T3, 256, D2);
    encoder(D2, 128, 2, T3); distill(T3, 128, Eb);

    attn(PE, PE, PE, T1, 512, 512, 3);
    attn(T1, Eb, T1, T2, 512, 64, 4);
    gemm128(T2, dw1T, db1, nullptr, HID, 8192, 2048, 512, 1, 2048);
    gemm64(HID, dw2T, db2, T2, T3, 8192, 512, 2048, 0, 512);
    final_k<<<(8192 * 64) / 256, 256, 0, stream>>>(T3, ow, ob, OUT, 8192);
}

// Round 8
// 1874.620 us; speedup vs baseline: 7.7486x; 1.0763x over previous
//
#include <hip/hip_runtime.h>
#include <cstdint>
#include <cmath>

// ---------------------------------------------------------------------------
// Informer forward. Round 8: msamp K-slab staged in LDS (R7 post-mortem:
// random K-gather is L2-miss bound at 185 MB HBM/dispatch; K per (b,h) is
// 131 KB -> fits LDS, fetched once, gathers become LDS reads at stride-65
// rows for bank spread). jax.random via threefry2x32 (H2, verified R1).
// ---------------------------------------------------------------------------

#define HD __host__ __device__

typedef short short8 __attribute__((ext_vector_type(8)));
typedef short short4v __attribute__((ext_vector_type(4)));
typedef float float4v __attribute__((ext_vector_type(4)));

__device__ inline short f2bf(float f) {  // RNE
    unsigned u = __float_as_uint(f);
    unsigned r = u + 0x7FFFu + ((u >> 16) & 1u);
    return (short)(r >> 16);
}

HD inline unsigned rotl32(unsigned x, int r) { return (x << r) | (x >> (32 - r)); }
HD inline void tfround(unsigned& x0, unsigned& x1, int r) {
    x0 += x1; x1 = rotl32(x1, r); x1 ^= x0;
}
HD inline void threefry2x32(unsigned k0, unsigned k1, unsigned c0, unsigned c1,
                            unsigned& o0, unsigned& o1) {
    unsigned ks2 = k0 ^ k1 ^ 0x1BD11BDAu;
    unsigned x0 = c0 + k0, x1 = c1 + k1;
    tfround(x0, x1, 13); tfround(x0, x1, 15); tfround(x0, x1, 26); tfround(x0, x1, 6);
    x0 += k1; x1 += ks2 + 1u;
    tfround(x0, x1, 17); tfround(x0, x1, 29); tfround(x0, x1, 16); tfround(x0, x1, 24);
    x0 += ks2; x1 += k0 + 2u;
    tfround(x0, x1, 13); tfround(x0, x1, 15); tfround(x0, x1, 26); tfround(x0, x1, 6);
    x0 += k0; x1 += k1 + 3u;
    tfround(x0, x1, 17); tfround(x0, x1, 29); tfround(x0, x1, 16); tfround(x0, x1, 24);
    x0 += k1; x1 += ks2 + 4u;
    tfround(x0, x1, 13); tfround(x0, x1, 15); tfround(x0, x1, 26); tfround(x0, x1, 6);
    x0 += ks2; x1 += k0 + 5u;
    o0 = x0; o1 = x1;
}

// ---------------------------------------------------------------------------
// Kernels
// ---------------------------------------------------------------------------

__global__ void pe_add_k(const float* __restrict__ in, float* __restrict__ out, int total) {
    int t = blockIdx.x * 256 + threadIdx.x;
    if (t >= total) return;
    int d = t % 512;
    int l = (t / 512) % 512;
    float i2 = (float)(d & ~1);
    float div = expf(i2 * (-0.017988946039016f));  // -ln(10000)/512
    float ang = (float)l * div;
    float v = (d & 1) ? cosf(ang) : sinf(ang);
    out[t] = in[t] + v;
}

// fp32 [K][N] -> bf16 [N][K] via 32x32 LDS tile
__global__ __launch_bounds__(256) void transpose_bf16_k(const float* __restrict__ in,
                                                        short* __restrict__ out, int K, int N) {
    __shared__ float tile[32][33];
    int k0 = blockIdx.y * 32, n0 = blockIdx.x * 32;
    int c = threadIdx.x & 31, r0 = threadIdx.x >> 5;
    for (int rr = r0; rr < 32; rr += 8)
        tile[rr][c] = in[(size_t)(k0 + rr) * N + n0 + c];
    __syncthreads();
    for (int rr = r0; rr < 32; rr += 8)
        out[(size_t)(n0 + rr) * K + k0 + c] = f2bf(tile[c][rr]);
}

// dist_w (O,I,H) -> bf16 W2T[o][h*512+i]
__global__ void w2t_k(const float* __restrict__ dw, short* __restrict__ out, int total) {
    int t = blockIdx.x * 256 + threadIdx.x;
    if (t >= total) return;
    int kk = t % 1536;
    int o = t / 1536;
    int h = kk / 512, i = kk % 512;
    out[t] = f2bf(dw[(size_t)o * 1536 + i * 3 + h]);
}

// concat biases bq|bk|bv -> bqkv[1536]
__global__ void bcat_k(const float* __restrict__ b0, const float* __restrict__ b1,
                       const float* __restrict__ b2, float* __restrict__ out) {
    int t = blockIdx.x * 256 + threadIdx.x;
    if (t >= 1536) return;
    out[t] = (t < 512) ? b0[t] : (t < 1024 ? b1[t - 512] : b2[t - 1024]);
}

// bf16 MFMA GEMM, 128x128 block, BK=32; 4 waves, each 64x64 (4x4 MFMA tiles).
__global__ __launch_bounds__(256) void gemm_bf_k(
    const float* __restrict__ A, const short* __restrict__ Bt,
    const float* __restrict__ bias, const float* __restrict__ res,
    float* __restrict__ C, int M, int N, int K, int relu, int ldC) {
    __shared__ short As[128 * 40];
    __shared__ short Bs[128 * 40];
    int tid = threadIdx.x;
    int wave = tid >> 6, lane = tid & 63;
    int wy = wave >> 1, wx = wave & 1;
    int rl = lane & 15, quad = lane >> 4;
    int bm = blockIdx.y * 128, bn = blockIdx.x * 128;

    float4v acc[4][4];
    #pragma unroll
    for (int i = 0; i < 4; i++)
        #pragma unroll
        for (int j = 0; j < 4; j++) acc[i][j] = (float4v){0.f, 0.f, 0.f, 0.f};

    for (int k0 = 0; k0 < K; k0 += 32) {
        #pragma unroll
        for (int it = 0; it < 4; it++) {
            int f = tid + it * 256;
            int row = f >> 3, c4 = f & 7;
            const float4* src = (const float4*)(A + (size_t)(bm + row) * K + k0 + c4 * 4);
            float4 v = *src;
            short4v s = {f2bf(v.x), f2bf(v.y), f2bf(v.z), f2bf(v.w)};
            *(short4v*)&As[row * 40 + c4 * 4] = s;
        }
        #pragma unroll
        for (int it = 0; it < 2; it++) {
            int c = tid + it * 256;
            int n = c >> 2, seg = c & 3;
            const float4* src = (const float4*)(Bt + (size_t)(bn + n) * K + k0 + seg * 8);
            *(float4*)&Bs[n * 40 + seg * 8] = *src;
        }
        __syncthreads();
        short8 a[4], b[4];
        #pragma unroll
        for (int i = 0; i < 4; i++)
            a[i] = *(const short8*)&As[(wy * 64 + i * 16 + rl) * 40 + quad * 8];
        #pragma unroll
        for (int j = 0; j < 4; j++)
            b[j] = *(const short8*)&Bs[(wx * 64 + j * 16 + rl) * 40 + quad * 8];
        #pragma unroll
        for (int i = 0; i < 4; i++)
            #pragma unroll
            for (int j = 0; j < 4; j++)
                acc[i][j] = __builtin_amdgcn_mfma_f32_16x16x32_bf16(a[i], b[j], acc[i][j], 0, 0, 0);
        __syncthreads();
    }
    #pragma unroll
    for (int i = 0; i < 4; i++) {
        #pragma unroll
        for (int r = 0; r < 4; r++) {
            int gm = bm + wy * 64 + i * 16 + quad * 4 + r;
            #pragma unroll
            for (int j = 0; j < 4; j++) {
                int gn = bn + wx * 64 + j * 16 + rl;
                float v = acc[i][j][r];
                if (bias) v += bias[gn];
                if (relu) v = fmaxf(v, 0.f);
                if (res) v += res[(size_t)gm * ldC + gn];
                C[(size_t)gm * ldC + gn] = v;
            }
        }
    }
}

// 64x64-tile variant for small-N GEMMs. 4 waves, each 16x64.
__global__ __launch_bounds__(256) void gemm64_k(
    const float* __restrict__ A, const short* __restrict__ Bt,
    const float* __restrict__ bias, const float* __restrict__ res,
    float* __restrict__ C, int M, int N, int K, int relu, int ldC) {
    __shared__ short As[64 * 40];
    __shared__ short Bs[64 * 40];
    int tid = threadIdx.x;
    int wave = tid >> 6, lane = tid & 63;
    int rl = lane & 15, quad = lane >> 4;
    int bm = blockIdx.y * 64, bn = blockIdx.x * 64;

    float4v acc[4];
    #pragma unroll
    for (int j = 0; j < 4; j++) acc[j] = (float4v){0.f, 0.f, 0.f, 0.f};

    for (int k0 = 0; k0 < K; k0 += 32) {
        #pragma unroll
        for (int it = 0; it < 2; it++) {
            int f = tid + it * 256;
            int row = f >> 3, c4 = f & 7;
            const float4* src = (const float4*)(A + (size_t)(bm + row) * K + k0 + c4 * 4);
            float4 v = *src;
            short4v s = {f2bf(v.x), f2bf(v.y), f2bf(v.z), f2bf(v.w)};
            *(short4v*)&As[row * 40 + c4 * 4] = s;
        }
        {
            int n = tid >> 2, seg = tid & 3;
            const float4* src = (const float4*)(Bt + (size_t)(bn + n) * K + k0 + seg * 8);
            *(float4*)&Bs[n * 40 + seg * 8] = *src;
        }
        __syncthreads();
        short8 a = *(const short8*)&As[(wave * 16 + rl) * 40 + quad * 8];
        short8 b[4];
        #pragma unroll
        for (int j = 0; j < 4; j++)
            b[j] = *(const short8*)&Bs[(j * 16 + rl) * 40 + quad * 8];
        #pragma unroll
        for (int j = 0; j < 4; j++)
            acc[j] = __builtin_amdgcn_mfma_f32_16x16x32_bf16(a, b[j], acc[j], 0, 0, 0);
        __syncthreads();
    }
    #pragma unroll
    for (int r = 0; r < 4; r++) {
        int gm = bm + wave * 16 + quad * 4 + r;
        #pragma unroll
        for (int j = 0; j < 4; j++) {
            int gn = bn + j * 16 + rl;
            float v = acc[j][r];
            if (bias) v += bias[gn];
            if (relu) v = fmaxf(v, 0.f);
            if (res) v += res[(size_t)gm * ldC + gn];
            C[(size_t)gm * ldC + gn] = v;
        }
    }
}

// idx[j] = threefry(rkey, (j, j+size)).second & mask   (H2, verified R1)
__global__ void ridx_k(unsigned k0, unsigned k1, int size, unsigned mask, int* __restrict__ idx) {
    int j = blockIdx.x * 256 + threadIdx.x;
    if (j >= size) return;
    unsigned o0, o1;
    threefry2x32(k0, k1, (unsigned)j, (unsigned)(j + size), o0, o1);
    idx[j] = (int)(o1 & mask);
}

// msamp, K-slab in LDS. One block per (b, h, l-half); grid 16*8*2 = 256.
// LDS rows stride 65 (65 % 32 == 1) -> random-row gathers spread banks.
// Serial s-loop per thread == R6 fp32 summation order.
extern __shared__ float kslab[];
__global__ __launch_bounds__(256) void msamp_lds_k(
    const float* __restrict__ Qp, const float* __restrict__ Kp,
    const int* __restrict__ idx, float* __restrict__ Mout,
    int LQ, int LK, int U, int ld) {
    int bid = blockIdx.x;
    int half = bid & 1;
    int bh = bid >> 1;
    int h = bh & 7, b = bh >> 3;
    const float* kbase = Kp + (size_t)b * LK * ld + h * 64;
    for (int t = threadIdx.x; t < LK * 16; t += 256) {
        int r = t >> 4, seg = t & 15;
        float4 v = *(const float4*)(kbase + (size_t)r * ld + seg * 4);
        float* dst = &kslab[r * 65 + seg * 4];
        dst[0] = v.x; dst[1] = v.y; dst[2] = v.z; dst[3] = v.w;
    }
    __syncthreads();
    int halfL = LQ >> 1;
    for (int li = threadIdx.x; li < halfL; li += 256) {
        int l = half * halfL + li;
        const float4* q = (const float4*)(Qp + (size_t)(b * LQ + l) * ld + h * 64);
        float qr[64];
        #pragma unroll
        for (int d4 = 0; d4 < 16; d4++) {
            float4 v = q[d4];
            qr[4 * d4] = v.x; qr[4 * d4 + 1] = v.y; qr[4 * d4 + 2] = v.z; qr[4 * d4 + 3] = v.w;
        }
        const int* ip = idx + l * U;
        float mx = -INFINITY, sm = 0.f;
        for (int s = 0; s < U; s++) {
            const float* kr = &kslab[ip[s] * 65];
            float acc = 0.f;
            #pragma unroll
            for (int d = 0; d < 64; d++) acc += qr[d] * kr[d];
            mx = fmaxf(mx, acc);
            sm += acc;
        }
        Mout[(size_t)bh * LQ + l] = mx - sm / (float)LK;
    }
}

// Fallback msamp (R7 style) if large dynamic-LDS attribute fails.
__global__ void msamp_k(const float* __restrict__ Qp, const float* __restrict__ Kp,
                        const int* __restrict__ idx, float* __restrict__ Mout,
                        int LQ, int LK, int U, int ld) {
    int t = blockIdx.x * 256 + threadIdx.x;
    int total = 16 * 8 * LQ * 4;
    if (t >= total) return;
    int p = t & 3;
    int rest = t >> 2;
    int l = rest % LQ;
    int h = (rest / LQ) & 7;
    int b = rest / (LQ * 8);
    const float4* q = (const float4*)(Qp + ((size_t)(b * LQ + l) * ld + h * 64));
    const float* kb = Kp + ((size_t)b * LK * ld + h * 64);
    float4 qr[16];
    #pragma unroll
    for (int d = 0; d < 16; d++) qr[d] = q[d];
    float mx = -INFINITY, sm = 0.f;
    for (int s = p; s < U; s += 4) {
        const float4* kr = (const float4*)(kb + (size_t)idx[l * U + s] * ld);
        float acc = 0.f;
        #pragma unroll
        for (int d = 0; d < 16; d++) {
            float4 kv = kr[d];
            acc += qr[d].x * kv.x + qr[d].y * kv.y + qr[d].z * kv.z + qr[d].w * kv.w;
        }
        mx = fmaxf(mx, acc);
        sm += acc;
    }
    mx = fmaxf(mx, __shfl_xor(mx, 1));
    mx = fmaxf(mx, __shfl_xor(mx, 2));
    sm += __shfl_xor(sm, 1);
    sm += __shfl_xor(sm, 2);
    if (p == 0)
        Mout[(size_t)((b * 8) + h) * LQ + l] = mx - sm / (float)LK;
}

// Parallel top-u per (b,h): iterative argmax in LDS, lowest-index tie-break.
__global__ __launch_bounds__(256) void topk_k(const float* __restrict__ M,
                                              int* __restrict__ top, int LQ, int u) {
    __shared__ float vals[512];
    __shared__ float rv[256];
    __shared__ int ri[256];
    int bh = blockIdx.x;
    int tid = threadIdx.x;
    const float* m = M + (size_t)bh * LQ;
    for (int l = tid; l < LQ; l += 256) vals[l] = m[l];
    __syncthreads();
    for (int j = 0; j < u; j++) {
        float best = -INFINITY;
        int bi = LQ;
        for (int l = tid; l < LQ; l += 256) {
            float v = vals[l];
            if (v > best) { best = v; bi = l; }
        }
        rv[tid] = best; ri[tid] = bi;
        __syncthreads();
        for (int s = 128; s > 0; s >>= 1) {
            if (tid < s) {
                float v2 = rv[tid + s]; int i2 = ri[tid + s];
                if (v2 > rv[tid] || (v2 == rv[tid] && i2 < ri[tid])) { rv[tid] = v2; ri[tid] = i2; }
            }
            __syncthreads();
        }
        int sel = ri[0];
        if (tid == 0) {
            top[bh * u + j] = sel;
            vals[sel] = -INFINITY;
        }
        __syncthreads();
    }
}

// vm[b,c] = mean over l of V[b,l,c]; parallel over l. grid (16 c-chunks, 16 b).
__global__ __launch_bounds__(256) void vmean_k(const float* __restrict__ Vp,
                                               float* __restrict__ vm, int LK, int ld) {
    __shared__ float red[8][33];
    int b = blockIdx.y;
    int c0 = blockIdx.x * 32;
    int ci = threadIdx.x & 31, g = threadIdx.x >> 5;
    const float* base = Vp + (size_t)b * LK * ld + c0 + ci;
    float s = 0.f;
    for (int l = g; l < LK; l += 8) s += base[(size_t)l * ld];
    red[g][ci] = s;
    __syncthreads();
    if (threadIdx.x < 32) {
        float t = 0.f;
        #pragma unroll
        for (int g2 = 0; g2 < 8; g2++) t += red[g2][threadIdx.x];
        vm[b * 512 + c0 + threadIdx.x] = t / (float)LK;
    }
}

// ctx[b,l,c] = vm[b,c]
__global__ void ctx_fill_k(const float* __restrict__ vm, float* __restrict__ ctx, int LQ, int total) {
    int t = blockIdx.x * 256 + threadIdx.x;
    if (t >= total) return;
    int c = t % 512;
    int b = t / (512 * LQ);
    ctx[t] = vm[b * 512 + c];
}

// Flash-style ProbSparse attention: one block per (b, h, u-half).
__global__ __launch_bounds__(256) void attn_flash_k(
    const float* __restrict__ Qp, const float* __restrict__ Kp, const float* __restrict__ Vp,
    const int* __restrict__ top, float* __restrict__ ctx, int LQ, int LK, int u, int ld) {
    __shared__ float qs[18][64];
    __shared__ int ls[18];
    __shared__ float kv[64][65];
    __shared__ float sc[18][512];
    int bid = blockIdx.x;
    int chunk = bid & 1;  // 2 chunks per (b,h)
    int h = (bid >> 1) & 7;
    int b = bid >> 4;
    int CH = (u + 1) >> 1;
    int r0 = chunk * CH;
    int nr = min(CH, u - r0);
    int tid = threadIdx.x;
    int wave = tid >> 6, lane = tid & 63;

    if (tid < nr) ls[tid] = top[((b * 8) + h) * u + r0 + tid];
    __syncthreads();
    for (int t = tid; t < nr * 64; t += 256) {
        int r = t >> 6, d = t & 63;
        qs[r][d] = Qp[((size_t)(b * LQ + ls[r])) * ld + h * 64 + d];
    }

    int ntile = LK >> 6;
    const float* kbase = Kp + ((size_t)b * LK) * ld + h * 64;
    for (int T = 0; T < ntile; T++) {
        __syncthreads();
        for (int t = tid; t < 4096; t += 256) {
            int kk = t >> 6, d = t & 63;
            kv[kk][d] = kbase[(size_t)(T * 64 + kk) * ld + d];
        }
        __syncthreads();
        for (int p = tid; p < nr * 64; p += 256) {
            int r = p >> 6, kk = p & 63;
            float acc = 0.f;
            #pragma unroll
            for (int d = 0; d < 64; d++) acc += qs[r][d] * kv[kk][d];
            sc[r][T * 64 + kk] = acc * 0.125f;  // 1/sqrt(64)
        }
    }
    // softmax per row (wave r%4 owns row r)
    for (int r = wave; r < nr; r += 4) {
        float mx = -INFINITY;
        for (int k = lane; k < LK; k += 64) mx = fmaxf(mx, sc[r][k]);
        #pragma unroll
        for (int o = 32; o > 0; o >>= 1) mx = fmaxf(mx, __shfl_xor(mx, o));
        float s = 0.f;
        for (int k = lane; k < LK; k += 64) {
            float e = expf(sc[r][k] - mx);
            sc[r][k] = e;
            s += e;
        }
        #pragma unroll
        for (int o = 32; o > 0; o >>= 1) s += __shfl_xor(s, o);
        float inv = 1.0f / s;
        for (int k = lane; k < LK; k += 64) sc[r][k] *= inv;
    }
    // PV
    float acc[5];
    #pragma unroll
    for (int i = 0; i < 5; i++) acc[i] = 0.f;
    const float* vbase = Vp + ((size_t)b * LK) * ld + h * 64;
    for (int T = 0; T < ntile; T++) {
        __syncthreads();
        for (int t = tid; t < 4096; t += 256) {
            int kk = t >> 6, d = t & 63;
            kv[kk][d] = vbase[(size_t)(T * 64 + kk) * ld + d];
        }
        __syncthreads();
        int ri = 0;
        for (int r = wave; r < nr; r += 4, ri++) {
            float a = 0.f;
            #pragma unroll
            for (int kk = 0; kk < 64; kk++) a += sc[r][T * 64 + kk] * kv[kk][lane];
            acc[ri] += a;
        }
    }
    int ri = 0;
    for (int r = wave; r < nr; r += 4, ri++)
        ctx[((size_t)(b * LQ + ls[r])) * 512 + h * 64 + lane] = acc[ri];
}

// per-row layer norm, D=512
__global__ __launch_bounds__(256) void ln_k(const float* __restrict__ in, float* __restrict__ out) {
    __shared__ float red[256];
    int r = blockIdx.x;
    int tid = threadIdx.x;
    const float* x = in + (size_t)r * 512;
    float a = x[tid], b = x[tid + 256];
    red[tid] = a + b;
    __syncthreads();
    for (int s = 128; s > 0; s >>= 1) {
        if (tid < s) red[tid] += red[tid + s];
        __syncthreads();
    }
    float mu = red[0] / 512.f;
    __syncthreads();
    float d1 = a - mu, d2 = b - mu;
    red[tid] = d1 * d1 + d2 * d2;
    __syncthreads();
    for (int s = 128; s > 0; s >>= 1) {
        if (tid < s) red[tid] += red[tid + s];
        __syncthreads();
    }
    float inv = 1.0f / sqrtf(red[0] / 512.f + 1e-5f);
    out[(size_t)r * 512 + tid] = d1 * inv;
    out[(size_t)r * 512 + tid + 256] = d2 * inv;
}

// circular-pad im2col: xc[(b*L+t)*1536 + h*512 + i] = x[b, (t+h-1) mod L, i]
__global__ void xcat_k(const float* __restrict__ x, float* __restrict__ xc, int L, int total) {
    int t = blockIdx.x * 256 + threadIdx.x;
    if (t >= total) return;
    int i = t % 512;
    int h = (t / 512) % 3;
    int bt = t / 1536;
    int tt = bt % L;
    int b = bt / L;
    int src = (tt + h - 1 + L) % L;
    xc[t] = x[(size_t)(b * L + src) * 512 + i];
}

// per-channel mean/var over all rows
__global__ __launch_bounds__(256) void bnstats_k(const float* __restrict__ y,
                                                 float* __restrict__ mu, float* __restrict__ var,
                                                 int rows) {
    __shared__ float red[256];
    int o = blockIdx.x;
    int tid = threadIdx.x;
    float s = 0.f;
    for (int r = tid; r < rows; r += 256) s += y[(size_t)r * 512 + o];
    red[tid] = s;
    __syncthreads();
    for (int st = 128; st > 0; st >>= 1) {
        if (tid < st) red[tid] += red[tid + st];
        __syncthreads();
    }
    float m = red[0] / (float)rows;
    __syncthreads();
    float s2 = 0.f;
    for (int r = tid; r < rows; r += 256) {
        float d = y[(size_t)r * 512 + o] - m;
        s2 += d * d;
    }
    red[tid] = s2;
    __syncthreads();
    for (int st = 128; st > 0; st >>= 1) {
        if (tid < st) red[tid] += red[tid + st];
        __syncthreads();
    }
    if (tid == 0) {
        mu[o] = m;
        var[o] = red[0] / (float)rows;
    }
}

// normalize -> max-pool(3,2,pad1) -> elu (monotone, pool first)
__global__ void elu_pool_k(const float* __restrict__ y, const float* __restrict__ mu,
                           const float* __restrict__ var, float* __restrict__ out,
                           int L, int total) {
    int t = blockIdx.x * 256 + threadIdx.x;
    if (t >= total) return;
    int o = t % 512;
    int tp = (t / 512) % (L / 2);
    int b = t / (512 * (L / 2));
    float mm = mu[o];
    float inv = 1.0f / sqrtf(var[o] + 1e-5f);
    float m = -INFINITY;
    #pragma unroll
    for (int dt = 0; dt < 3; dt++) {
        int tt = 2 * tp - 1 + dt;
        if (tt < 0 || tt >= L) continue;
        float v = (y[(size_t)(b * L + tt) * 512 + o] - mm) * inv;
        m = fmaxf(m, v);
    }
    out[t] = m > 0.f ? m : expm1f(m);
}

// out[r] = dot(x[r,:512], w) + b
__global__ void final_k(const float* __restrict__ x, const float* __restrict__ w,
                        const float* __restrict__ bb, float* __restrict__ out, int rows) {
    int gid = blockIdx.x * 256 + threadIdx.x;
    int wid = gid >> 6;
    int lane = gid & 63;
    if (wid >= rows) return;
    const float* xr = x + (size_t)wid * 512;
    float acc = 0.f;
    for (int k = lane; k < 512; k += 64) acc += xr[k] * w[k];
    for (int off = 32; off > 0; off >>= 1) acc += __shfl_down(acc, off);
    if (lane == 0) out[wid] = acc + bb[0];
}

// ---------------------------------------------------------------------------
// Host driver
// ---------------------------------------------------------------------------

static inline int iceil_log(int L) { return (int)ceil(log((double)L)); }
static inline int imin(int a, int b) { return a < b ? a : b; }

extern "C" void kernel_launch(void* const* d_in, const int* in_sizes, int n_in,
                              void* d_out, int out_size, void* d_ws, size_t ws_size,
                              hipStream_t stream) {
    const float* IN  = (const float*)d_in[0];
    const float* Wq  = (const float*)d_in[1];
    const float* bq  = (const float*)d_in[2];
    const float* Wk  = (const float*)d_in[3];
    const float* bk  = (const float*)d_in[4];
    const float* Wv  = (const float*)d_in[5];
    const float* bv  = (const float*)d_in[6];
    const float* Wo  = (const float*)d_in[7];
    const float* bo  = (const float*)d_in[8];
    const float* ew1 = (const float*)d_in[9];
    const float* eb1 = (const float*)d_in[10];
    const float* ew2 = (const float*)d_in[11];
    const float* eb2 = (const float*)d_in[12];
    const float* dw1 = (const float*)d_in[13];
    const float* db1 = (const float*)d_in[14];
    const float* dw2 = (const float*)d_in[15];
    const float* db2 = (const float*)d_in[16];
    const float* DW  = (const float*)d_in[17];
    const float* db  = (const float*)d_in[18];
    const float* ow  = (const float*)d_in[19];
    const float* ob  = (const float*)d_in[20];
    float* OUT = (float*)d_out;

    float* ws = (float*)d_ws;
    size_t off = 0;
    auto alloc = [&](size_t n) { float* p = ws + off; off += n; return p; };
    float* PE   = alloc(4194304);
    float* QKV  = alloc(12582912);  // [8192][1536]: Q|K|V columns
    float* CTX  = alloc(4194304);
    float* T1   = alloc(4194304);
    float* XLN  = alloc(4194304);
    float* T2   = alloc(4194304);
    float* T3   = alloc(4194304);
    float* HID  = alloc(16777216);
    float* D1   = alloc(2097152);
    float* D2   = alloc(1048576);
    float* Eb   = alloc(524288);
    float* MB   = alloc(65536);
    float* VM   = alloc(8192);
    float* MU   = alloc(512);
    float* VARb = alloc(512);
    float* BQKV = alloc(1536);
    int* IDX  = (int*)alloc(17920);
    int* TOPB = (int*)alloc(4480);
    short* WqkvT = (short*)alloc(393216);  // [1536][512] bf16: Wq|Wk|Wv rows
    short* WoT   = (short*)alloc(131072);
    short* ew1T  = (short*)alloc(524288);
    short* ew2T  = (short*)alloc(524288);
    short* dw1T  = (short*)alloc(524288);
    short* dw2T  = (short*)alloc(524288);
    short* W2T   = (short*)alloc(393216);
    (void)ws_size; (void)n_in; (void)in_sizes; (void)out_size;

    // allow >64KB dynamic LDS for the K-slab kernel (needed at LK=512)
    static_assert(512 * 65 * 4 == 133120, "");
    hipError_t attr_ok = hipFuncSetAttribute(
        (const void*)msamp_lds_k, hipFuncAttributeMaxDynamicSharedMemorySize, 133120);

    auto gemm128 = [&](const float* A, const short* Bt, const float* bias, const float* res,
                       float* C, int M, int N, int K, int relu, int ldC) {
        dim3 g(N / 128, M / 128);
        gemm_bf_k<<<g, 256, 0, stream>>>(A, Bt, bias, res, C, M, N, K, relu, ldC);
    };
    auto gemm64 = [&](const float* A, const short* Bt, const float* bias, const float* res,
                      float* C, int M, int N, int K, int relu, int ldC) {
        dim3 g(N / 64, M / 64);
        gemm64_k<<<g, 256, 0, stream>>>(A, Bt, bias, res, C, M, N, K, relu, ldC);
    };
    auto tr = [&](const float* W, short* Wt, int K, int N) {
        dim3 g(N / 32, K / 32);
        transpose_bf16_k<<<g, 256, 0, stream>>>(W, Wt, K, N);
    };

    auto attn = [&](const float* qin, const float* kvin, const float* resp, float* outp,
                    int LQ, int LK, int ikey) {
        int Mq = 16 * LQ, Mk = 16 * LK;
        const int ld = 1536;
        float* Qp = QKV;
        float* Kp = QKV + 512;
        float* Vp = QKV + 1024;
        if (qin == kvin) {
            gemm128(qin, WqkvT, BQKV, nullptr, QKV, Mq, 1536, 512, 0, ld);
        } else {
            gemm64(qin, WqkvT, BQKV, nullptr, QKV, Mq, 512, 512, 0, ld);
            gemm64(kvin, WqkvT + 512 * 512, BQKV + 512, nullptr, QKV + 512, Mk, 1024, 512, 0, ld);
        }
        int U = imin(5 * iceil_log(LK), LK);
        int u = imin(5 * iceil_log(LQ), LQ);
        unsigned rk0, rk1;
        threefry2x32(0u, 42u, 0u, (unsigned)ikey, rk0, rk1);
        int size = LQ * U;
        ridx_k<<<(size + 255) / 256, 256, 0, stream>>>(rk0, rk1, size, (unsigned)(LK - 1), IDX);
        size_t shbytes = (size_t)LK * 65 * 4;
        if (attr_ok == hipSuccess || shbytes <= 65536) {
            msamp_lds_k<<<16 * 8 * 2, 256, shbytes, stream>>>(Qp, Kp, IDX, MB, LQ, LK, U, ld);
        } else {
            int totM = 16 * 8 * LQ * 4;
            msamp_k<<<(totM + 255) / 256, 256, 0, stream>>>(Qp, Kp, IDX, MB, LQ, LK, U, ld);
        }
        topk_k<<<128, 256, 0, stream>>>(MB, TOPB, LQ, u);
        vmean_k<<<dim3(16, 16), 256, 0, stream>>>(Vp, VM, LK, ld);
        int totC = 16 * LQ * 512;
        ctx_fill_k<<<(totC + 255) / 256, 256, 0, stream>>>(VM, CTX, LQ, totC);
        attn_flash_k<<<16 * 8 * 2, 256, 0, stream>>>(Qp, Kp, Vp, TOPB, CTX, LQ, LK, u, ld);
        gemm64(CTX, WoT, bo, resp, outp, Mq, 512, 512, 0, 512);
    };

    auto encoder = [&](const float* X, int L, int ikey, float* OUTenc) {
        int M = 16 * L;
        attn(X, X, X, T1, L, L, ikey);
        ln_k<<<M, 256, 0, stream>>>(T1, XLN);
        gemm128(XLN, ew1T, eb1, nullptr, HID, M, 2048, 512, 1, 2048);
        gemm64(HID, ew2T, eb2, XLN, T2, M, 512, 2048, 0, 512);
        ln_k<<<M, 256, 0, stream>>>(T2, OUTenc);
    };

    auto distill = [&](const float* X, int L, float* OUTd) {
        int M = 16 * L;
        int tot = M * 1536;
        xcat_k<<<(tot + 255) / 256, 256, 0, stream>>>(X, HID, L, tot);
        gemm64(HID, W2T, db, nullptr, CTX, M, 512, 1536, 0, 512);
        bnstats_k<<<512, 256, 0, stream>>>(CTX, MU, VARb, M);
        int toto = 16 * (L / 2) * 512;
        elu_pool_k<<<(toto + 255) / 256, 256, 0, stream>>>(CTX, MU, VARb, OUTd, L, toto);
    };

    // --- weight conversion (once per launch) ---
    tr(Wq, WqkvT, 512, 512);
    tr(Wk, WqkvT + 512 * 512, 512, 512);
    tr(Wv, WqkvT + 1024 * 512, 512, 512);
    tr(Wo, WoT, 512, 512);
    tr(ew1, ew1T, 512, 2048);
    tr(ew2, ew2T, 2048, 512);
    tr(dw1, dw1T, 512, 2048);
    tr(dw2, dw2T, 2048, 512);
    w2t_k<<<(786432 + 255) / 256, 256, 0, stream>>>(DW, W2T, 786432);
    bcat_k<<<6, 256, 0, stream>>>(bq, bk, bv, BQKV);

    // --- forward ---
    int totPE = 16 * 512 * 512;
    pe_add_k<<<(totPE + 255) / 256, 256, 0, stream>>>(IN, PE, totPE);

    encoder(PE, 512, 0, T3); distill(T3, 512, D1);
    encoder(D1, 256, 1, T3); distill(T3, 256, D2);
    encoder(D2, 128, 2, T3); distill(T3, 128, Eb);

    attn(PE, PE, PE, T1, 512, 512, 3);
    attn(T1, Eb, T1, T2, 512, 64, 4);
    gemm128(T2, dw1T, db1, nullptr, HID, 8192, 2048, 512, 1, 2048);
    gemm64(HID, dw2T, db2, T2, T3, 8192, 512, 2048, 0, 512);
    final_k<<<(8192 * 64) / 256, 256, 0, stream>>>(T3, ow, ob, OUT, 8192);
}

// Round 9
// 1705.176 us; speedup vs baseline: 8.5186x; 1.0994x over previous
//
#include <hip/hip_runtime.h>
#include <cstdint>
#include <cmath>

// ---------------------------------------------------------------------------
// Informer forward. Round 9: (a) bf16 activation mirrors for ALL GEMM A-inputs
// (bit-identical to R8's in-staging conversion; halves A-side HBM traffic),
// (b) XCD-aware block swizzle in both GEMMs (R8 post-mortem: FFN-down fetched
// 271 MB because A-tile-sharing blocks were round-robined across the 8
// non-coherent XCD L2s). jax.random via threefry2x32 (H2, verified R1).
// ---------------------------------------------------------------------------

#define HD __host__ __device__

typedef short short8 __attribute__((ext_vector_type(8)));
typedef float float4v __attribute__((ext_vector_type(4)));

__device__ inline short f2bf(float f) {  // RNE
    unsigned u = __float_as_uint(f);
    unsigned r = u + 0x7FFFu + ((u >> 16) & 1u);
    return (short)(r >> 16);
}

HD inline unsigned rotl32(unsigned x, int r) { return (x << r) | (x >> (32 - r)); }
HD inline void tfround(unsigned& x0, unsigned& x1, int r) {
    x0 += x1; x1 = rotl32(x1, r); x1 ^= x0;
}
HD inline void threefry2x32(unsigned k0, unsigned k1, unsigned c0, unsigned c1,
                            unsigned& o0, unsigned& o1) {
    unsigned ks2 = k0 ^ k1 ^ 0x1BD11BDAu;
    unsigned x0 = c0 + k0, x1 = c1 + k1;
    tfround(x0, x1, 13); tfround(x0, x1, 15); tfround(x0, x1, 26); tfround(x0, x1, 6);
    x0 += k1; x1 += ks2 + 1u;
    tfround(x0, x1, 17); tfround(x0, x1, 29); tfround(x0, x1, 16); tfround(x0, x1, 24);
    x0 += ks2; x1 += k0 + 2u;
    tfround(x0, x1, 13); tfround(x0, x1, 15); tfround(x0, x1, 26); tfround(x0, x1, 6);
    x0 += k0; x1 += k1 + 3u;
    tfround(x0, x1, 17); tfround(x0, x1, 29); tfround(x0, x1, 16); tfround(x0, x1, 24);
    x0 += k1; x1 += ks2 + 4u;
    tfround(x0, x1, 13); tfround(x0, x1, 15); tfround(x0, x1, 26); tfround(x0, x1, 6);
    x0 += ks2; x1 += k0 + 5u;
    o0 = x0; o1 = x1;
}

// ---------------------------------------------------------------------------
// Kernels
// ---------------------------------------------------------------------------

// out = in + PE; outb = bf16(out)
__global__ void pe_add_k(const float* __restrict__ in, float* __restrict__ out,
                         short* __restrict__ outb, int total) {
    int t = blockIdx.x * 256 + threadIdx.x;
    if (t >= total) return;
    int d = t % 512;
    int l = (t / 512) % 512;
    float i2 = (float)(d & ~1);
    float div = expf(i2 * (-0.017988946039016f));  // -ln(10000)/512
    float ang = (float)l * div;
    float v = (d & 1) ? cosf(ang) : sinf(ang);
    float r = in[t] + v;
    out[t] = r;
    outb[t] = f2bf(r);
}

// fp32 [K][N] -> bf16 [N][K] via 32x32 LDS tile
__global__ __launch_bounds__(256) void transpose_bf16_k(const float* __restrict__ in,
                                                        short* __restrict__ out, int K, int N) {
    __shared__ float tile[32][33];
    int k0 = blockIdx.y * 32, n0 = blockIdx.x * 32;
    int c = threadIdx.x & 31, r0 = threadIdx.x >> 5;
    for (int rr = r0; rr < 32; rr += 8)
        tile[rr][c] = in[(size_t)(k0 + rr) * N + n0 + c];
    __syncthreads();
    for (int rr = r0; rr < 32; rr += 8)
        out[(size_t)(n0 + rr) * K + k0 + c] = f2bf(tile[c][rr]);
}

// dist_w (O,I,H) -> bf16 W2T[o][h*512+i]
__global__ void w2t_k(const float* __restrict__ dw, short* __restrict__ out, int total) {
    int t = blockIdx.x * 256 + threadIdx.x;
    if (t >= total) return;
    int kk = t % 1536;
    int o = t / 1536;
    int h = kk / 512, i = kk % 512;
    out[t] = f2bf(dw[(size_t)o * 1536 + i * 3 + h]);
}

// concat biases bq|bk|bv -> bqkv[1536]
__global__ void bcat_k(const float* __restrict__ b0, const float* __restrict__ b1,
                       const float* __restrict__ b2, float* __restrict__ out) {
    int t = blockIdx.x * 256 + threadIdx.x;
    if (t >= 1536) return;
    out[t] = (t < 512) ? b0[t] : (t < 1024 ? b1[t - 512] : b2[t - 1024]);
}

__device__ inline void swizzle_bid(int bid, int nbx, int nby, int& bm, int& bn) {
    if ((nby & 7) == 0) {
        int stripe = nby >> 3;
        int x = bid & 7, w = bid >> 3;
        bn = w % nbx;
        bm = x * stripe + w / nbx;
    } else {
        bn = bid % nbx;
        bm = bid / nbx;
    }
}

// bf16 MFMA GEMM, 128x128 tile, BK=32; A bf16 [M][K], Bt bf16 [N][K].
// C32 (fp32) and/or C16 (bf16), both stride ldC. XCD-swizzled 1D grid.
__global__ __launch_bounds__(256) void gemm128_k(
    const short* __restrict__ A, const short* __restrict__ Bt,
    const float* __restrict__ bias, const float* __restrict__ res,
    float* __restrict__ C32, short* __restrict__ C16,
    int M, int N, int K, int relu, int ldC) {
    __shared__ short As[128 * 40];
    __shared__ short Bs[128 * 40];
    int tid = threadIdx.x;
    int wave = tid >> 6, lane = tid & 63;
    int wy = wave >> 1, wx = wave & 1;
    int rl = lane & 15, quad = lane >> 4;
    int bm, bn;
    swizzle_bid(blockIdx.x, N >> 7, M >> 7, bm, bn);
    bm <<= 7; bn <<= 7;

    float4v acc[4][4];
    #pragma unroll
    for (int i = 0; i < 4; i++)
        #pragma unroll
        for (int j = 0; j < 4; j++) acc[i][j] = (float4v){0.f, 0.f, 0.f, 0.f};

    for (int k0 = 0; k0 < K; k0 += 32) {
        #pragma unroll
        for (int it = 0; it < 2; it++) {
            int c = tid + it * 256;
            int row = c >> 2, seg = c & 3;
            *(float4*)&As[row * 40 + seg * 8] =
                *(const float4*)(A + (size_t)(bm + row) * K + k0 + seg * 8);
        }
        #pragma unroll
        for (int it = 0; it < 2; it++) {
            int c = tid + it * 256;
            int row = c >> 2, seg = c & 3;
            *(float4*)&Bs[row * 40 + seg * 8] =
                *(const float4*)(Bt + (size_t)(bn + row) * K + k0 + seg * 8);
        }
        __syncthreads();
        short8 a[4], b[4];
        #pragma unroll
        for (int i = 0; i < 4; i++)
            a[i] = *(const short8*)&As[(wy * 64 + i * 16 + rl) * 40 + quad * 8];
        #pragma unroll
        for (int j = 0; j < 4; j++)
            b[j] = *(const short8*)&Bs[(wx * 64 + j * 16 + rl) * 40 + quad * 8];
        #pragma unroll
        for (int i = 0; i < 4; i++)
            #pragma unroll
            for (int j = 0; j < 4; j++)
                acc[i][j] = __builtin_amdgcn_mfma_f32_16x16x32_bf16(a[i], b[j], acc[i][j], 0, 0, 0);
        __syncthreads();
    }
    #pragma unroll
    for (int i = 0; i < 4; i++) {
        #pragma unroll
        for (int r = 0; r < 4; r++) {
            int gm = bm + wy * 64 + i * 16 + quad * 4 + r;
            #pragma unroll
            for (int j = 0; j < 4; j++) {
                int gn = bn + wx * 64 + j * 16 + rl;
                float v = acc[i][j][r];
                if (bias) v += bias[gn];
                if (relu) v = fmaxf(v, 0.f);
                if (res) v += res[(size_t)gm * ldC + gn];
                if (C32) C32[(size_t)gm * ldC + gn] = v;
                if (C16) C16[(size_t)gm * ldC + gn] = f2bf(v);
            }
        }
    }
}

// 64x64-tile variant. 4 waves, each 16x64.
__global__ __launch_bounds__(256) void gemm64_k(
    const short* __restrict__ A, const short* __restrict__ Bt,
    const float* __restrict__ bias, const float* __restrict__ res,
    float* __restrict__ C32, short* __restrict__ C16,
    int M, int N, int K, int relu, int ldC) {
    __shared__ short As[64 * 40];
    __shared__ short Bs[64 * 40];
    int tid = threadIdx.x;
    int wave = tid >> 6, lane = tid & 63;
    int rl = lane & 15, quad = lane >> 4;
    int bm, bn;
    swizzle_bid(blockIdx.x, N >> 6, M >> 6, bm, bn);
    bm <<= 6; bn <<= 6;

    float4v acc[4];
    #pragma unroll
    for (int j = 0; j < 4; j++) acc[j] = (float4v){0.f, 0.f, 0.f, 0.f};

    int row = tid >> 2, seg = tid & 3;
    for (int k0 = 0; k0 < K; k0 += 32) {
        *(float4*)&As[row * 40 + seg * 8] =
            *(const float4*)(A + (size_t)(bm + row) * K + k0 + seg * 8);
        *(float4*)&Bs[row * 40 + seg * 8] =
            *(const float4*)(Bt + (size_t)(bn + row) * K + k0 + seg * 8);
        __syncthreads();
        short8 a = *(const short8*)&As[(wave * 16 + rl) * 40 + quad * 8];
        short8 b[4];
        #pragma unroll
        for (int j = 0; j < 4; j++)
            b[j] = *(const short8*)&Bs[(j * 16 + rl) * 40 + quad * 8];
        #pragma unroll
        for (int j = 0; j < 4; j++)
            acc[j] = __builtin_amdgcn_mfma_f32_16x16x32_bf16(a, b[j], acc[j], 0, 0, 0);
        __syncthreads();
    }
    #pragma unroll
    for (int r = 0; r < 4; r++) {
        int gm = bm + wave * 16 + quad * 4 + r;
        #pragma unroll
        for (int j = 0; j < 4; j++) {
            int gn = bn + j * 16 + rl;
            float v = acc[j][r];
            if (bias) v += bias[gn];
            if (relu) v = fmaxf(v, 0.f);
            if (res) v += res[(size_t)gm * ldC + gn];
            if (C32) C32[(size_t)gm * ldC + gn] = v;
            if (C16) C16[(size_t)gm * ldC + gn] = f2bf(v);
        }
    }
}

// idx[j] = threefry(rkey, (j, j+size)).second & mask   (H2, verified R1)
__global__ void ridx_k(unsigned k0, unsigned k1, int size, unsigned mask, int* __restrict__ idx) {
    int j = blockIdx.x * 256 + threadIdx.x;
    if (j >= size) return;
    unsigned o0, o1;
    threefry2x32(k0, k1, (unsigned)j, (unsigned)(j + size), o0, o1);
    idx[j] = (int)(o1 & mask);
}

// msamp, K-slab in LDS. One block per (b, h, l-half); grid 16*8*2 = 256.
extern __shared__ float kslab[];
__global__ __launch_bounds__(256) void msamp_lds_k(
    const float* __restrict__ Qp, const float* __restrict__ Kp,
    const int* __restrict__ idx, float* __restrict__ Mout,
    int LQ, int LK, int U, int ld) {
    int bid = blockIdx.x;
    int half = bid & 1;
    int bh = bid >> 1;
    int h = bh & 7, b = bh >> 3;
    const float* kbase = Kp + (size_t)b * LK * ld + h * 64;
    for (int t = threadIdx.x; t < LK * 16; t += 256) {
        int r = t >> 4, seg = t & 15;
        float4 v = *(const float4*)(kbase + (size_t)r * ld + seg * 4);
        float* dst = &kslab[r * 65 + seg * 4];
        dst[0] = v.x; dst[1] = v.y; dst[2] = v.z; dst[3] = v.w;
    }
    __syncthreads();
    int halfL = LQ >> 1;
    for (int li = threadIdx.x; li < halfL; li += 256) {
        int l = half * halfL + li;
        const float4* q = (const float4*)(Qp + (size_t)(b * LQ + l) * ld + h * 64);
        float qr[64];
        #pragma unroll
        for (int d4 = 0; d4 < 16; d4++) {
            float4 v = q[d4];
            qr[4 * d4] = v.x; qr[4 * d4 + 1] = v.y; qr[4 * d4 + 2] = v.z; qr[4 * d4 + 3] = v.w;
        }
        const int* ip = idx + l * U;
        float mx = -INFINITY, sm = 0.f;
        for (int s = 0; s < U; s++) {
            const float* kr = &kslab[ip[s] * 65];
            float acc = 0.f;
            #pragma unroll
            for (int d = 0; d < 64; d++) acc += qr[d] * kr[d];
            mx = fmaxf(mx, acc);
            sm += acc;
        }
        Mout[(size_t)bh * LQ + l] = mx - sm / (float)LK;
    }
}

// Fallback msamp if large dynamic-LDS attribute fails.
__global__ void msamp_k(const float* __restrict__ Qp, const float* __restrict__ Kp,
                        const int* __restrict__ idx, float* __restrict__ Mout,
                        int LQ, int LK, int U, int ld) {
    int t = blockIdx.x * 256 + threadIdx.x;
    int total = 16 * 8 * LQ * 4;
    if (t >= total) return;
    int p = t & 3;
    int rest = t >> 2;
    int l = rest % LQ;
    int h = (rest / LQ) & 7;
    int b = rest / (LQ * 8);
    const float4* q = (const float4*)(Qp + ((size_t)(b * LQ + l) * ld + h * 64));
    const float* kb = Kp + ((size_t)b * LK * ld + h * 64);
    float4 qr[16];
    #pragma unroll
    for (int d = 0; d < 16; d++) qr[d] = q[d];
    float mx = -INFINITY, sm = 0.f;
    for (int s = p; s < U; s += 4) {
        const float4* kr = (const float4*)(kb + (size_t)idx[l * U + s] * ld);
        float acc = 0.f;
        #pragma unroll
        for (int d = 0; d < 16; d++) {
            float4 kv = kr[d];
            acc += qr[d].x * kv.x + qr[d].y * kv.y + qr[d].z * kv.z + qr[d].w * kv.w;
        }
        mx = fmaxf(mx, acc);
        sm += acc;
    }
    mx = fmaxf(mx, __shfl_xor(mx, 1));
    mx = fmaxf(mx, __shfl_xor(mx, 2));
    sm += __shfl_xor(sm, 1);
    sm += __shfl_xor(sm, 2);
    if (p == 0)
        Mout[(size_t)((b * 8) + h) * LQ + l] = mx - sm / (float)LK;
}

// Parallel top-u per (b,h): iterative argmax in LDS, lowest-index tie-break.
__global__ __launch_bounds__(256) void topk_k(const float* __restrict__ M,
                                              int* __restrict__ top, int LQ, int u) {
    __shared__ float vals[512];
    __shared__ float rv[256];
    __shared__ int ri[256];
    int bh = blockIdx.x;
    int tid = threadIdx.x;
    const float* m = M + (size_t)bh * LQ;
    for (int l = tid; l < LQ; l += 256) vals[l] = m[l];
    __syncthreads();
    for (int j = 0; j < u; j++) {
        float best = -INFINITY;
        int bi = LQ;
        for (int l = tid; l < LQ; l += 256) {
            float v = vals[l];
            if (v > best) { best = v; bi = l; }
        }
        rv[tid] = best; ri[tid] = bi;
        __syncthreads();
        for (int s = 128; s > 0; s >>= 1) {
            if (tid < s) {
                float v2 = rv[tid + s]; int i2 = ri[tid + s];
                if (v2 > rv[tid] || (v2 == rv[tid] && i2 < ri[tid])) { rv[tid] = v2; ri[tid] = i2; }
            }
            __syncthreads();
        }
        int sel = ri[0];
        if (tid == 0) {
            top[bh * u + j] = sel;
            vals[sel] = -INFINITY;
        }
        __syncthreads();
    }
}

// vm[b,c] = mean over l of V[b,l,c]; parallel over l. grid (16 c-chunks, 16 b).
__global__ __launch_bounds__(256) void vmean_k(const float* __restrict__ Vp,
                                               float* __restrict__ vm, int LK, int ld) {
    __shared__ float red[8][33];
    int b = blockIdx.y;
    int c0 = blockIdx.x * 32;
    int ci = threadIdx.x & 31, g = threadIdx.x >> 5;
    const float* base = Vp + (size_t)b * LK * ld + c0 + ci;
    float s = 0.f;
    for (int l = g; l < LK; l += 8) s += base[(size_t)l * ld];
    red[g][ci] = s;
    __syncthreads();
    if (threadIdx.x < 32) {
        float t = 0.f;
        #pragma unroll
        for (int g2 = 0; g2 < 8; g2++) t += red[g2][threadIdx.x];
        vm[b * 512 + c0 + threadIdx.x] = t / (float)LK;
    }
}

// ctxb[b,l,c] = bf16(vm[b,c])
__global__ void ctx_fill_k(const float* __restrict__ vm, short* __restrict__ ctxb,
                           int LQ, int total) {
    int t = blockIdx.x * 256 + threadIdx.x;
    if (t >= total) return;
    int c = t % 512;
    int b = t / (512 * LQ);
    ctxb[t] = f2bf(vm[b * 512 + c]);
}

// Flash-style ProbSparse attention: one block per (b, h, u-half). bf16 ctx out.
__global__ __launch_bounds__(256) void attn_flash_k(
    const float* __restrict__ Qp, const float* __restrict__ Kp, const float* __restrict__ Vp,
    const int* __restrict__ top, short* __restrict__ ctxb, int LQ, int LK, int u, int ld) {
    __shared__ float qs[18][64];
    __shared__ int ls[18];
    __shared__ float kv[64][65];
    __shared__ float sc[18][512];
    int bid = blockIdx.x;
    int chunk = bid & 1;
    int h = (bid >> 1) & 7;
    int b = bid >> 4;
    int CH = (u + 1) >> 1;
    int r0 = chunk * CH;
    int nr = min(CH, u - r0);
    int tid = threadIdx.x;
    int wave = tid >> 6, lane = tid & 63;

    if (tid < nr) ls[tid] = top[((b * 8) + h) * u + r0 + tid];
    __syncthreads();
    for (int t = tid; t < nr * 64; t += 256) {
        int r = t >> 6, d = t & 63;
        qs[r][d] = Qp[((size_t)(b * LQ + ls[r])) * ld + h * 64 + d];
    }

    int ntile = LK >> 6;
    const float* kbase = Kp + ((size_t)b * LK) * ld + h * 64;
    for (int T = 0; T < ntile; T++) {
        __syncthreads();
        for (int t = tid; t < 4096; t += 256) {
            int kk = t >> 6, d = t & 63;
            kv[kk][d] = kbase[(size_t)(T * 64 + kk) * ld + d];
        }
        __syncthreads();
        for (int p = tid; p < nr * 64; p += 256) {
            int r = p >> 6, kk = p & 63;
            float acc = 0.f;
            #pragma unroll
            for (int d = 0; d < 64; d++) acc += qs[r][d] * kv[kk][d];
            sc[r][T * 64 + kk] = acc * 0.125f;  // 1/sqrt(64)
        }
    }
    for (int r = wave; r < nr; r += 4) {
        float mx = -INFINITY;
        for (int k = lane; k < LK; k += 64) mx = fmaxf(mx, sc[r][k]);
        #pragma unroll
        for (int o = 32; o > 0; o >>= 1) mx = fmaxf(mx, __shfl_xor(mx, o));
        float s = 0.f;
        for (int k = lane; k < LK; k += 64) {
            float e = expf(sc[r][k] - mx);
            sc[r][k] = e;
            s += e;
        }
        #pragma unroll
        for (int o = 32; o > 0; o >>= 1) s += __shfl_xor(s, o);
        float inv = 1.0f / s;
        for (int k = lane; k < LK; k += 64) sc[r][k] *= inv;
    }
    float acc[5];
    #pragma unroll
    for (int i = 0; i < 5; i++) acc[i] = 0.f;
    const float* vbase = Vp + ((size_t)b * LK) * ld + h * 64;
    for (int T = 0; T < ntile; T++) {
        __syncthreads();
        for (int t = tid; t < 4096; t += 256) {
            int kk = t >> 6, d = t & 63;
            kv[kk][d] = vbase[(size_t)(T * 64 + kk) * ld + d];
        }
        __syncthreads();
        int ri = 0;
        for (int r = wave; r < nr; r += 4, ri++) {
            float a = 0.f;
            #pragma unroll
            for (int kk = 0; kk < 64; kk++) a += sc[r][T * 64 + kk] * kv[kk][lane];
            acc[ri] += a;
        }
    }
    int ri = 0;
    for (int r = wave; r < nr; r += 4, ri++)
        ctxb[((size_t)(b * LQ + ls[r])) * 512 + h * 64 + lane] = f2bf(acc[ri]);
}

// per-row layer norm, D=512; optional bf16 mirror
__global__ __launch_bounds__(256) void ln_k(const float* __restrict__ in,
                                            float* __restrict__ out, short* __restrict__ outb) {
    __shared__ float red[256];
    int r = blockIdx.x;
    int tid = threadIdx.x;
    const float* x = in + (size_t)r * 512;
    float a = x[tid], b = x[tid + 256];
    red[tid] = a + b;
    __syncthreads();
    for (int s = 128; s > 0; s >>= 1) {
        if (tid < s) red[tid] += red[tid + s];
        __syncthreads();
    }
    float mu = red[0] / 512.f;
    __syncthreads();
    float d1 = a - mu, d2 = b - mu;
    red[tid] = d1 * d1 + d2 * d2;
    __syncthreads();
    for (int s = 128; s > 0; s >>= 1) {
        if (tid < s) red[tid] += red[tid + s];
        __syncthreads();
    }
    float inv = 1.0f / sqrtf(red[0] / 512.f + 1e-5f);
    float v1 = d1 * inv, v2 = d2 * inv;
    out[(size_t)r * 512 + tid] = v1;
    out[(size_t)r * 512 + tid + 256] = v2;
    if (outb) {
        outb[(size_t)r * 512 + tid] = f2bf(v1);
        outb[(size_t)r * 512 + tid + 256] = f2bf(v2);
    }
}

// circular-pad im2col -> bf16: xc[(b*L+t)*1536 + h*512 + i] = bf16(x[b,(t+h-1)%L,i])
__global__ void xcat_k(const float* __restrict__ x, short* __restrict__ xc, int L, int total) {
    int t = blockIdx.x * 256 + threadIdx.x;
    if (t >= total) return;
    int i = t % 512;
    int h = (t / 512) % 3;
    int bt = t / 1536;
    int tt = bt % L;
    int b = bt / L;
    int src = (tt + h - 1 + L) % L;
    xc[t] = f2bf(x[(size_t)(b * L + src) * 512 + i]);
}

// per-channel mean/var over all rows
__global__ __launch_bounds__(256) void bnstats_k(const float* __restrict__ y,
                                                 float* __restrict__ mu, float* __restrict__ var,
                                                 int rows) {
    __shared__ float red[256];
    int o = blockIdx.x;
    int tid = threadIdx.x;
    float s = 0.f;
    for (int r = tid; r < rows; r += 256) s += y[(size_t)r * 512 + o];
    red[tid] = s;
    __syncthreads();
    for (int st = 128; st > 0; st >>= 1) {
        if (tid < st) red[tid] += red[tid + st];
        __syncthreads();
    }
    float m = red[0] / (float)rows;
    __syncthreads();
    float s2 = 0.f;
    for (int r = tid; r < rows; r += 256) {
        float d = y[(size_t)r * 512 + o] - m;
        s2 += d * d;
    }
    red[tid] = s2;
    __syncthreads();
    for (int st = 128; st > 0; st >>= 1) {
        if (tid < st) red[tid] += red[tid + st];
        __syncthreads();
    }
    if (tid == 0) {
        mu[o] = m;
        var[o] = red[0] / (float)rows;
    }
}

// normalize -> max-pool(3,2,pad1) -> elu; writes fp32 + bf16 mirror
__global__ void elu_pool_k(const float* __restrict__ y, const float* __restrict__ mu,
                           const float* __restrict__ var, float* __restrict__ out,
                           short* __restrict__ outb, int L, int total) {
    int t = blockIdx.x * 256 + threadIdx.x;
    if (t >= total) return;
    int o = t % 512;
    int tp = (t / 512) % (L / 2);
    int b = t / (512 * (L / 2));
    float mm = mu[o];
    float inv = 1.0f / sqrtf(var[o] + 1e-5f);
    float m = -INFINITY;
    #pragma unroll
    for (int dt = 0; dt < 3; dt++) {
        int tt = 2 * tp - 1 + dt;
        if (tt < 0 || tt >= L) continue;
        float v = (y[(size_t)(b * L + tt) * 512 + o] - mm) * inv;
        m = fmaxf(m, v);
    }
    float r = m > 0.f ? m : expm1f(m);
    out[t] = r;
    outb[t] = f2bf(r);
}

// out[r] = dot(x[r,:512], w) + b
__global__ void final_k(const float* __restrict__ x, const float* __restrict__ w,
                        const float* __restrict__ bb, float* __restrict__ out, int rows) {
    int gid = blockIdx.x * 256 + threadIdx.x;
    int wid = gid >> 6;
    int lane = gid & 63;
    if (wid >= rows) return;
    const float* xr = x + (size_t)wid * 512;
    float acc = 0.f;
    for (int k = lane; k < 512; k += 64) acc += xr[k] * w[k];
    for (int off = 32; off > 0; off >>= 1) acc += __shfl_down(acc, off);
    if (lane == 0) out[wid] = acc + bb[0];
}

// ---------------------------------------------------------------------------
// Host driver
// ---------------------------------------------------------------------------

static inline int iceil_log(int L) { return (int)ceil(log((double)L)); }
static inline int imin(int a, int b) { return a < b ? a : b; }

extern "C" void kernel_launch(void* const* d_in, const int* in_sizes, int n_in,
                              void* d_out, int out_size, void* d_ws, size_t ws_size,
                              hipStream_t stream) {
    const float* IN  = (const float*)d_in[0];
    const float* Wq  = (const float*)d_in[1];
    const float* bq  = (const float*)d_in[2];
    const float* Wk  = (const float*)d_in[3];
    const float* bk  = (const float*)d_in[4];
    const float* Wv  = (const float*)d_in[5];
    const float* bv  = (const float*)d_in[6];
    const float* Wo  = (const float*)d_in[7];
    const float* bo  = (const float*)d_in[8];
    const float* ew1 = (const float*)d_in[9];
    const float* eb1 = (const float*)d_in[10];
    const float* ew2 = (const float*)d_in[11];
    const float* eb2 = (const float*)d_in[12];
    const float* dw1 = (const float*)d_in[13];
    const float* db1 = (const float*)d_in[14];
    const float* dw2 = (const float*)d_in[15];
    const float* db2 = (const float*)d_in[16];
    const float* DW  = (const float*)d_in[17];
    const float* db  = (const float*)d_in[18];
    const float* ow  = (const float*)d_in[19];
    const float* ob  = (const float*)d_in[20];
    float* OUT = (float*)d_out;

    float* ws = (float*)d_ws;
    size_t off = 0;
    auto alloc = [&](size_t n) { float* p = ws + off; off += n; return p; };
    float* PE   = alloc(4194304);
    short* PEb  = (short*)alloc(2097152);
    float* QKV  = alloc(12582912);  // [8192][1536] fp32: Q|K|V columns
    float* CTX  = alloc(4194304);   // distill conv output (fp32)
    short* CTXb = (short*)alloc(2097152);  // attention context (bf16)
    float* T1   = alloc(4194304);
    short* T1b  = (short*)alloc(2097152);
    float* XLN  = alloc(4194304);
    short* XLNb = (short*)alloc(2097152);
    float* T2   = alloc(4194304);
    short* T2b  = (short*)alloc(2097152);
    float* T3   = alloc(4194304);
    short* HIDb = (short*)alloc(8388608);  // FFN hidden bf16; reused as im2col
    float* D1   = alloc(2097152);
    short* D1b  = (short*)alloc(1048576);
    float* D2   = alloc(1048576);
    short* D2b  = (short*)alloc(524288);
    short* Ebb  = (short*)alloc(262144);
    float* Ebf  = alloc(524288);
    float* MB   = alloc(65536);
    float* VM   = alloc(8192);
    float* MU   = alloc(512);
    float* VARb = alloc(512);
    float* BQKV = alloc(1536);
    int* IDX  = (int*)alloc(17920);
    int* TOPB = (int*)alloc(4480);
    short* WqkvT = (short*)alloc(393216);  // [1536][512] bf16
    short* WoT   = (short*)alloc(131072);
    short* ew1T  = (short*)alloc(524288);
    short* ew2T  = (short*)alloc(524288);
    short* dw1T  = (short*)alloc(524288);
    short* dw2T  = (short*)alloc(524288);
    short* W2T   = (short*)alloc(393216);
    (void)ws_size; (void)n_in; (void)in_sizes; (void)out_size;

    static_assert(512 * 65 * 4 == 133120, "");
    hipError_t attr_ok = hipFuncSetAttribute(
        (const void*)msamp_lds_k, hipFuncAttributeMaxDynamicSharedMemorySize, 133120);

    auto gemm128 = [&](const short* A, const short* Bt, const float* bias, const float* res,
                       float* C32, short* C16, int M, int N, int K, int relu, int ldC) {
        gemm128_k<<<(N / 128) * (M / 128), 256, 0, stream>>>(A, Bt, bias, res, C32, C16,
                                                             M, N, K, relu, ldC);
    };
    auto gemm64 = [&](const short* A, const short* Bt, const float* bias, const float* res,
                      float* C32, short* C16, int M, int N, int K, int relu, int ldC) {
        gemm64_k<<<(N / 64) * (M / 64), 256, 0, stream>>>(A, Bt, bias, res, C32, C16,
                                                          M, N, K, relu, ldC);
    };
    auto tr = [&](const float* W, short* Wt, int K, int N) {
        dim3 g(N / 32, K / 32);
        transpose_bf16_k<<<g, 256, 0, stream>>>(W, Wt, K, N);
    };

    // attn: qinb/kvinb are bf16 [rows][512]; resp fp32 residual; out fp32 + opt bf16
    auto attn = [&](const short* qinb, const short* kvinb, const float* resp,
                    float* out32, short* out16, int LQ, int LK, int ikey) {
        int Mq = 16 * LQ, Mk = 16 * LK;
        const int ld = 1536;
        float* Qp = QKV;
        float* Kp = QKV + 512;
        float* Vp = QKV + 1024;
        if (qinb == kvinb) {
            gemm128(qinb, WqkvT, BQKV, nullptr, QKV, nullptr, Mq, 1536, 512, 0, ld);
        } else {
            gemm64(qinb, WqkvT, BQKV, nullptr, QKV, nullptr, Mq, 512, 512, 0, ld);
            gemm64(kvinb, WqkvT + 512 * 512, BQKV + 512, nullptr, QKV + 512, nullptr,
                   Mk, 1024, 512, 0, ld);
        }
        int U = imin(5 * iceil_log(LK), LK);
        int u = imin(5 * iceil_log(LQ), LQ);
        unsigned rk0, rk1;
        threefry2x32(0u, 42u, 0u, (unsigned)ikey, rk0, rk1);
        int size = LQ * U;
        ridx_k<<<(size + 255) / 256, 256, 0, stream>>>(rk0, rk1, size, (unsigned)(LK - 1), IDX);
        size_t shbytes = (size_t)LK * 65 * 4;
        if (attr_ok == hipSuccess || shbytes <= 65536) {
            msamp_lds_k<<<16 * 8 * 2, 256, shbytes, stream>>>(Qp, Kp, IDX, MB, LQ, LK, U, ld);
        } else {
            int totM = 16 * 8 * LQ * 4;
            msamp_k<<<(totM + 255) / 256, 256, 0, stream>>>(Qp, Kp, IDX, MB, LQ, LK, U, ld);
        }
        topk_k<<<128, 256, 0, stream>>>(MB, TOPB, LQ, u);
        vmean_k<<<dim3(16, 16), 256, 0, stream>>>(Vp, VM, LK, ld);
        int totC = 16 * LQ * 512;
        ctx_fill_k<<<(totC + 255) / 256, 256, 0, stream>>>(VM, CTXb, LQ, totC);
        attn_flash_k<<<16 * 8 * 2, 256, 0, stream>>>(Qp, Kp, Vp, TOPB, CTXb, LQ, LK, u, ld);
        gemm64(CTXb, WoT, bo, resp, out32, out16, Mq, 512, 512, 0, 512);
    };

    // encoder: Xb bf16 input (GEMM A), X fp32 (residual)
    auto encoder = [&](const short* Xb, const float* X, int L, int ikey, float* OUTenc) {
        int M = 16 * L;
        attn(Xb, Xb, X, T1, nullptr, L, L, ikey);
        ln_k<<<M, 256, 0, stream>>>(T1, XLN, XLNb);
        gemm128(XLNb, ew1T, eb1, nullptr, nullptr, HIDb, M, 2048, 512, 1, 2048);
        gemm64(HIDb, ew2T, eb2, XLN, T2, nullptr, M, 512, 2048, 0, 512);
        ln_k<<<M, 256, 0, stream>>>(T2, OUTenc, nullptr);
    };

    auto distill = [&](const float* X, int L, float* OUTd, short* OUTdb) {
        int M = 16 * L;
        int tot = M * 1536;
        xcat_k<<<(tot + 255) / 256, 256, 0, stream>>>(X, HIDb, L, tot);
        gemm64(HIDb, W2T, db, nullptr, CTX, nullptr, M, 512, 1536, 0, 512);
        bnstats_k<<<512, 256, 0, stream>>>(CTX, MU, VARb, M);
        int toto = 16 * (L / 2) * 512;
        elu_pool_k<<<(toto + 255) / 256, 256, 0, stream>>>(CTX, MU, VARb, OUTd, OUTdb, L, toto);
    };

    // --- weight conversion (once per launch) ---
    tr(Wq, WqkvT, 512, 512);
    tr(Wk, WqkvT + 512 * 512, 512, 512);
    tr(Wv, WqkvT + 1024 * 512, 512, 512);
    tr(Wo, WoT, 512, 512);
    tr(ew1, ew1T, 512, 2048);
    tr(ew2, ew2T, 2048, 512);
    tr(dw1, dw1T, 512, 2048);
    tr(dw2, dw2T, 2048, 512);
    w2t_k<<<(786432 + 255) / 256, 256, 0, stream>>>(DW, W2T, 786432);
    bcat_k<<<6, 256, 0, stream>>>(bq, bk, bv, BQKV);

    // --- forward ---
    int totPE = 16 * 512 * 512;
    pe_add_k<<<(totPE + 255) / 256, 256, 0, stream>>>(IN, PE, PEb, totPE);

    encoder(PEb, PE, 512, 0, T3); distill(T3, 512, D1, D1b);
    encoder(D1b, D1, 256, 1, T3); distill(T3, 256, D2, D2b);
    encoder(D2b, D2, 128, 2, T3); distill(T3, 128, Ebf, Ebb);

    attn(PEb, PEb, PE, T1, T1b, 512, 512, 3);   // out1 = dec_inp + attn
    attn(T1b, Ebb, T1, T2, T2b, 512, 64, 4);    // out2 = out1 + cross-attn
    gemm128(T2b, dw1T, db1, nullptr, nullptr, HIDb, 8192, 2048, 512, 1, 2048);
    gemm64(HIDb, dw2T, db2, T2, T3, nullptr, 8192, 512, 2048, 0, 512);
    final_k<<<(8192 * 64) / 256, 256, 0, stream>>>(T3, ow, ob, OUT, 8192);
}